// Round 6
// baseline (649.394 us; speedup 1.0000x reference)
//
#include <hip/hip_runtime.h>
#include <hip/hip_bf16.h>

typedef __bf16 bf16;
typedef __bf16 bf16x8 __attribute__((ext_vector_type(8)));
typedef float  f32x4  __attribute__((ext_vector_type(4)));

static __device__ __forceinline__ float b2f(bf16 x) { return (float)x; }
static __device__ __forceinline__ bf16  f2b(float x) { return (bf16)x; }
static __device__ __forceinline__ float ldval(float v) { return v; }
static __device__ __forceinline__ float ldval(bf16 v)  { return (float)v; }

// async global->LDS, 16B per lane; lds dest is wave-uniform base (+lane*16)
static __device__ __forceinline__ void gl_lds16(const bf16* g, bf16* l)
{
    __builtin_amdgcn_global_load_lds(
        (const __attribute__((address_space(1))) void*)g,
        (__attribute__((address_space(3))) void*)l,
        16, 0, 0);
}

// ---------------------------------------------------------------------------
// dtype detection: flag=1 -> f32 inputs.
// ---------------------------------------------------------------------------
__global__ void detect_dtype(const unsigned short* __restrict__ p, int* __restrict__ flag)
{
    if (threadIdx.x == 0 && blockIdx.x == 0) {
        int big = 0;
        for (int i = 0; i < 512; ++i) {
            int e = (p[i] >> 7) & 0xFF;
            if (e >= 0xE0) big++;
        }
        *flag = (big > 0) ? 1 : 0;
    }
}

// convert two tensors in one launch (grid split in half)
__global__ __launch_bounds__(256) void convert2(
    const void* __restrict__ sa, const void* __restrict__ sb,
    bf16* __restrict__ da, bf16* __restrict__ db, int n,
    const int* __restrict__ flag)
{
    int f = *flag;
    int half = gridDim.x >> 1;
    const void* s = (blockIdx.x < half) ? sa : sb;
    bf16* d = (blockIdx.x < half) ? da : db;
    int bid = (blockIdx.x < half) ? blockIdx.x : blockIdx.x - half;
    for (int i = bid * 256 + threadIdx.x; i < n; i += half * 256) {
        float v = f ? ((const float*)s)[i] : (float)((const bf16*)s)[i];
        d[i] = f2b(v);
    }
}

struct VecPack { const void* src[14]; int n[14]; };
__global__ __launch_bounds__(256) void convert_vecs(
    VecPack vp, bf16* __restrict__ dst, const int* __restrict__ flag)
{
    int v = blockIdx.x;
    int f = *flag;
    const void* s = vp.src[v];
    int n = vp.n[v];
    bf16* d = dst + (size_t)v * 4096;
    for (int i = threadIdx.x; i < n; i += 256) {
        float x = f ? ((const float*)s)[i] : (float)((const bf16*)s)[i];
        d[i] = f2b(x);
    }
}

// ---------------------------------------------------------------------------
// GEMM: C[M,N] = A[M,K] @ Bt[n][k]. MT x 128 tile, BK=64, 4 waves.
// ---------------------------------------------------------------------------
template <int EPI, int MT>
__global__ __launch_bounds__(256) void gemm_bt(
    const bf16* __restrict__ A0, int lda, int zsA, int zsA2,
    const bf16* __restrict__ B0, int ldb, int zsB, int zsB2,
    void* __restrict__ C0, int ldc, int zsC, int zsC2,
    const bf16* __restrict__ bias, int zsBias, float scale, int K)
{
    constexpr int IFR = MT / 32;
    __shared__ __align__(16) bf16 As[MT * 64];
    __shared__ __align__(16) bf16 Bs[128 * 64];
    const int z = blockIdx.z;
    const bf16* A  = A0 + (size_t)z * zsA + (size_t)(z >> 2) * zsA2;
    const bf16* Bt = B0 + (size_t)z * zsB + (size_t)(z >> 2) * zsB2;
    const size_t cbase = (size_t)z * zsC + (size_t)(z >> 2) * zsC2;
    if (bias) bias += (size_t)z * zsBias;
    const int tid  = threadIdx.x;
    const int lane = tid & 63, wave = tid >> 6;
    const int quad = lane >> 4, l16 = lane & 15;
    const size_t tm = (size_t)blockIdx.y * MT, tn = (size_t)blockIdx.x * 128;
    const int wm = (wave >> 1) * (MT / 2), wn = (wave & 1) * 64;
    const int srow = lane >> 3;
    const int scol = ((lane & 7) ^ srow) * 8;

    f32x4 acc[IFR][4];
    const f32x4 zro = {0.f, 0.f, 0.f, 0.f};
    #pragma unroll
    for (int i = 0; i < IFR; ++i)
        #pragma unroll
        for (int j = 0; j < 4; ++j) acc[i][j] = zro;

    const int swzA = l16 & 7;
    for (int k0 = 0; k0 < K; k0 += 64) {
        #pragma unroll
        for (int i = 0; i < IFR; ++i) {
            int chunk = (wave * IFR + i) * 64;
            int row = (chunk >> 3) + srow;
            gl_lds16(A + (tm + row) * (size_t)lda + k0 + scol, As + (size_t)chunk * 8);
        }
        #pragma unroll
        for (int i = 0; i < 4; ++i) {
            int chunk = (wave * 4 + i) * 64;
            int row = (chunk >> 3) + srow;
            gl_lds16(Bt + (tn + row) * (size_t)ldb + k0 + scol, Bs + (size_t)chunk * 8);
        }
        __syncthreads();
        #pragma unroll
        for (int kk = 0; kk < 2; ++kk) {
            bf16x8 af[IFR], bfr[4];
            #pragma unroll
            for (int i = 0; i < IFR; ++i) {
                int row = wm + i * 16 + l16;
                af[i] = *(const bf16x8*)(const void*)&As[(row * 8 + ((kk*4 + quad) ^ swzA)) * 8];
            }
            #pragma unroll
            for (int j = 0; j < 4; ++j) {
                int row = wn + j * 16 + l16;
                bfr[j] = *(const bf16x8*)(const void*)&Bs[(row * 8 + ((kk*4 + quad) ^ swzA)) * 8];
            }
            #pragma unroll
            for (int i = 0; i < IFR; ++i)
                #pragma unroll
                for (int j = 0; j < 4; ++j)
                    acc[i][j] = __builtin_amdgcn_mfma_f32_16x16x32_bf16(
                        af[i], bfr[j], acc[i][j], 0, 0, 0);
        }
        __syncthreads();
    }

    float* Cf = (float*)C0;
    bf16*  Cb = (bf16*)C0;
    #pragma unroll
    for (int i = 0; i < IFR; ++i) {
        #pragma unroll
        for (int j = 0; j < 4; ++j) {
            size_t col = tn + wn + j*16 + l16;
            float bb = bias ? b2f(bias[col]) : 0.f;
            #pragma unroll
            for (int r = 0; r < 4; ++r) {
                size_t row = tm + wm + i*16 + quad*4 + r;
                float v = acc[i][j][r] + bb;
                size_t off = cbase + row * (size_t)ldc + col;
                if (EPI == 0) {
                    Cf[off] = v;
                } else if (EPI == 1) {
                    Cb[off] = f2b(v * scale);
                } else {
                    float g = 0.5f * v * (1.f + tanhf(0.7978845608028654f *
                                  (v + 0.044715f * v * v * v)));
                    Cb[off] = f2b(g);
                }
            }
        }
    }
}

// ---------------------------------------------------------------------------
// FF1 GEMM, 256x256 tile, BK=64, 8 waves, 8-phase-style pipelined schedule.
// C[M,N] = gelu(A[M,K] @ Bt[N,K]^T + bias), bf16 out.
// ---------------------------------------------------------------------------
__global__ __launch_bounds__(512, 2) void gemm_ff1_8ph(
    const bf16* __restrict__ A, int lda,
    const bf16* __restrict__ Bt, int ldb,
    bf16* __restrict__ C, int ldc,
    const bf16* __restrict__ bias, int K)
{
    __shared__ __align__(16) bf16 As[2][256 * 64];
    __shared__ __align__(16) bf16 Bs[2][256 * 64];
    const int tid  = threadIdx.x;
    const int lane = tid & 63, wave = tid >> 6;
    const int quad = lane >> 4, l16 = lane & 15;
    const int wr = wave >> 2, wc = wave & 3;          // 2M x 4N wave grid
    const size_t tm = (size_t)blockIdx.y * 256;
    const size_t tn = (size_t)blockIdx.x * 256;
    const int srow = lane >> 3;
    const int scol = ((lane & 7) ^ srow) * 8;         // pre-swizzled global col
    const int swz  = l16 & 7;                         // read-side swizzle

    f32x4 acc[8][4];
    const f32x4 zro = {0.f, 0.f, 0.f, 0.f};
    #pragma unroll
    for (int m = 0; m < 8; ++m)
        #pragma unroll
        for (int n = 0; n < 4; ++n) acc[m][n] = zro;

    const bf16* aSrc[4];
    const bf16* bSrc[4];
    #pragma unroll
    for (int i = 0; i < 4; ++i) {
        int grow = wave * 32 + i * 8 + srow;
        aSrc[i] = A  + (tm + grow) * (size_t)lda + scol;
        bSrc[i] = Bt + (tn + grow) * (size_t)ldb + scol;
    }

#define STAGE(BUF, K0, I)                                                     \
    do {                                                                      \
        gl_lds16(aSrc[I] + (K0), &As[BUF][(wave * 4 + (I)) * 512]);           \
        gl_lds16(bSrc[I] + (K0), &Bs[BUF][(wave * 4 + (I)) * 512]);           \
    } while (0)

#define LDA_F(BUF, M, KK)                                                     \
    (*(const bf16x8*)(const void*)&As[BUF][(wr * 128 + (M) * 16 + l16) * 64 + \
        ((((KK) * 4 + quad) ^ swz) << 3)])
#define LDB_F(BUF, N, KK)                                                     \
    (*(const bf16x8*)(const void*)&Bs[BUF][(wc * 64 + (N) * 16 + l16) * 64 +  \
        ((((KK) * 4 + quad) ^ swz) << 3)])

#define PHASE(M0, M1, PREF_STMT, TAIL_STMT)                                   \
    {                                                                         \
        PREF_STMT;                                                            \
        bf16x8 x0 = LDA_F(cur, M0, 0), x1 = LDA_F(cur, M0, 1);                \
        bf16x8 y0 = LDA_F(cur, M1, 0), y1 = LDA_F(cur, M1, 1);                \
        asm volatile("s_barrier" ::: "memory");                               \
        __builtin_amdgcn_s_setprio(1);                                        \
        _Pragma("unroll")                                                     \
        for (int n = 0; n < 4; ++n) {                                         \
            acc[M0][n] = __builtin_amdgcn_mfma_f32_16x16x32_bf16(x0, bfr[n][0], acc[M0][n], 0, 0, 0); \
            acc[M0][n] = __builtin_amdgcn_mfma_f32_16x16x32_bf16(x1, bfr[n][1], acc[M0][n], 0, 0, 0); \
            acc[M1][n] = __builtin_amdgcn_mfma_f32_16x16x32_bf16(y0, bfr[n][0], acc[M1][n], 0, 0, 0); \
            acc[M1][n] = __builtin_amdgcn_mfma_f32_16x16x32_bf16(y1, bfr[n][1], acc[M1][n], 0, 0, 0); \
        }                                                                     \
        __builtin_amdgcn_s_setprio(0);                                        \
        TAIL_STMT;                                                            \
        asm volatile("s_barrier" ::: "memory");                               \
    }

    #pragma unroll
    for (int i = 0; i < 4; ++i) STAGE(0, 0, i);
    asm volatile("s_waitcnt vmcnt(0)" ::: "memory");
    asm volatile("s_barrier" ::: "memory");

    const int NT = K >> 6;
    bf16x8 bfr[4][2];
    for (int t = 0; t < NT; ++t) {
        const int cur = t & 1, nxt = cur ^ 1;
        const int k1  = (t + 1) << 6;
        const bool pref = (t + 1 < NT);

        #pragma unroll
        for (int n = 0; n < 4; ++n) {
            bfr[n][0] = LDB_F(cur, n, 0);
            bfr[n][1] = LDB_F(cur, n, 1);
        }
        PHASE(0, 1,
              if (pref) { STAGE(nxt, k1, 0); STAGE(nxt, k1, 1); }, )
        PHASE(2, 3,
              if (pref) { STAGE(nxt, k1, 2); STAGE(nxt, k1, 3); }, )
        PHASE(4, 5, , )
        PHASE(6, 7, ,
              asm volatile("s_waitcnt vmcnt(0)" ::: "memory"))
    }
#undef PHASE
#undef LDB_F
#undef LDA_F
#undef STAGE

    // epilogue: bias + fast gelu (v * sigmoid(1.59577 v + 0.0713548 v^3))
    #pragma unroll
    for (int m = 0; m < 8; ++m) {
        #pragma unroll
        for (int n = 0; n < 4; ++n) {
            size_t col = tn + wc * 64 + n * 16 + l16;
            float bb = b2f(bias[col]);
            #pragma unroll
            for (int r = 0; r < 4; ++r) {
                size_t row = tm + wr * 128 + m * 16 + quad * 4 + r;
                float v = acc[m][n][r] + bb;
                float s = v * (1.5957691216057308f + 0.07135481627f * v * v);
                float g = v / (1.f + __expf(-s));
                C[row * (size_t)ldc + col] = f2b(g);
            }
        }
    }
}

// ---------------------------------------------------------------------------
// dtype-branching transpose for raw weight inputs -> bf16 transposed
// ---------------------------------------------------------------------------
__global__ void transpose_any(const void* __restrict__ in, int R, int C,
                              unsigned short* __restrict__ out, int ldo,
                              const int* __restrict__ flag)
{
    __shared__ unsigned short t[32][33];
    int f = *flag;
    int c0 = blockIdx.x * 32, r0 = blockIdx.y * 32;
    int tx = threadIdx.x, ty = threadIdx.y;
    for (int i = ty; i < 32; i += 8) {
        size_t idx = (size_t)(r0 + i) * C + c0 + tx;
        bf16 v = f ? f2b(((const float*)in)[idx]) : ((const bf16*)in)[idx];
        t[i][tx] = *(unsigned short*)&v;
    }
    __syncthreads();
    for (int i = ty; i < 32; i += 8)
        out[(size_t)(c0 + i) * ldo + r0 + tx] = t[tx][i];
}

// videoT [b][2048][1024] -> VTpad [b][1024][512 + 2048] (col offset 512), z=b
__global__ void transpose_vt(const unsigned short* __restrict__ in,
                             unsigned short* __restrict__ out)
{
    __shared__ unsigned short t[32][33];
    int b = blockIdx.z;
    const unsigned short* src = in + (size_t)b * 2048 * 1024;
    unsigned short* dst = out + (size_t)b * 1024 * 2560;
    int c0 = blockIdx.x * 32, r0 = blockIdx.y * 32;
    int tx = threadIdx.x, ty = threadIdx.y;
    for (int i = ty; i < 32; i += 8)
        t[i][tx] = src[(size_t)(r0 + i) * 1024 + c0 + tx];
    __syncthreads();
    for (int i = ty; i < 32; i += 8)
        dst[(size_t)(c0 + i) * 2560 + 512 + r0 + tx] = t[tx][i];
}

// ---------------------------------------------------------------------------
// V transpose into per-head Vt[bh][64][2048] bf16.
// ---------------------------------------------------------------------------
__global__ void transpose_v(const float* __restrict__ qkv, bf16* __restrict__ Vt)
{
    __shared__ float t[32][33];
    int bh = blockIdx.z, b = bh >> 3, h = bh & 7;
    const float* src = qkv + (size_t)b * 2048 * 1536 + 1024 + h * 64;
    int c0 = blockIdx.x * 32, r0 = blockIdx.y * 32;
    int tx = threadIdx.x, ty = threadIdx.y;
    for (int i = ty; i < 32; i += 8)
        t[i][tx] = src[(size_t)(r0 + i) * 1536 + c0 + tx];
    __syncthreads();
    bf16* dst = Vt + (size_t)bh * 64 * 2048;
    for (int i = ty; i < 32; i += 8)
        dst[(size_t)(c0 + i) * 2048 + r0 + tx] = f2b(t[tx][i]);
}

// ---------------------------------------------------------------------------
// Row LayerNorm: one block per row.
// ---------------------------------------------------------------------------
template <typename Tin>
__global__ __launch_bounds__(256) void ln_rows(
    const Tin* __restrict__ in, int C,
    const bf16* __restrict__ g, const bf16* __restrict__ b,
    bf16* __restrict__ out, float eps)
{
    const int row = blockIdx.x, tid = threadIdx.x;
    const Tin* p = in + (size_t)row * C;
    float s = 0.f, ss = 0.f;
    for (int c = tid; c < C; c += 256) {
        float v = ldval(p[c]);
        s += v; ss += v * v;
    }
    #pragma unroll
    for (int d = 32; d > 0; d >>= 1) { s += __shfl_xor(s, d); ss += __shfl_xor(ss, d); }
    __shared__ float red[2][4];
    int wave = tid >> 6, lane = tid & 63;
    if (lane == 0) { red[0][wave] = s; red[1][wave] = ss; }
    __syncthreads();
    s  = red[0][0] + red[0][1] + red[0][2] + red[0][3];
    ss = red[1][0] + red[1][1] + red[1][2] + red[1][3];
    float mu   = s / C;
    float var  = ss / C - mu * mu;
    float rstd = rsqrtf(var + eps);
    bf16* q = out + (size_t)row * C;
    for (int c = tid; c < C; c += 256) {
        float v = ldval(p[c]);
        q[c] = f2b((v - mu) * rstd * b2f(g[c]) + b2f(b[c]));
    }
}

// both adapter LNs in one launch: rows 0..4095 audio, 4096..8191 video. C=1024.
__global__ __launch_bounds__(256) void ln_rows2(
    const bf16* __restrict__ in,
    const bf16* __restrict__ g0, const bf16* __restrict__ b0,
    const bf16* __restrict__ g1, const bf16* __restrict__ b1,
    bf16* __restrict__ out0, bf16* __restrict__ out1)
{
    const int row = blockIdx.x, tid = threadIdx.x;
    const int sel = row >> 12;
    const bf16* p = in + (size_t)row * 1024;
    const bf16* g = sel ? g1 : g0;
    const bf16* b = sel ? b1 : b0;
    bf16* q = (sel ? out1 + (size_t)(row - 4096) * 1024 : out0 + (size_t)row * 1024);
    float s = 0.f, ss = 0.f;
    for (int c = tid; c < 1024; c += 256) {
        float v = b2f(p[c]);
        s += v; ss += v * v;
    }
    #pragma unroll
    for (int d = 32; d > 0; d >>= 1) { s += __shfl_xor(s, d); ss += __shfl_xor(ss, d); }
    __shared__ float red[2][4];
    int wave = tid >> 6, lane = tid & 63;
    if (lane == 0) { red[0][wave] = s; red[1][wave] = ss; }
    __syncthreads();
    s  = red[0][0] + red[0][1] + red[0][2] + red[0][3];
    ss = red[1][0] + red[1][1] + red[1][2] + red[1][3];
    float mu   = s * (1.f / 1024.f);
    float var  = ss * (1.f / 1024.f) - mu * mu;
    float rstd = rsqrtf(var + 1e-5f);
    for (int c = tid; c < 1024; c += 256) {
        float v = b2f(p[c]);
        q[c] = f2b((v - mu) * rstd * b2f(g[c]) + b2f(b[c]));
    }
}

// ---------------------------------------------------------------------------
// Rotary (reads raw text via flag): qrot = rope(text)*DIM^-0.5 ;
// krotPad[b][512+t] = rope(audio_t).
// ---------------------------------------------------------------------------
__global__ __launch_bounds__(256) void rotary_kernel(
    const void* __restrict__ text, const int* __restrict__ flag,
    const bf16* __restrict__ audioT,
    bf16* __restrict__ qrot, bf16* __restrict__ krotPad)
{
    int row = blockIdx.x;
    int t = row & 2047, b = row >> 11;
    int tid = threadIdx.x;
    int f = *flag;
    const float lg = 9.210340371976184f / 512.f;
    size_t base = (size_t)row * 1024;
    size_t kb = ((size_t)(b * 2560 + 512 + t)) * 1024;
    for (int c = tid; c < 512; c += 256) {
        float invf = __expf(-(float)c * lg);
        float th = (float)t * invf;
        float sn, cs;
        sincosf(th, &sn, &cs);
        float q1 = f ? ((const float*)text)[base + c]
                     : b2f(((const bf16*)text)[base + c]);
        float q2 = f ? ((const float*)text)[base + c + 512]
                     : b2f(((const bf16*)text)[base + c + 512]);
        qrot[base + c]       = f2b((q1 * cs - q2 * sn) * 0.03125f);
        qrot[base + c + 512] = f2b((q2 * cs + q1 * sn) * 0.03125f);
        float k1 = b2f(audioT[base + c]), k2 = b2f(audioT[base + c + 512]);
        krotPad[kb + c]       = f2b(k1 * cs - k2 * sn);
        krotPad[kb + c + 512] = f2b(k2 * cs + k1 * sn);
    }
}

// ---------------------------------------------------------------------------
// Local-attention masked softmax. sim [b][w][512][1024] f32 -> attn bf16.
// ---------------------------------------------------------------------------
__global__ __launch_bounds__(256) void softmax_local(
    const float* __restrict__ sim, bf16* __restrict__ attn)
{
    int i  = blockIdx.x;
    int zz = blockIdx.y;
    int w  = zz & 3;
    int tid = threadIdx.x;
    const float* p = sim + ((size_t)zz * 512 + i) * 1024;
    bf16* q = attn + ((size_t)zz * 512 + i) * 1024;
    int jlo = (w == 0) ? 512 : 0;
    int jhi = 512 + i;
    float m = -1e30f;
    #pragma unroll
    for (int k = 0; k < 4; ++k) {
        int c = tid + k * 256;
        if (c >= jlo && c <= jhi) m = fmaxf(m, p[c]);
    }
    #pragma unroll
    for (int d = 32; d > 0; d >>= 1) m = fmaxf(m, __shfl_xor(m, d));
    __shared__ float red[2][4];
    int wave = tid >> 6, lane = tid & 63;
    if (lane == 0) red[0][wave] = m;
    __syncthreads();
    m = fmaxf(fmaxf(red[0][0], red[0][1]), fmaxf(red[0][2], red[0][3]));
    float pv[4];
    float s = 0.f;
    #pragma unroll
    for (int k = 0; k < 4; ++k) {
        int c = tid + k * 256;
        float e = (c >= jlo && c <= jhi) ? __expf(p[c] - m) : 0.f;
        pv[k] = e; s += e;
    }
    #pragma unroll
    for (int d = 32; d > 0; d >>= 1) s += __shfl_xor(s, d);
    if (lane == 0) red[1][wave] = s;
    __syncthreads();
    s = red[1][0] + red[1][1] + red[1][2] + red[1][3];
    float inv = 1.f / s;
    #pragma unroll
    for (int k = 0; k < 4; ++k) q[tid + k * 256] = f2b(pv[k] * inv);
}

// ---------------------------------------------------------------------------
// pack_qk: RMSNorm q/k from qkv f32 [4096][1536] -> per-head bf16 buffers.
// ---------------------------------------------------------------------------
__global__ __launch_bounds__(256) void pack_qk(
    const float* __restrict__ qkv, bf16* __restrict__ Qp, bf16* __restrict__ Kp,
    const bf16* __restrict__ qn_g, const bf16* __restrict__ kn_g)
{
    int gid  = blockIdx.x * 4 + (threadIdx.x >> 6);
    int lane = threadIdx.x & 63;
    int token = gid >> 4, r = gid & 15, part = r >> 3, h = r & 7;
    const float* p = qkv + (size_t)token * 1536 + part * 512 + h * 64 + lane;
    float v = *p;
    float ss = v * v;
    #pragma unroll
    for (int d = 32; d > 0; d >>= 1) ss += __shfl_xor(ss, d);
    float sc = rsqrtf(ss * (1.f / 64.f) + 1e-6f);
    const bf16* gw = part ? kn_g : qn_g;
    float outv = v * sc * b2f(gw[lane]);
    if (!part) outv *= 0.125f;
    int b = token >> 11, t = token & 2047;
    bf16* dst = (part ? Kp : Qp) + ((size_t)(b * 8 + h) * 2048 + t) * 64 + lane;
    *dst = f2b(outv);
}

// ---------------------------------------------------------------------------
// Fused causal flash attention (D=64), swapped-operand softmax + LDS-staged
// K/V (double-buffered, reg prefetch). 32 q-rows/block, 2 waves.
// Grid (64, 16): qb = 63 - blockIdx.x (LPT). QK^T computed as mfma(K, Q):
// lane's l16 = its q-row, so the 16 key-scores live in that lane's registers;
// per-quad (m,sum) computed locally and merged across quads with only TWO
// overlapped shuffle steps (vs 8 dependent shuffles in the row-parallel form).
// LDS fragment addresses identical to the verified flash_fused3 kernel.
// ---------------------------------------------------------------------------
__global__ __launch_bounds__(128, 2) void flash_fused4(
    const bf16* __restrict__ Qp, const bf16* __restrict__ Kp,
    const bf16* __restrict__ Vt, bf16* __restrict__ o)
{
    __shared__ __align__(16) bf16 Ks[2][64][72];
    __shared__ __align__(16) bf16 Vs[2][64][72];
    __shared__ __align__(16) bf16 Ps[2][16][72];
    const int qb = 63 - blockIdx.x;
    const int bh = blockIdx.y, b = bh >> 3, h = bh & 7;
    const int qm = qb * 32;
    const int tid = threadIdx.x, wave = tid >> 6, lane = tid & 63;
    const int quad = lane >> 4, l16 = lane & 15;
    const bf16* Qg = Qp + (size_t)bh * 2048 * 64;
    const bf16* Kg = Kp + (size_t)bh * 2048 * 64;
    const bf16* Vg = Vt + (size_t)bh * 64 * 2048;

    // Q as B-operand: lane l16 -> q-row, quad -> d-chunk
    const int q_row = qm + wave * 16 + l16;
    bf16x8 qa[2];
    qa[0] = *(const bf16x8*)(const void*)(Qg + (size_t)q_row * 64 + quad * 8);
    qa[1] = *(const bf16x8*)(const void*)(Qg + (size_t)q_row * 64 + 32 + quad * 8);

    f32x4 oacc[4];
    const f32x4 zro = {0.f, 0.f, 0.f, 0.f};
    #pragma unroll
    for (int j = 0; j < 4; ++j) oacc[j] = zro;
    float mst = -1e30f, lst = 0.f;

    // staging: 128 threads, each covers half a 64-elem row (4 x 16B)
    const int ldr = tid >> 1, ldc = (tid & 1) * 32;
    const int nt = (qb >> 1) + 1;

    uint4 kreg[4], vreg[4];
    #pragma unroll
    for (int c = 0; c < 4; ++c) {
        kreg[c] = *(const uint4*)(const void*)(Kg + (size_t)ldr * 64 + ldc + c * 8);
        vreg[c] = *(const uint4*)(const void*)(Vg + (size_t)ldr * 2048 + ldc + c * 8);
    }
    #pragma unroll
    for (int c = 0; c < 4; ++c) {
        *(uint4*)(void*)&Ks[0][ldr][ldc + c * 8] = kreg[c];
        *(uint4*)(void*)&Vs[0][ldr][ldc + c * 8] = vreg[c];
    }
    __syncthreads();

    for (int t = 0; t < nt; ++t) {
        const int cur = t & 1, nxt = cur ^ 1;
        const int jt = t * 64;
        const bool pref = (t + 1 < nt);
        if (pref) {
            const int jn = jt + 64;
            #pragma unroll
            for (int c = 0; c < 4; ++c) {
                kreg[c] = *(const uint4*)(const void*)(Kg + (size_t)(jn + ldr) * 64 + ldc + c * 8);
                vreg[c] = *(const uint4*)(const void*)(Vg + (size_t)ldr * 2048 + jn + ldc + c * 8);
            }
        }

        // ---- QK^T swapped: s[j][r] = score(key = jt + j*16 + quad*4 + r, q_row)
        f32x4 s[4];
        #pragma unroll
        for (int j = 0; j < 4; ++j) s[j] = zro;
        #pragma unroll
        for (int kk = 0; kk < 2; ++kk) {
            #pragma unroll
            for (int j = 0; j < 4; ++j) {
                bf16x8 kf = *(const bf16x8*)(const void*)&Ks[cur][j*16 + l16][kk*32 + quad*8];
                s[j] = __builtin_amdgcn_mfma_f32_16x16x32_bf16(kf, qa[kk], s[j], 0, 0, 0);
            }
        }

        // causal mask
        if (jt + 63 > q_row) {
            #pragma unroll
            for (int j = 0; j < 4; ++j) {
                #pragma unroll
                for (int r = 0; r < 4; ++r) {
                    int key = jt + j * 16 + quad * 4 + r;
                    if (key > q_row) s[j][r] = -1e30f;
                }
            }
        }

        // per-lane (per-quad) local max + exp-sum
        float mq = s[0][0];
        #pragma unroll
        for (int j = 0; j < 4; ++j)
            #pragma unroll
            for (int r = 0; r < 4; ++r) mq = fmaxf(mq, s[j][r]);
        float e[4][4];
        float sq = 0.f;
        #pragma unroll
        for (int j = 0; j < 4; ++j)
            #pragma unroll
            for (int r = 0; r < 4; ++r) {
                float v = __expf(s[j][r] - mq);
                e[j][r] = v; sq += v;
            }

        // merge (m, s) across the 4 quads of this q-row: two overlapped steps
        float mo = __shfl_xor(mq, 16);
        float so = __shfl_xor(sq, 16);
        float mm = fmaxf(mq, mo);
        sq = sq * __expf(mq - mm) + so * __expf(mo - mm);
        float mo2 = __shfl_xor(mm, 32);
        float so2 = __shfl_xor(sq, 32);
        float mtile = fmaxf(mm, mo2);
        float stile = sq * __expf(mm - mtile) + so2 * __expf(mo2 - mtile);

        // online update (uniform across the 4 quad-lanes of this q-row)
        float mn  = fmaxf(mst, mtile);
        float scl = __expf(mst - mn);
        lst = lst * scl + stile * __expf(mtile - mn);
        mst = mn;
        float pf = __expf(mq - mn);   // per-lane factor for its e[] values

        // rescale O (rows quad*4+r): fetch scl of those q-rows
        float sclq[4];
        #pragma unroll
        for (int r = 0; r < 4; ++r) sclq[r] = __shfl(scl, quad * 4 + r);
        #pragma unroll
        for (int j = 0; j < 4; ++j)
            #pragma unroll
            for (int r = 0; r < 4; ++r) oacc[j][r] *= sclq[r];

        // pack P = e*pf -> bf16, bounce via Ps to A-fragment layout
        #pragma unroll
        for (int j = 0; j < 4; ++j) {
            union { bf16 hx[4]; uint2 u; } pk;
            pk.hx[0] = f2b(e[j][0] * pf); pk.hx[1] = f2b(e[j][1] * pf);
            pk.hx[2] = f2b(e[j][2] * pf); pk.hx[3] = f2b(e[j][3] * pf);
            *(uint2*)(void*)&Ps[wave][l16][j * 16 + quad * 4] = pk.u;
        }
        bf16x8 pa0 = *(const bf16x8*)(const void*)&Ps[wave][l16][quad * 8];
        bf16x8 pa1 = *(const bf16x8*)(const void*)&Ps[wave][l16][32 + quad * 8];

        // PV (same fragments as before)
        #pragma unroll
        for (int j = 0; j < 4; ++j) {
            bf16x8 vb = *(const bf16x8*)(const void*)&Vs[cur][j*16 + l16][quad*8];
            oacc[j] = __builtin_amdgcn_mfma_f32_16x16x32_bf16(pa0, vb, oacc[j], 0, 0, 0);
        }
        #pragma unroll
        for (int j = 0; j < 4; ++j) {
            bf16x8 vb = *(const bf16x8*)(const void*)&Vs[cur][j*16 + l16][32 + quad*8];
            oacc[j] = __builtin_amdgcn_mfma_f32_16x16x32_bf16(pa1, vb, oacc[j], 0, 0, 0);
        }

        if (pref) {
            #pragma unroll
            for (int c = 0; c < 4; ++c) {
                *(uint4*)(void*)&Ks[nxt][ldr][ldc + c * 8] = kreg[c];
                *(uint4*)(void*)&Vs[nxt][ldr][ldc + c * 8] = vreg[c];
            }
            __syncthreads();
        }
    }

    float invq[4];
    #pragma unroll
    for (int r = 0; r < 4; ++r) invq[r] = 1.f / __shfl(lst, quad * 4 + r);
    #pragma unroll
    for (int j = 0; j < 4; ++j) {
        #pragma unroll
        for (int r = 0; r < 4; ++r) {
            int tr = qm + wave * 16 + quad * 4 + r;
            o[((size_t)(b * 2048 + tr)) * 512 + h * 64 + j * 16 + l16] =
                f2b(oacc[j][r] * invq[r]);
        }
    }
}

// ---------------------------------------------------------------------------
// FF2 split-K merge + bias + residual: out f32 = p0+p1+b2+x2. 4M elements.
// ---------------------------------------------------------------------------
__global__ __launch_bounds__(256) void combine_ff2(
    const float* __restrict__ p0, const float* __restrict__ p1,
    const bf16* __restrict__ x2, const bf16* __restrict__ b2,
    float* __restrict__ out)
{
    int i4 = (blockIdx.x * 256 + threadIdx.x) * 4;
    #pragma unroll
    for (int k = 0; k < 4; ++k) {
        int i = i4 + k;
        out[i] = p0[i] + p1[i] + b2f(x2[i]) + b2f(b2[i & 1023]);
    }
}

// ---------------------------------------------------------------------------
static void launch_gemm(int epi, hipStream_t s,
                        const bf16* A, int lda, int zsA, int zsA2,
                        const bf16* Bt, int ldb, int zsB, int zsB2,
                        void* C, int ldc, int zsC, int zsC2,
                        const bf16* bias, int zsBias, float scale,
                        int M, int N, int K, int nz)
{
    bool mt64 = ((M >> 7) * (N >> 7) * nz) <= 512;
    dim3 blk(256);
    if (mt64) {
        dim3 g(N / 128, M / 64, nz);
        switch (epi) {
        case 0: gemm_bt<0,64><<<g, blk, 0, s>>>(A, lda, zsA, zsA2, Bt, ldb, zsB, zsB2, C, ldc, zsC, zsC2, bias, zsBias, scale, K); break;
        case 1: gemm_bt<1,64><<<g, blk, 0, s>>>(A, lda, zsA, zsA2, Bt, ldb, zsB, zsB2, C, ldc, zsC, zsC2, bias, zsBias, scale, K); break;
        default: gemm_bt<2,64><<<g, blk, 0, s>>>(A, lda, zsA, zsA2, Bt, ldb, zsB, zsB2, C, ldc, zsC, zsC2, bias, zsBias, scale, K); break;
        }
    } else {
        dim3 g(N / 128, M / 128, nz);
        switch (epi) {
        case 0: gemm_bt<0,128><<<g, blk, 0, s>>>(A, lda, zsA, zsA2, Bt, ldb, zsB, zsB2, C, ldc, zsC, zsC2, bias, zsBias, scale, K); break;
        case 1: gemm_bt<1,128><<<g, blk, 0, s>>>(A, lda, zsA, zsA2, Bt, ldb, zsB, zsB2, C, ldc, zsC, zsC2, bias, zsBias, scale, K); break;
        default: gemm_bt<2,128><<<g, blk, 0, s>>>(A, lda, zsA, zsA2, Bt, ldb, zsB, zsB2, C, ldc, zsC, zsC2, bias, zsBias, scale, K); break;
        }
    }
}

extern "C" void kernel_launch(void* const* d_in, const int* in_sizes, int n_in,
                              void* d_out, int out_size, void* d_ws, size_t ws_size,
                              hipStream_t stream)
{
    const void* text  = d_in[0];
    const void* audio = d_in[1];
    const void* video = d_in[2];
    const void* Wa    = d_in[3];
    const void* ba    = d_in[4];
    const void* lna_g = d_in[5];
    const void* lna_b = d_in[6];
    const void* Wvid  = d_in[7];
    const void* bvid  = d_in[8];
    const void* lnv_g = d_in[9];
    const void* lnv_b = d_in[10];
    const void* ln1_g = d_in[11];
    const void* ln1_b = d_in[12];
    const void* Wq    = d_in[13];
    const void* Wkv   = d_in[14];
    const void* qn_g  = d_in[15];
    const void* kn_g  = d_in[16];
    const void* Wo    = d_in[17];
    const void* W1    = d_in[18];
    const void* b1    = d_in[19];
    const void* ln2_g = d_in[20];
    const void* ln2_b = d_in[21];
    const void* W2    = d_in[22];
    const void* b2    = d_in[23];

    char* ws = (char*)d_ws;
    size_t off = 0;
    auto alloc = [&](size_t bytes) -> char* {
        char* p = ws + off;
        off += (bytes + 255) & ~(size_t)255;
        return p;
    };
    const size_t MB = 1024 * 1024;
    int*  flag  = (int*)alloc(256);
    bf16* vecs  = (bf16*)alloc(14 * 4096 * 2);
    bf16* WqkvT = (bf16*)alloc((size_t)1536 * 1024 * 2);
    bf16* WoT   = (bf16*)alloc((size_t)1024 * 512 * 2);
    bf16* W1T   = (bf16*)alloc((size_t)4096 * 1024 * 2);
    bf16* W2T   = (bf16*)alloc((size_t)1024 * 4096 * 2);
    char* regionIn = alloc(24 * MB);   // audioC,videoC -> qkvF -> p0
    char* region2  = alloc(32 * MB);   // tmp2/tmpF/xF -> g
    char* regionH  = alloc(8 * MB);    // audioT -> h
    char* regionX  = alloc(8 * MB);    // videoT -> x2
    char* regionO  = alloc(4 * MB);    // WaT,WvT -> o
    bf16* qrot    = (bf16*)alloc((size_t)4096 * 1024 * 2);
    bf16* krotPad = (bf16*)alloc((size_t)2 * 2560 * 1024 * 2);
    bf16* VTpad   = (bf16*)alloc((size_t)2 * 1024 * 2560 * 2);
    bf16* attn    = (bf16*)alloc((size_t)8 * 512 * 1024 * 2);

    bf16*  audioC = (bf16*)regionIn;
    bf16*  videoC = audioC + (size_t)4096 * 1024;
    float* qkvF   = (float*)regionIn;
    bf16*  tmp2   = (bf16*)region2;          // adapter GEMM out (2 x 4096x1024 bf16)
    float* tmpF   = (float*)region2;         // sim scores f32
    float* xF     = (float*)(region2 + 16 * MB);
    bf16*  g      = (bf16*)region2;
    bf16*  audioT = (bf16*)regionH;
    bf16*  h      = (bf16*)regionH;
    bf16*  videoT = (bf16*)regionX;
    bf16*  x2     = (bf16*)regionX;
    bf16*  WaT    = (bf16*)regionO;
    bf16*  WvT    = WaT + (size_t)1024 * 1024;
    bf16*  o      = (bf16*)regionO;
    bf16*  Qp     = qrot;
    bf16*  Kp     = krotPad;
    bf16*  Vth    = attn;
    // FF2 split-K partials (dead regions at FF2 time)
    float* p0     = (float*)regionIn;        // 16 MB of 24
    float* p1     = (float*)VTpad;           // VTpad+attn contiguous 18 MB

    bf16* baC   = vecs + 0 * 4096;
    bf16* bvidC = vecs + 1 * 4096;
    bf16* lnagC = vecs + 2 * 4096;
    bf16* lnabC = vecs + 3 * 4096;
    bf16* lnvgC = vecs + 4 * 4096;
    bf16* lnvbC = vecs + 5 * 4096;
    bf16* ln1gC = vecs + 6 * 4096;
    bf16* ln1bC = vecs + 7 * 4096;
    bf16* qngC  = vecs + 8 * 4096;
    bf16* kngC  = vecs + 9 * 4096;
    bf16* b1C   = vecs + 10 * 4096;
    bf16* ln2gC = vecs + 11 * 4096;
    bf16* ln2bC = vecs + 12 * 4096;
    bf16* b2C   = vecs + 13 * 4096;

    // 1) dtype flag
    detect_dtype<<<1, 64, 0, stream>>>((const unsigned short*)text, flag);

    // 2) canonicalize audio+video (one launch) + small vectors
    const int NTOK = 4096 * 1024;
    convert2<<<4096, 256, 0, stream>>>(audio, video, audioC, videoC, NTOK, flag);
    VecPack vp;
    const void* vsrc[14] = {ba, bvid, lna_g, lna_b, lnv_g, lnv_b, ln1_g, ln1_b,
                            qn_g, kn_g, b1, ln2_g, ln2_b, b2};
    int vn[14] = {1024, 1024, 1024, 1024, 1024, 1024, 1024, 1024,
                  64, 64, 4096, 4096, 4096, 1024};
    for (int i = 0; i < 14; ++i) { vp.src[i] = vsrc[i]; vp.n[i] = vn[i]; }
    convert_vecs<<<14, 256, 0, stream>>>(vp, vecs, flag);

    // 3) weight transposes
    dim3 tb(32, 8);
    transpose_any<<<dim3(32, 32), tb, 0, stream>>>(Wa, 1024, 1024, (unsigned short*)WaT, 1024, flag);
    transpose_any<<<dim3(32, 32), tb, 0, stream>>>(Wvid, 1024, 1024, (unsigned short*)WvT, 1024, flag);
    transpose_any<<<dim3(16, 32), tb, 0, stream>>>(Wq, 1024, 512, (unsigned short*)WqkvT, 1024, flag);
    transpose_any<<<dim3(32, 32), tb, 0, stream>>>(Wkv, 1024, 1024, (unsigned short*)(WqkvT + (size_t)512 * 1024), 1024, flag);
    transpose_any<<<dim3(32, 16), tb, 0, stream>>>(Wo, 512, 1024, (unsigned short*)WoT, 512, flag);
    transpose_any<<<dim3(128, 32), tb, 0, stream>>>(W1, 1024, 4096, (unsigned short*)W1T, 1024, flag);
    transpose_any<<<dim3(32, 128), tb, 0, stream>>>(W2, 4096, 1024, (unsigned short*)W2T, 4096, flag);

    // 4) adapters: one batched GEMM (nz=2, bf16 out w/ bias) + merged LN
    launch_gemm(1, stream, audioC, 1024, 4096*1024, 0, WaT, 1024, 1024*1024, 0,
                tmp2, 1024, 4096*1024, 0, baC, 4096, 1.f, 4096, 1024, 1024, 2);
    ln_rows2<<<8192, 256, 0, stream>>>(tmp2, lnagC, lnabC, lnvgC, lnvbC, audioT, videoT);

    // 5) pads, rotary (raw text), batched VTpad transpose
    hipMemsetAsync(krotPad, 0, (size_t)2 * 2560 * 1024 * 2, stream);
    hipMemsetAsync(VTpad, 0, (size_t)2 * 1024 * 2560 * 2, stream);
    rotary_kernel<<<4096, 256, 0, stream>>>(text, flag, audioT, qrot, krotPad);
    transpose_vt<<<dim3(32, 64, 2), tb, 0, stream>>>(
        (const unsigned short*)videoT, (unsigned short*)VTpad);

    // 6) local attention: batched sim (nz=8) -> softmax -> batched @V (nz=8)
    launch_gemm(0, stream, qrot, 1024, 512*1024, 0,
                krotPad, 1024, 512*1024, 512*1024,
                tmpF, 1024, 512*1024, 0, nullptr, 0, 1.f, 512, 1024, 1024, 8);
    softmax_local<<<dim3(512, 8), 256, 0, stream>>>(tmpF, attn);
    launch_gemm(0, stream, attn, 1024, 512*1024, 0,
                VTpad, 2560, 512, 1024*2560 - 2048,
                xF, 1024, 512*1024, 0, nullptr, 0, 1.f, 512, 1024, 1024, 8);

    // 7) ln1 -> qkv -> pack -> V transpose -> swapped-softmax fused flash
    ln_rows<float><<<4096, 256, 0, stream>>>(xF, 1024, ln1gC, ln1bC, h, 1e-5f);
    launch_gemm(0, stream, h, 1024, 0, 0, WqkvT, 1024, 0, 0,
                qkvF, 1536, 0, 0, nullptr, 0, 1.f, 4096, 1536, 1024, 1);
    pack_qk<<<16384, 256, 0, stream>>>(qkvF, Qp, Kp, qngC, kngC);
    transpose_v<<<dim3(2, 64, 16), tb, 0, stream>>>(qkvF, Vth);
    flash_fused4<<<dim3(64, 16), 128, 0, stream>>>(Qp, Kp, Vth, o);

    // 8) x2 = 2*(o@Wo) ; g = gelu(x2@W1+b1) via 8-phase 256^2 ; ln2 ; FF2
    launch_gemm(1, stream, o, 512, 0, 0, WoT, 512, 0, 0,
                x2, 1024, 0, 0, nullptr, 0, 2.f, 4096, 1024, 512, 1);
    gemm_ff1_8ph<<<dim3(16, 16), 512, 0, stream>>>(x2, 1024, W1T, 1024,
                                                   g, 4096, b1C, 1024);
    ln_rows<bf16><<<4096, 256, 0, stream>>>(g, 4096, ln2gC, ln2bC, g, 1e-5f);
    launch_gemm(0, stream, g, 4096, 2048, 0, W2T, 4096, 2048, 0,
                p0, 1024, (int)(p1 - p0), 0, nullptr, 0, 1.f, 4096, 1024, 2048, 2);
    combine_ff2<<<4096, 256, 0, stream>>>(p0, p1, x2, b2C, (float*)d_out);

    (void)in_sizes; (void)n_in; (void)out_size; (void)ws_size;
}

// Round 7
// 569.379 us; speedup vs baseline: 1.1405x; 1.1405x over previous
//
#include <hip/hip_runtime.h>
#include <hip/hip_bf16.h>

typedef __bf16 bf16;
typedef __bf16 bf16x8 __attribute__((ext_vector_type(8)));
typedef float  f32x4  __attribute__((ext_vector_type(4)));

static __device__ __forceinline__ float b2f(bf16 x) { return (float)x; }
static __device__ __forceinline__ bf16  f2b(float x) { return (bf16)x; }
static __device__ __forceinline__ float ldval(float v) { return v; }
static __device__ __forceinline__ float ldval(bf16 v)  { return (float)v; }

// pack two floats -> one uint holding two bf16 (low = a, high = b)
static __device__ __forceinline__ unsigned pk2(float a, float b)
{
    bf16 x = f2b(a), y = f2b(b);
    unsigned short ux = *(unsigned short*)&x;
    unsigned short uy = *(unsigned short*)&y;
    return (unsigned)ux | ((unsigned)uy << 16);
}

// async global->LDS, 16B per lane; lds dest is wave-uniform base (+lane*16)
static __device__ __forceinline__ void gl_lds16(const bf16* g, bf16* l)
{
    __builtin_amdgcn_global_load_lds(
        (const __attribute__((address_space(1))) void*)g,
        (__attribute__((address_space(3))) void*)l,
        16, 0, 0);
}

// ---------------------------------------------------------------------------
// dtype detection: flag=1 -> f32 inputs.
// ---------------------------------------------------------------------------
__global__ void detect_dtype(const unsigned short* __restrict__ p, int* __restrict__ flag)
{
    if (threadIdx.x == 0 && blockIdx.x == 0) {
        int big = 0;
        for (int i = 0; i < 512; ++i) {
            int e = (p[i] >> 7) & 0xFF;
            if (e >= 0xE0) big++;
        }
        *flag = (big > 0) ? 1 : 0;
    }
}

// convert two tensors in one launch (grid split in half)
__global__ __launch_bounds__(256) void convert2(
    const void* __restrict__ sa, const void* __restrict__ sb,
    bf16* __restrict__ da, bf16* __restrict__ db, int n,
    const int* __restrict__ flag)
{
    int f = *flag;
    int half = gridDim.x >> 1;
    const void* s = (blockIdx.x < half) ? sa : sb;
    bf16* d = (blockIdx.x < half) ? da : db;
    int bid = (blockIdx.x < half) ? blockIdx.x : blockIdx.x - half;
    for (int i = bid * 256 + threadIdx.x; i < n; i += half * 256) {
        float v = f ? ((const float*)s)[i] : (float)((const bf16*)s)[i];
        d[i] = f2b(v);
    }
}

struct VecPack { const void* src[14]; int n[14]; };
__global__ __launch_bounds__(256) void convert_vecs(
    VecPack vp, bf16* __restrict__ dst, const int* __restrict__ flag)
{
    int v = blockIdx.x;
    int f = *flag;
    const void* s = vp.src[v];
    int n = vp.n[v];
    bf16* d = dst + (size_t)v * 4096;
    for (int i = threadIdx.x; i < n; i += 256) {
        float x = f ? ((const float*)s)[i] : (float)((const bf16*)s)[i];
        d[i] = f2b(x);
    }
}

// ---------------------------------------------------------------------------
// GEMM: C[M,N] = A[M,K] @ Bt[n][k]. MT x 128 tile, BK=64, 4 waves.
// ---------------------------------------------------------------------------
template <int EPI, int MT>
__global__ __launch_bounds__(256) void gemm_bt(
    const bf16* __restrict__ A0, int lda, int zsA, int zsA2,
    const bf16* __restrict__ B0, int ldb, int zsB, int zsB2,
    void* __restrict__ C0, int ldc, int zsC, int zsC2,
    const bf16* __restrict__ bias, int zsBias, float scale, int K)
{
    constexpr int IFR = MT / 32;
    __shared__ __align__(16) bf16 As[MT * 64];
    __shared__ __align__(16) bf16 Bs[128 * 64];
    const int z = blockIdx.z;
    const bf16* A  = A0 + (size_t)z * zsA + (size_t)(z >> 2) * zsA2;
    const bf16* Bt = B0 + (size_t)z * zsB + (size_t)(z >> 2) * zsB2;
    const size_t cbase = (size_t)z * zsC + (size_t)(z >> 2) * zsC2;
    if (bias) bias += (size_t)z * zsBias;
    const int tid  = threadIdx.x;
    const int lane = tid & 63, wave = tid >> 6;
    const int quad = lane >> 4, l16 = lane & 15;
    const size_t tm = (size_t)blockIdx.y * MT, tn = (size_t)blockIdx.x * 128;
    const int wm = (wave >> 1) * (MT / 2), wn = (wave & 1) * 64;
    const int srow = lane >> 3;
    const int scol = ((lane & 7) ^ srow) * 8;

    f32x4 acc[IFR][4];
    const f32x4 zro = {0.f, 0.f, 0.f, 0.f};
    #pragma unroll
    for (int i = 0; i < IFR; ++i)
        #pragma unroll
        for (int j = 0; j < 4; ++j) acc[i][j] = zro;

    const int swzA = l16 & 7;
    for (int k0 = 0; k0 < K; k0 += 64) {
        #pragma unroll
        for (int i = 0; i < IFR; ++i) {
            int chunk = (wave * IFR + i) * 64;
            int row = (chunk >> 3) + srow;
            gl_lds16(A + (tm + row) * (size_t)lda + k0 + scol, As + (size_t)chunk * 8);
        }
        #pragma unroll
        for (int i = 0; i < 4; ++i) {
            int chunk = (wave * 4 + i) * 64;
            int row = (chunk >> 3) + srow;
            gl_lds16(Bt + (tn + row) * (size_t)ldb + k0 + scol, Bs + (size_t)chunk * 8);
        }
        __syncthreads();
        #pragma unroll
        for (int kk = 0; kk < 2; ++kk) {
            bf16x8 af[IFR], bfr[4];
            #pragma unroll
            for (int i = 0; i < IFR; ++i) {
                int row = wm + i * 16 + l16;
                af[i] = *(const bf16x8*)(const void*)&As[(row * 8 + ((kk*4 + quad) ^ swzA)) * 8];
            }
            #pragma unroll
            for (int j = 0; j < 4; ++j) {
                int row = wn + j * 16 + l16;
                bfr[j] = *(const bf16x8*)(const void*)&Bs[(row * 8 + ((kk*4 + quad) ^ swzA)) * 8];
            }
            #pragma unroll
            for (int i = 0; i < IFR; ++i)
                #pragma unroll
                for (int j = 0; j < 4; ++j)
                    acc[i][j] = __builtin_amdgcn_mfma_f32_16x16x32_bf16(
                        af[i], bfr[j], acc[i][j], 0, 0, 0);
        }
        __syncthreads();
    }

    float* Cf = (float*)C0;
    bf16*  Cb = (bf16*)C0;
    #pragma unroll
    for (int i = 0; i < IFR; ++i) {
        #pragma unroll
        for (int j = 0; j < 4; ++j) {
            size_t col = tn + wn + j*16 + l16;
            float bb = bias ? b2f(bias[col]) : 0.f;
            #pragma unroll
            for (int r = 0; r < 4; ++r) {
                size_t row = tm + wm + i*16 + quad*4 + r;
                float v = acc[i][j][r] + bb;
                size_t off = cbase + row * (size_t)ldc + col;
                if (EPI == 0) {
                    Cf[off] = v;
                } else if (EPI == 1) {
                    Cb[off] = f2b(v * scale);
                } else {
                    float g = 0.5f * v * (1.f + tanhf(0.7978845608028654f *
                                  (v + 0.044715f * v * v * v)));
                    Cb[off] = f2b(g);
                }
            }
        }
    }
}

// ---------------------------------------------------------------------------
// FF1 GEMM, 256x256 tile, BK=64, 8 waves, 8-phase-style pipelined schedule.
// C[M,N] = gelu(A[M,K] @ Bt[N,K]^T + bias), bf16 out.
// ---------------------------------------------------------------------------
__global__ __launch_bounds__(512, 2) void gemm_ff1_8ph(
    const bf16* __restrict__ A, int lda,
    const bf16* __restrict__ Bt, int ldb,
    bf16* __restrict__ C, int ldc,
    const bf16* __restrict__ bias, int K)
{
    __shared__ __align__(16) bf16 As[2][256 * 64];
    __shared__ __align__(16) bf16 Bs[2][256 * 64];
    const int tid  = threadIdx.x;
    const int lane = tid & 63, wave = tid >> 6;
    const int quad = lane >> 4, l16 = lane & 15;
    const int wr = wave >> 2, wc = wave & 3;          // 2M x 4N wave grid
    const size_t tm = (size_t)blockIdx.y * 256;
    const size_t tn = (size_t)blockIdx.x * 256;
    const int srow = lane >> 3;
    const int scol = ((lane & 7) ^ srow) * 8;         // pre-swizzled global col
    const int swz  = l16 & 7;                         // read-side swizzle

    f32x4 acc[8][4];
    const f32x4 zro = {0.f, 0.f, 0.f, 0.f};
    #pragma unroll
    for (int m = 0; m < 8; ++m)
        #pragma unroll
        for (int n = 0; n < 4; ++n) acc[m][n] = zro;

    const bf16* aSrc[4];
    const bf16* bSrc[4];
    #pragma unroll
    for (int i = 0; i < 4; ++i) {
        int grow = wave * 32 + i * 8 + srow;
        aSrc[i] = A  + (tm + grow) * (size_t)lda + scol;
        bSrc[i] = Bt + (tn + grow) * (size_t)ldb + scol;
    }

#define STAGE(BUF, K0, I)                                                     \
    do {                                                                      \
        gl_lds16(aSrc[I] + (K0), &As[BUF][(wave * 4 + (I)) * 512]);           \
        gl_lds16(bSrc[I] + (K0), &Bs[BUF][(wave * 4 + (I)) * 512]);           \
    } while (0)

#define LDA_F(BUF, M, KK)                                                     \
    (*(const bf16x8*)(const void*)&As[BUF][(wr * 128 + (M) * 16 + l16) * 64 + \
        ((((KK) * 4 + quad) ^ swz) << 3)])
#define LDB_F(BUF, N, KK)                                                     \
    (*(const bf16x8*)(const void*)&Bs[BUF][(wc * 64 + (N) * 16 + l16) * 64 +  \
        ((((KK) * 4 + quad) ^ swz) << 3)])

#define PHASE(M0, M1, PREF_STMT, TAIL_STMT)                                   \
    {                                                                         \
        PREF_STMT;                                                            \
        bf16x8 x0 = LDA_F(cur, M0, 0), x1 = LDA_F(cur, M0, 1);                \
        bf16x8 y0 = LDA_F(cur, M1, 0), y1 = LDA_F(cur, M1, 1);                \
        asm volatile("s_barrier" ::: "memory");                               \
        __builtin_amdgcn_s_setprio(1);                                        \
        _Pragma("unroll")                                                     \
        for (int n = 0; n < 4; ++n) {                                         \
            acc[M0][n] = __builtin_amdgcn_mfma_f32_16x16x32_bf16(x0, bfr[n][0], acc[M0][n], 0, 0, 0); \
            acc[M0][n] = __builtin_amdgcn_mfma_f32_16x16x32_bf16(x1, bfr[n][1], acc[M0][n], 0, 0, 0); \
            acc[M1][n] = __builtin_amdgcn_mfma_f32_16x16x32_bf16(y0, bfr[n][0], acc[M1][n], 0, 0, 0); \
            acc[M1][n] = __builtin_amdgcn_mfma_f32_16x16x32_bf16(y1, bfr[n][1], acc[M1][n], 0, 0, 0); \
        }                                                                     \
        __builtin_amdgcn_s_setprio(0);                                        \
        TAIL_STMT;                                                            \
        asm volatile("s_barrier" ::: "memory");                               \
    }

    #pragma unroll
    for (int i = 0; i < 4; ++i) STAGE(0, 0, i);
    asm volatile("s_waitcnt vmcnt(0)" ::: "memory");
    asm volatile("s_barrier" ::: "memory");

    const int NT = K >> 6;
    bf16x8 bfr[4][2];
    for (int t = 0; t < NT; ++t) {
        const int cur = t & 1, nxt = cur ^ 1;
        const int k1  = (t + 1) << 6;
        const bool pref = (t + 1 < NT);

        #pragma unroll
        for (int n = 0; n < 4; ++n) {
            bfr[n][0] = LDB_F(cur, n, 0);
            bfr[n][1] = LDB_F(cur, n, 1);
        }
        PHASE(0, 1,
              if (pref) { STAGE(nxt, k1, 0); STAGE(nxt, k1, 1); }, )
        PHASE(2, 3,
              if (pref) { STAGE(nxt, k1, 2); STAGE(nxt, k1, 3); }, )
        PHASE(4, 5, , )
        PHASE(6, 7, ,
              asm volatile("s_waitcnt vmcnt(0)" ::: "memory"))
    }
#undef PHASE
#undef LDB_F
#undef LDA_F
#undef STAGE

    // epilogue: bias + fast gelu (v * sigmoid(1.59577 v + 0.0713548 v^3))
    #pragma unroll
    for (int m = 0; m < 8; ++m) {
        #pragma unroll
        for (int n = 0; n < 4; ++n) {
            size_t col = tn + wc * 64 + n * 16 + l16;
            float bb = b2f(bias[col]);
            #pragma unroll
            for (int r = 0; r < 4; ++r) {
                size_t row = tm + wr * 128 + m * 16 + quad * 4 + r;
                float v = acc[m][n][r] + bb;
                float s = v * (1.5957691216057308f + 0.07135481627f * v * v);
                float g = v / (1.f + __expf(-s));
                C[row * (size_t)ldc + col] = f2b(g);
            }
        }
    }
}

// ---------------------------------------------------------------------------
// dtype-branching transpose for raw weight inputs -> bf16 transposed
// ---------------------------------------------------------------------------
__global__ void transpose_any(const void* __restrict__ in, int R, int C,
                              unsigned short* __restrict__ out, int ldo,
                              const int* __restrict__ flag)
{
    __shared__ unsigned short t[32][33];
    int f = *flag;
    int c0 = blockIdx.x * 32, r0 = blockIdx.y * 32;
    int tx = threadIdx.x, ty = threadIdx.y;
    for (int i = ty; i < 32; i += 8) {
        size_t idx = (size_t)(r0 + i) * C + c0 + tx;
        bf16 v = f ? f2b(((const float*)in)[idx]) : ((const bf16*)in)[idx];
        t[i][tx] = *(unsigned short*)&v;
    }
    __syncthreads();
    for (int i = ty; i < 32; i += 8)
        out[(size_t)(c0 + i) * ldo + r0 + tx] = t[tx][i];
}

// videoT [b][2048][1024] -> VTpad [b][1024][512 + 2048] (col offset 512), z=b
__global__ void transpose_vt(const unsigned short* __restrict__ in,
                             unsigned short* __restrict__ out)
{
    __shared__ unsigned short t[32][33];
    int b = blockIdx.z;
    const unsigned short* src = in + (size_t)b * 2048 * 1024;
    unsigned short* dst = out + (size_t)b * 1024 * 2560;
    int c0 = blockIdx.x * 32, r0 = blockIdx.y * 32;
    int tx = threadIdx.x, ty = threadIdx.y;
    for (int i = ty; i < 32; i += 8)
        t[i][tx] = src[(size_t)(r0 + i) * 1024 + c0 + tx];
    __syncthreads();
    for (int i = ty; i < 32; i += 8)
        dst[(size_t)(c0 + i) * 2560 + 512 + r0 + tx] = t[tx][i];
}

// ---------------------------------------------------------------------------
// V transpose into per-head Vt[bh][64][2048] bf16.
// ---------------------------------------------------------------------------
__global__ void transpose_v(const float* __restrict__ qkv, bf16* __restrict__ Vt)
{
    __shared__ float t[32][33];
    int bh = blockIdx.z, b = bh >> 3, h = bh & 7;
    const float* src = qkv + (size_t)b * 2048 * 1536 + 1024 + h * 64;
    int c0 = blockIdx.x * 32, r0 = blockIdx.y * 32;
    int tx = threadIdx.x, ty = threadIdx.y;
    for (int i = ty; i < 32; i += 8)
        t[i][tx] = src[(size_t)(r0 + i) * 1536 + c0 + tx];
    __syncthreads();
    bf16* dst = Vt + (size_t)bh * 64 * 2048;
    for (int i = ty; i < 32; i += 8)
        dst[(size_t)(c0 + i) * 2048 + r0 + tx] = f2b(t[tx][i]);
}

// ---------------------------------------------------------------------------
// Row LayerNorm: one block per row.
// ---------------------------------------------------------------------------
template <typename Tin>
__global__ __launch_bounds__(256) void ln_rows(
    const Tin* __restrict__ in, int C,
    const bf16* __restrict__ g, const bf16* __restrict__ b,
    bf16* __restrict__ out, float eps)
{
    const int row = blockIdx.x, tid = threadIdx.x;
    const Tin* p = in + (size_t)row * C;
    float s = 0.f, ss = 0.f;
    for (int c = tid; c < C; c += 256) {
        float v = ldval(p[c]);
        s += v; ss += v * v;
    }
    #pragma unroll
    for (int d = 32; d > 0; d >>= 1) { s += __shfl_xor(s, d); ss += __shfl_xor(ss, d); }
    __shared__ float red[2][4];
    int wave = tid >> 6, lane = tid & 63;
    if (lane == 0) { red[0][wave] = s; red[1][wave] = ss; }
    __syncthreads();
    s  = red[0][0] + red[0][1] + red[0][2] + red[0][3];
    ss = red[1][0] + red[1][1] + red[1][2] + red[1][3];
    float mu   = s / C;
    float var  = ss / C - mu * mu;
    float rstd = rsqrtf(var + eps);
    bf16* q = out + (size_t)row * C;
    for (int c = tid; c < C; c += 256) {
        float v = ldval(p[c]);
        q[c] = f2b((v - mu) * rstd * b2f(g[c]) + b2f(b[c]));
    }
}

// both adapter LNs in one launch: rows 0..4095 audio, 4096..8191 video. C=1024.
__global__ __launch_bounds__(256) void ln_rows2(
    const bf16* __restrict__ in,
    const bf16* __restrict__ g0, const bf16* __restrict__ b0,
    const bf16* __restrict__ g1, const bf16* __restrict__ b1,
    bf16* __restrict__ out0, bf16* __restrict__ out1)
{
    const int row = blockIdx.x, tid = threadIdx.x;
    const int sel = row >> 12;
    const bf16* p = in + (size_t)row * 1024;
    const bf16* g = sel ? g1 : g0;
    const bf16* b = sel ? b1 : b0;
    bf16* q = (sel ? out1 + (size_t)(row - 4096) * 1024 : out0 + (size_t)row * 1024);
    float s = 0.f, ss = 0.f;
    for (int c = tid; c < 1024; c += 256) {
        float v = b2f(p[c]);
        s += v; ss += v * v;
    }
    #pragma unroll
    for (int d = 32; d > 0; d >>= 1) { s += __shfl_xor(s, d); ss += __shfl_xor(ss, d); }
    __shared__ float red[2][4];
    int wave = tid >> 6, lane = tid & 63;
    if (lane == 0) { red[0][wave] = s; red[1][wave] = ss; }
    __syncthreads();
    s  = red[0][0] + red[0][1] + red[0][2] + red[0][3];
    ss = red[1][0] + red[1][1] + red[1][2] + red[1][3];
    float mu   = s * (1.f / 1024.f);
    float var  = ss * (1.f / 1024.f) - mu * mu;
    float rstd = rsqrtf(var + 1e-5f);
    for (int c = tid; c < 1024; c += 256) {
        float v = b2f(p[c]);
        q[c] = f2b((v - mu) * rstd * b2f(g[c]) + b2f(b[c]));
    }
}

// ---------------------------------------------------------------------------
// Rotary (reads raw text via flag): qrot = rope(text)*DIM^-0.5 ;
// krotPad[b][512+t] = rope(audio_t).
// ---------------------------------------------------------------------------
__global__ __launch_bounds__(256) void rotary_kernel(
    const void* __restrict__ text, const int* __restrict__ flag,
    const bf16* __restrict__ audioT,
    bf16* __restrict__ qrot, bf16* __restrict__ krotPad)
{
    int row = blockIdx.x;
    int t = row & 2047, b = row >> 11;
    int tid = threadIdx.x;
    int f = *flag;
    const float lg = 9.210340371976184f / 512.f;
    size_t base = (size_t)row * 1024;
    size_t kb = ((size_t)(b * 2560 + 512 + t)) * 1024;
    for (int c = tid; c < 512; c += 256) {
        float invf = __expf(-(float)c * lg);
        float th = (float)t * invf;
        float sn, cs;
        sincosf(th, &sn, &cs);
        float q1 = f ? ((const float*)text)[base + c]
                     : b2f(((const bf16*)text)[base + c]);
        float q2 = f ? ((const float*)text)[base + c + 512]
                     : b2f(((const bf16*)text)[base + c + 512]);
        qrot[base + c]       = f2b((q1 * cs - q2 * sn) * 0.03125f);
        qrot[base + c + 512] = f2b((q2 * cs + q1 * sn) * 0.03125f);
        float k1 = b2f(audioT[base + c]), k2 = b2f(audioT[base + c + 512]);
        krotPad[kb + c]       = f2b(k1 * cs - k2 * sn);
        krotPad[kb + c + 512] = f2b(k2 * cs + k1 * sn);
    }
}

// ---------------------------------------------------------------------------
// Local-attention masked softmax. sim [b][w][512][1024] f32 -> attn bf16.
// ---------------------------------------------------------------------------
__global__ __launch_bounds__(256) void softmax_local(
    const float* __restrict__ sim, bf16* __restrict__ attn)
{
    int i  = blockIdx.x;
    int zz = blockIdx.y;
    int w  = zz & 3;
    int tid = threadIdx.x;
    const float* p = sim + ((size_t)zz * 512 + i) * 1024;
    bf16* q = attn + ((size_t)zz * 512 + i) * 1024;
    int jlo = (w == 0) ? 512 : 0;
    int jhi = 512 + i;
    float m = -1e30f;
    #pragma unroll
    for (int k = 0; k < 4; ++k) {
        int c = tid + k * 256;
        if (c >= jlo && c <= jhi) m = fmaxf(m, p[c]);
    }
    #pragma unroll
    for (int d = 32; d > 0; d >>= 1) m = fmaxf(m, __shfl_xor(m, d));
    __shared__ float red[2][4];
    int wave = tid >> 6, lane = tid & 63;
    if (lane == 0) red[0][wave] = m;
    __syncthreads();
    m = fmaxf(fmaxf(red[0][0], red[0][1]), fmaxf(red[0][2], red[0][3]));
    float pv[4];
    float s = 0.f;
    #pragma unroll
    for (int k = 0; k < 4; ++k) {
        int c = tid + k * 256;
        float e = (c >= jlo && c <= jhi) ? __expf(p[c] - m) : 0.f;
        pv[k] = e; s += e;
    }
    #pragma unroll
    for (int d = 32; d > 0; d >>= 1) s += __shfl_xor(s, d);
    if (lane == 0) red[1][wave] = s;
    __syncthreads();
    s = red[1][0] + red[1][1] + red[1][2] + red[1][3];
    float inv = 1.f / s;
    #pragma unroll
    for (int k = 0; k < 4; ++k) q[tid + k * 256] = f2b(pv[k] * inv);
}

// ---------------------------------------------------------------------------
// pack_qk: RMSNorm q/k from qkv f32 [4096][1536] -> per-head bf16 buffers.
// ---------------------------------------------------------------------------
__global__ __launch_bounds__(256) void pack_qk(
    const float* __restrict__ qkv, bf16* __restrict__ Qp, bf16* __restrict__ Kp,
    const bf16* __restrict__ qn_g, const bf16* __restrict__ kn_g)
{
    int gid  = blockIdx.x * 4 + (threadIdx.x >> 6);
    int lane = threadIdx.x & 63;
    int token = gid >> 4, r = gid & 15, part = r >> 3, h = r & 7;
    const float* p = qkv + (size_t)token * 1536 + part * 512 + h * 64 + lane;
    float v = *p;
    float ss = v * v;
    #pragma unroll
    for (int d = 32; d > 0; d >>= 1) ss += __shfl_xor(ss, d);
    float sc = rsqrtf(ss * (1.f / 64.f) + 1e-6f);
    const bf16* gw = part ? kn_g : qn_g;
    float outv = v * sc * b2f(gw[lane]);
    if (!part) outv *= 0.125f;
    int b = token >> 11, t = token & 2047;
    bf16* dst = (part ? Kp : Qp) + ((size_t)(b * 8 + h) * 2048 + t) * 64 + lane;
    *dst = f2b(outv);
}

// ---------------------------------------------------------------------------
// Fused causal flash attention (D=64): fused3's proven single-buffered LDS
// staging + swapped-operand softmax, register-slim (no reg dbuf, no e[][],
// no union). 32 q-rows/block, 2 waves, grid (64,16), qb = 63-bx (LPT).
// QK^T = mfma(K, Q): lane's l16 = its q-row -> 16 key-scores in registers;
// reduction = in-reg tree + 2 overlapped shuffle-merge steps (vs 8 dependent
// shuffles in the row-parallel form). Math verified by R6 (passed, absmax ok).
// ---------------------------------------------------------------------------
__global__ __launch_bounds__(128) void flash_fused5(
    const bf16* __restrict__ Qp, const bf16* __restrict__ Kp,
    const bf16* __restrict__ Vt, bf16* __restrict__ o)
{
    __shared__ __align__(16) bf16 Ks[64][72];
    __shared__ __align__(16) bf16 Vs[64][72];
    __shared__ __align__(16) bf16 Ps[2][16][72];
    const int qb = 63 - blockIdx.x;
    const int bh = blockIdx.y, b = bh >> 3, h = bh & 7;
    const int qm = qb * 32;
    const int tid = threadIdx.x, wave = tid >> 6, lane = tid & 63;
    const int quad = lane >> 4, l16 = lane & 15;
    const bf16* Qg = Qp + (size_t)bh * 2048 * 64;
    const bf16* Kg = Kp + (size_t)bh * 2048 * 64;
    const bf16* Vg = Vt + (size_t)bh * 64 * 2048;

    // Q as B-operand: lane l16 -> q-row, quad -> d-chunk
    const int q_row = qm + wave * 16 + l16;
    bf16x8 qa[2];
    qa[0] = *(const bf16x8*)(const void*)(Qg + (size_t)q_row * 64 + quad * 8);
    qa[1] = *(const bf16x8*)(const void*)(Qg + (size_t)q_row * 64 + 32 + quad * 8);

    f32x4 oacc[4];
    const f32x4 zro = {0.f, 0.f, 0.f, 0.f};
    #pragma unroll
    for (int j = 0; j < 4; ++j) oacc[j] = zro;
    float mst = -1e30f, lst = 0.f;

    // staging: 128 threads, each covers half a 64-elem row (4 x 16B)
    const int ldr = tid >> 1, ldc = (tid & 1) * 32;
    const int nt = (qb >> 1) + 1;

    for (int t = 0; t < nt; ++t) {
        const int jt = t * 64;
        #pragma unroll
        for (int c = 0; c < 4; ++c) {
            *(uint4*)(void*)&Ks[ldr][ldc + c * 8] =
                *(const uint4*)(const void*)(Kg + (size_t)(jt + ldr) * 64 + ldc + c * 8);
            *(uint4*)(void*)&Vs[ldr][ldc + c * 8] =
                *(const uint4*)(const void*)(Vg + (size_t)ldr * 2048 + jt + ldc + c * 8);
        }
        __syncthreads();

        // ---- QK^T swapped: s[j][r] = score(key = jt + j*16 + quad*4 + r, q_row)
        f32x4 s[4];
        #pragma unroll
        for (int j = 0; j < 4; ++j) s[j] = zro;
        #pragma unroll
        for (int kk = 0; kk < 2; ++kk) {
            #pragma unroll
            for (int j = 0; j < 4; ++j) {
                bf16x8 kf = *(const bf16x8*)(const void*)&Ks[j*16 + l16][kk*32 + quad*8];
                s[j] = __builtin_amdgcn_mfma_f32_16x16x32_bf16(kf, qa[kk], s[j], 0, 0, 0);
            }
        }

        // causal mask
        if (jt + 63 > q_row) {
            #pragma unroll
            for (int j = 0; j < 4; ++j) {
                #pragma unroll
                for (int r = 0; r < 4; ++r) {
                    int key = jt + j * 16 + quad * 4 + r;
                    if (key > q_row) s[j][r] = -1e30f;
                }
            }
        }

        // per-lane (per-quad) local max, then in-place exp + sum
        float mq = s[0][0];
        #pragma unroll
        for (int j = 0; j < 4; ++j)
            #pragma unroll
            for (int r = 0; r < 4; ++r) mq = fmaxf(mq, s[j][r]);
        float sq = 0.f;
        #pragma unroll
        for (int j = 0; j < 4; ++j)
            #pragma unroll
            for (int r = 0; r < 4; ++r) {
                float v = __expf(s[j][r] - mq);
                s[j][r] = v; sq += v;
            }

        // merge (m, s) across the 4 quads of this q-row: two overlapped steps
        float mo = __shfl_xor(mq, 16);
        float so = __shfl_xor(sq, 16);
        float mm = fmaxf(mq, mo);
        sq = sq * __expf(mq - mm) + so * __expf(mo - mm);
        float mo2 = __shfl_xor(mm, 32);
        float so2 = __shfl_xor(sq, 32);
        float mtile = fmaxf(mm, mo2);
        float stile = sq * __expf(mm - mtile) + so2 * __expf(mo2 - mtile);

        // online update (uniform across the 4 quad-lanes of this q-row)
        float mn  = fmaxf(mst, mtile);
        float scl = __expf(mst - mn);
        lst = lst * scl + stile * __expf(mtile - mn);
        mst = mn;
        float pf = __expf(mq - mn);   // per-lane factor for its s[] values

        // rescale O (rows quad*4+r): fetch scl of those q-rows
        float sclq[4];
        #pragma unroll
        for (int r = 0; r < 4; ++r) sclq[r] = __shfl(scl, quad * 4 + r);
        #pragma unroll
        for (int j = 0; j < 4; ++j)
            #pragma unroll
            for (int r = 0; r < 4; ++r) oacc[j][r] *= sclq[r];

        // pack P = s*pf -> bf16 pairs, one uint2 LDS write per j
        #pragma unroll
        for (int j = 0; j < 4; ++j) {
            uint2 u;
            u.x = pk2(s[j][0] * pf, s[j][1] * pf);
            u.y = pk2(s[j][2] * pf, s[j][3] * pf);
            *(uint2*)(void*)&Ps[wave][l16][j * 16 + quad * 4] = u;
        }
        bf16x8 pa0 = *(const bf16x8*)(const void*)&Ps[wave][l16][quad * 8];
        bf16x8 pa1 = *(const bf16x8*)(const void*)&Ps[wave][l16][32 + quad * 8];

        // PV (same fragments as fused3)
        #pragma unroll
        for (int j = 0; j < 4; ++j) {
            bf16x8 vb = *(const bf16x8*)(const void*)&Vs[j*16 + l16][quad*8];
            oacc[j] = __builtin_amdgcn_mfma_f32_16x16x32_bf16(pa0, vb, oacc[j], 0, 0, 0);
        }
        #pragma unroll
        for (int j = 0; j < 4; ++j) {
            bf16x8 vb = *(const bf16x8*)(const void*)&Vs[j*16 + l16][32 + quad*8];
            oacc[j] = __builtin_amdgcn_mfma_f32_16x16x32_bf16(pa1, vb, oacc[j], 0, 0, 0);
        }
        __syncthreads();
    }

    float invq[4];
    #pragma unroll
    for (int r = 0; r < 4; ++r) invq[r] = 1.f / __shfl(lst, quad * 4 + r);
    #pragma unroll
    for (int j = 0; j < 4; ++j) {
        #pragma unroll
        for (int r = 0; r < 4; ++r) {
            int tr = qm + wave * 16 + quad * 4 + r;
            o[((size_t)(b * 2048 + tr)) * 512 + h * 64 + j * 16 + l16] =
                f2b(oacc[j][r] * invq[r]);
        }
    }
}

// ---------------------------------------------------------------------------
// FF2 split-K merge + bias + residual: out f32 = p0+p1+b2+x2. 4M elements.
// ---------------------------------------------------------------------------
__global__ __launch_bounds__(256) void combine_ff2(
    const float* __restrict__ p0, const float* __restrict__ p1,
    const bf16* __restrict__ x2, const bf16* __restrict__ b2,
    float* __restrict__ out)
{
    int i4 = (blockIdx.x * 256 + threadIdx.x) * 4;
    #pragma unroll
    for (int k = 0; k < 4; ++k) {
        int i = i4 + k;
        out[i] = p0[i] + p1[i] + b2f(x2[i]) + b2f(b2[i & 1023]);
    }
}

// ---------------------------------------------------------------------------
static void launch_gemm(int epi, hipStream_t s,
                        const bf16* A, int lda, int zsA, int zsA2,
                        const bf16* Bt, int ldb, int zsB, int zsB2,
                        void* C, int ldc, int zsC, int zsC2,
                        const bf16* bias, int zsBias, float scale,
                        int M, int N, int K, int nz)
{
    bool mt64 = ((M >> 7) * (N >> 7) * nz) <= 512;
    dim3 blk(256);
    if (mt64) {
        dim3 g(N / 128, M / 64, nz);
        switch (epi) {
        case 0: gemm_bt<0,64><<<g, blk, 0, s>>>(A, lda, zsA, zsA2, Bt, ldb, zsB, zsB2, C, ldc, zsC, zsC2, bias, zsBias, scale, K); break;
        case 1: gemm_bt<1,64><<<g, blk, 0, s>>>(A, lda, zsA, zsA2, Bt, ldb, zsB, zsB2, C, ldc, zsC, zsC2, bias, zsBias, scale, K); break;
        default: gemm_bt<2,64><<<g, blk, 0, s>>>(A, lda, zsA, zsA2, Bt, ldb, zsB, zsB2, C, ldc, zsC, zsC2, bias, zsBias, scale, K); break;
        }
    } else {
        dim3 g(N / 128, M / 128, nz);
        switch (epi) {
        case 0: gemm_bt<0,128><<<g, blk, 0, s>>>(A, lda, zsA, zsA2, Bt, ldb, zsB, zsB2, C, ldc, zsC, zsC2, bias, zsBias, scale, K); break;
        case 1: gemm_bt<1,128><<<g, blk, 0, s>>>(A, lda, zsA, zsA2, Bt, ldb, zsB, zsB2, C, ldc, zsC, zsC2, bias, zsBias, scale, K); break;
        default: gemm_bt<2,128><<<g, blk, 0, s>>>(A, lda, zsA, zsA2, Bt, ldb, zsB, zsB2, C, ldc, zsC, zsC2, bias, zsBias, scale, K); break;
        }
    }
}

extern "C" void kernel_launch(void* const* d_in, const int* in_sizes, int n_in,
                              void* d_out, int out_size, void* d_ws, size_t ws_size,
                              hipStream_t stream)
{
    const void* text  = d_in[0];
    const void* audio = d_in[1];
    const void* video = d_in[2];
    const void* Wa    = d_in[3];
    const void* ba    = d_in[4];
    const void* lna_g = d_in[5];
    const void* lna_b = d_in[6];
    const void* Wvid  = d_in[7];
    const void* bvid  = d_in[8];
    const void* lnv_g = d_in[9];
    const void* lnv_b = d_in[10];
    const void* ln1_g = d_in[11];
    const void* ln1_b = d_in[12];
    const void* Wq    = d_in[13];
    const void* Wkv   = d_in[14];
    const void* qn_g  = d_in[15];
    const void* kn_g  = d_in[16];
    const void* Wo    = d_in[17];
    const void* W1    = d_in[18];
    const void* b1    = d_in[19];
    const void* ln2_g = d_in[20];
    const void* ln2_b = d_in[21];
    const void* W2    = d_in[22];
    const void* b2    = d_in[23];

    char* ws = (char*)d_ws;
    size_t off = 0;
    auto alloc = [&](size_t bytes) -> char* {
        char* p = ws + off;
        off += (bytes + 255) & ~(size_t)255;
        return p;
    };
    const size_t MB = 1024 * 1024;
    int*  flag  = (int*)alloc(256);
    bf16* vecs  = (bf16*)alloc(14 * 4096 * 2);
    bf16* WqkvT = (bf16*)alloc((size_t)1536 * 1024 * 2);
    bf16* WoT   = (bf16*)alloc((size_t)1024 * 512 * 2);
    bf16* W1T   = (bf16*)alloc((size_t)4096 * 1024 * 2);
    bf16* W2T   = (bf16*)alloc((size_t)1024 * 4096 * 2);
    char* regionIn = alloc(24 * MB);   // audioC,videoC -> qkvF -> p0
    char* region2  = alloc(32 * MB);   // tmp2/tmpF/xF -> g
    char* regionH  = alloc(8 * MB);    // audioT -> h
    char* regionX  = alloc(8 * MB);    // videoT -> x2
    char* regionO  = alloc(4 * MB);    // WaT,WvT -> o
    bf16* qrot    = (bf16*)alloc((size_t)4096 * 1024 * 2);
    bf16* krotPad = (bf16*)alloc((size_t)2 * 2560 * 1024 * 2);
    bf16* VTpad   = (bf16*)alloc((size_t)2 * 1024 * 2560 * 2);
    bf16* attn    = (bf16*)alloc((size_t)8 * 512 * 1024 * 2);

    bf16*  audioC = (bf16*)regionIn;
    bf16*  videoC = audioC + (size_t)4096 * 1024;
    float* qkvF   = (float*)regionIn;
    bf16*  tmp2   = (bf16*)region2;          // adapter GEMM out (2 x 4096x1024 bf16)
    float* tmpF   = (float*)region2;         // sim scores f32
    float* xF     = (float*)(region2 + 16 * MB);
    bf16*  g      = (bf16*)region2;
    bf16*  audioT = (bf16*)regionH;
    bf16*  h      = (bf16*)regionH;
    bf16*  videoT = (bf16*)regionX;
    bf16*  x2     = (bf16*)regionX;
    bf16*  WaT    = (bf16*)regionO;
    bf16*  WvT    = WaT + (size_t)1024 * 1024;
    bf16*  o      = (bf16*)regionO;
    bf16*  Qp     = qrot;
    bf16*  Kp     = krotPad;
    bf16*  Vth    = attn;
    // FF2 split-K partials (dead regions at FF2 time)
    float* p0     = (float*)regionIn;        // 16 MB of 24
    float* p1     = (float*)VTpad;           // VTpad+attn contiguous 18 MB

    bf16* baC   = vecs + 0 * 4096;
    bf16* bvidC = vecs + 1 * 4096;
    bf16* lnagC = vecs + 2 * 4096;
    bf16* lnabC = vecs + 3 * 4096;
    bf16* lnvgC = vecs + 4 * 4096;
    bf16* lnvbC = vecs + 5 * 4096;
    bf16* ln1gC = vecs + 6 * 4096;
    bf16* ln1bC = vecs + 7 * 4096;
    bf16* qngC  = vecs + 8 * 4096;
    bf16* kngC  = vecs + 9 * 4096;
    bf16* b1C   = vecs + 10 * 4096;
    bf16* ln2gC = vecs + 11 * 4096;
    bf16* ln2bC = vecs + 12 * 4096;
    bf16* b2C   = vecs + 13 * 4096;

    // 1) dtype flag
    detect_dtype<<<1, 64, 0, stream>>>((const unsigned short*)text, flag);

    // 2) canonicalize audio+video (one launch) + small vectors
    const int NTOK = 4096 * 1024;
    convert2<<<4096, 256, 0, stream>>>(audio, video, audioC, videoC, NTOK, flag);
    VecPack vp;
    const void* vsrc[14] = {ba, bvid, lna_g, lna_b, lnv_g, lnv_b, ln1_g, ln1_b,
                            qn_g, kn_g, b1, ln2_g, ln2_b, b2};
    int vn[14] = {1024, 1024, 1024, 1024, 1024, 1024, 1024, 1024,
                  64, 64, 4096, 4096, 4096, 1024};
    for (int i = 0; i < 14; ++i) { vp.src[i] = vsrc[i]; vp.n[i] = vn[i]; }
    convert_vecs<<<14, 256, 0, stream>>>(vp, vecs, flag);

    // 3) weight transposes
    dim3 tb(32, 8);
    transpose_any<<<dim3(32, 32), tb, 0, stream>>>(Wa, 1024, 1024, (unsigned short*)WaT, 1024, flag);
    transpose_any<<<dim3(32, 32), tb, 0, stream>>>(Wvid, 1024, 1024, (unsigned short*)WvT, 1024, flag);
    transpose_any<<<dim3(16, 32), tb, 0, stream>>>(Wq, 1024, 512, (unsigned short*)WqkvT, 1024, flag);
    transpose_any<<<dim3(32, 32), tb, 0, stream>>>(Wkv, 1024, 1024, (unsigned short*)(WqkvT + (size_t)512 * 1024), 1024, flag);
    transpose_any<<<dim3(32, 16), tb, 0, stream>>>(Wo, 512, 1024, (unsigned short*)WoT, 512, flag);
    transpose_any<<<dim3(128, 32), tb, 0, stream>>>(W1, 1024, 4096, (unsigned short*)W1T, 1024, flag);
    transpose_any<<<dim3(32, 128), tb, 0, stream>>>(W2, 4096, 1024, (unsigned short*)W2T, 4096, flag);

    // 4) adapters: one batched GEMM (nz=2, bf16 out w/ bias) + merged LN
    launch_gemm(1, stream, audioC, 1024, 4096*1024, 0, WaT, 1024, 1024*1024, 0,
                tmp2, 1024, 4096*1024, 0, baC, 4096, 1.f, 4096, 1024, 1024, 2);
    ln_rows2<<<8192, 256, 0, stream>>>(tmp2, lnagC, lnabC, lnvgC, lnvbC, audioT, videoT);

    // 5) pads, rotary (raw text), batched VTpad transpose
    hipMemsetAsync(krotPad, 0, (size_t)2 * 2560 * 1024 * 2, stream);
    hipMemsetAsync(VTpad, 0, (size_t)2 * 1024 * 2560 * 2, stream);
    rotary_kernel<<<4096, 256, 0, stream>>>(text, flag, audioT, qrot, krotPad);
    transpose_vt<<<dim3(32, 64, 2), tb, 0, stream>>>(
        (const unsigned short*)videoT, (unsigned short*)VTpad);

    // 6) local attention: batched sim (nz=8) -> softmax -> batched @V (nz=8)
    launch_gemm(0, stream, qrot, 1024, 512*1024, 0,
                krotPad, 1024, 512*1024, 512*1024,
                tmpF, 1024, 512*1024, 0, nullptr, 0, 1.f, 512, 1024, 1024, 8);
    softmax_local<<<dim3(512, 8), 256, 0, stream>>>(tmpF, attn);
    launch_gemm(0, stream, attn, 1024, 512*1024, 0,
                VTpad, 2560, 512, 1024*2560 - 2048,
                xF, 1024, 512*1024, 0, nullptr, 0, 1.f, 512, 1024, 1024, 8);

    // 7) ln1 -> qkv -> pack -> V transpose -> swapped-softmax fused flash
    ln_rows<float><<<4096, 256, 0, stream>>>(xF, 1024, ln1gC, ln1bC, h, 1e-5f);
    launch_gemm(0, stream, h, 1024, 0, 0, WqkvT, 1024, 0, 0,
                qkvF, 1536, 0, 0, nullptr, 0, 1.f, 4096, 1536, 1024, 1);
    pack_qk<<<16384, 256, 0, stream>>>(qkvF, Qp, Kp, qngC, kngC);
    transpose_v<<<dim3(2, 64, 16), tb, 0, stream>>>(qkvF, Vth);
    flash_fused5<<<dim3(64, 16), 128, 0, stream>>>(Qp, Kp, Vth, o);

    // 8) x2 = 2*(o@Wo) ; g = gelu(x2@W1+b1) via 8-phase 256^2 ; ln2 ; FF2
    launch_gemm(1, stream, o, 512, 0, 0, WoT, 512, 0, 0,
                x2, 1024, 0, 0, nullptr, 0, 2.f, 4096, 1024, 512, 1);
    gemm_ff1_8ph<<<dim3(16, 16), 512, 0, stream>>>(x2, 1024, W1T, 1024,
                                                   g, 4096, b1C, 1024);
    ln_rows<bf16><<<4096, 256, 0, stream>>>(g, 4096, ln2gC, ln2bC, g, 1e-5f);
    launch_gemm(0, stream, g, 4096, 2048, 0, W2T, 4096, 2048, 0,
                p0, 1024, (int)(p1 - p0), 0, nullptr, 0, 1.f, 4096, 1024, 2048, 2);
    combine_ff2<<<4096, 256, 0, stream>>>(p0, p1, x2, b2C, (float*)d_out);

    (void)in_sizes; (void)n_in; (void)out_size; (void)ws_size;
}

// Round 8
// 565.669 us; speedup vs baseline: 1.1480x; 1.0066x over previous
//
#include <hip/hip_runtime.h>
#include <hip/hip_bf16.h>

typedef __bf16 bf16;
typedef __bf16 bf16x8 __attribute__((ext_vector_type(8)));
typedef float  f32x4  __attribute__((ext_vector_type(4)));

static __device__ __forceinline__ float b2f(bf16 x) { return (float)x; }
static __device__ __forceinline__ bf16  f2b(float x) { return (bf16)x; }
static __device__ __forceinline__ float ldval(float v) { return v; }
static __device__ __forceinline__ float ldval(bf16 v)  { return (float)v; }

// pack two floats -> one uint holding two bf16 (low = a, high = b)
static __device__ __forceinline__ unsigned pk2(float a, float b)
{
    bf16 x = f2b(a), y = f2b(b);
    unsigned short ux = *(unsigned short*)&x;
    unsigned short uy = *(unsigned short*)&y;
    return (unsigned)ux | ((unsigned)uy << 16);
}

// async global->LDS, 16B per lane; lds dest is wave-uniform base (+lane*16)
static __device__ __forceinline__ void gl_lds16(const bf16* g, bf16* l)
{
    __builtin_amdgcn_global_load_lds(
        (const __attribute__((address_space(1))) void*)g,
        (__attribute__((address_space(3))) void*)l,
        16, 0, 0);
}

// ---------------------------------------------------------------------------
// dtype detection: flag=1 -> f32 inputs.
// ---------------------------------------------------------------------------
__global__ void detect_dtype(const unsigned short* __restrict__ p, int* __restrict__ flag)
{
    if (threadIdx.x == 0 && blockIdx.x == 0) {
        int big = 0;
        for (int i = 0; i < 512; ++i) {
            int e = (p[i] >> 7) & 0xFF;
            if (e >= 0xE0) big++;
        }
        *flag = (big > 0) ? 1 : 0;
    }
}

// convert two tensors in one launch (grid split in half)
__global__ __launch_bounds__(256) void convert2(
    const void* __restrict__ sa, const void* __restrict__ sb,
    bf16* __restrict__ da, bf16* __restrict__ db, int n,
    const int* __restrict__ flag)
{
    int f = *flag;
    int half = gridDim.x >> 1;
    const void* s = (blockIdx.x < half) ? sa : sb;
    bf16* d = (blockIdx.x < half) ? da : db;
    int bid = (blockIdx.x < half) ? blockIdx.x : blockIdx.x - half;
    for (int i = bid * 256 + threadIdx.x; i < n; i += half * 256) {
        float v = f ? ((const float*)s)[i] : (float)((const bf16*)s)[i];
        d[i] = f2b(v);
    }
}

struct VecPack { const void* src[14]; int n[14]; };
__global__ __launch_bounds__(256) void convert_vecs(
    VecPack vp, bf16* __restrict__ dst, const int* __restrict__ flag)
{
    int v = blockIdx.x;
    int f = *flag;
    const void* s = vp.src[v];
    int n = vp.n[v];
    bf16* d = dst + (size_t)v * 4096;
    for (int i = threadIdx.x; i < n; i += 256) {
        float x = f ? ((const float*)s)[i] : (float)((const bf16*)s)[i];
        d[i] = f2b(x);
    }
}

// ---------------------------------------------------------------------------
// GEMM: C[M,N] = A[M,K] @ Bt[n][k]. MT x 128 tile, BK=64, 4 waves.
// ---------------------------------------------------------------------------
template <int EPI, int MT>
__global__ __launch_bounds__(256) void gemm_bt(
    const bf16* __restrict__ A0, int lda, int zsA, int zsA2,
    const bf16* __restrict__ B0, int ldb, int zsB, int zsB2,
    void* __restrict__ C0, int ldc, int zsC, int zsC2,
    const bf16* __restrict__ bias, int zsBias, float scale, int K)
{
    constexpr int IFR = MT / 32;
    __shared__ __align__(16) bf16 As[MT * 64];
    __shared__ __align__(16) bf16 Bs[128 * 64];
    const int z = blockIdx.z;
    const bf16* A  = A0 + (size_t)z * zsA + (size_t)(z >> 2) * zsA2;
    const bf16* Bt = B0 + (size_t)z * zsB + (size_t)(z >> 2) * zsB2;
    const size_t cbase = (size_t)z * zsC + (size_t)(z >> 2) * zsC2;
    if (bias) bias += (size_t)z * zsBias;
    const int tid  = threadIdx.x;
    const int lane = tid & 63, wave = tid >> 6;
    const int quad = lane >> 4, l16 = lane & 15;
    const size_t tm = (size_t)blockIdx.y * MT, tn = (size_t)blockIdx.x * 128;
    const int wm = (wave >> 1) * (MT / 2), wn = (wave & 1) * 64;
    const int srow = lane >> 3;
    const int scol = ((lane & 7) ^ srow) * 8;

    f32x4 acc[IFR][4];
    const f32x4 zro = {0.f, 0.f, 0.f, 0.f};
    #pragma unroll
    for (int i = 0; i < IFR; ++i)
        #pragma unroll
        for (int j = 0; j < 4; ++j) acc[i][j] = zro;

    const int swzA = l16 & 7;
    for (int k0 = 0; k0 < K; k0 += 64) {
        #pragma unroll
        for (int i = 0; i < IFR; ++i) {
            int chunk = (wave * IFR + i) * 64;
            int row = (chunk >> 3) + srow;
            gl_lds16(A + (tm + row) * (size_t)lda + k0 + scol, As + (size_t)chunk * 8);
        }
        #pragma unroll
        for (int i = 0; i < 4; ++i) {
            int chunk = (wave * 4 + i) * 64;
            int row = (chunk >> 3) + srow;
            gl_lds16(Bt + (tn + row) * (size_t)ldb + k0 + scol, Bs + (size_t)chunk * 8);
        }
        __syncthreads();
        #pragma unroll
        for (int kk = 0; kk < 2; ++kk) {
            bf16x8 af[IFR], bfr[4];
            #pragma unroll
            for (int i = 0; i < IFR; ++i) {
                int row = wm + i * 16 + l16;
                af[i] = *(const bf16x8*)(const void*)&As[(row * 8 + ((kk*4 + quad) ^ swzA)) * 8];
            }
            #pragma unroll
            for (int j = 0; j < 4; ++j) {
                int row = wn + j * 16 + l16;
                bfr[j] = *(const bf16x8*)(const void*)&Bs[(row * 8 + ((kk*4 + quad) ^ swzA)) * 8];
            }
            #pragma unroll
            for (int i = 0; i < IFR; ++i)
                #pragma unroll
                for (int j = 0; j < 4; ++j)
                    acc[i][j] = __builtin_amdgcn_mfma_f32_16x16x32_bf16(
                        af[i], bfr[j], acc[i][j], 0, 0, 0);
        }
        __syncthreads();
    }

    float* Cf = (float*)C0;
    bf16*  Cb = (bf16*)C0;
    #pragma unroll
    for (int i = 0; i < IFR; ++i) {
        #pragma unroll
        for (int j = 0; j < 4; ++j) {
            size_t col = tn + wn + j*16 + l16;
            float bb = bias ? b2f(bias[col]) : 0.f;
            #pragma unroll
            for (int r = 0; r < 4; ++r) {
                size_t row = tm + wm + i*16 + quad*4 + r;
                float v = acc[i][j][r] + bb;
                size_t off = cbase + row * (size_t)ldc + col;
                if (EPI == 0) {
                    Cf[off] = v;
                } else if (EPI == 1) {
                    Cb[off] = f2b(v * scale);
                } else {
                    float g = 0.5f * v * (1.f + tanhf(0.7978845608028654f *
                                  (v + 0.044715f * v * v * v)));
                    Cb[off] = f2b(g);
                }
            }
        }
    }
}

// ---------------------------------------------------------------------------
// FF1 GEMM, 256x256 tile, BK=64, 8 waves, 8-phase-style pipelined schedule.
// C[M,N] = gelu(A[M,K] @ Bt[N,K]^T + bias), bf16 out.
// ---------------------------------------------------------------------------
__global__ __launch_bounds__(512, 2) void gemm_ff1_8ph(
    const bf16* __restrict__ A, int lda,
    const bf16* __restrict__ Bt, int ldb,
    bf16* __restrict__ C, int ldc,
    const bf16* __restrict__ bias, int K)
{
    __shared__ __align__(16) bf16 As[2][256 * 64];
    __shared__ __align__(16) bf16 Bs[2][256 * 64];
    const int tid  = threadIdx.x;
    const int lane = tid & 63, wave = tid >> 6;
    const int quad = lane >> 4, l16 = lane & 15;
    const int wr = wave >> 2, wc = wave & 3;          // 2M x 4N wave grid
    const size_t tm = (size_t)blockIdx.y * 256;
    const size_t tn = (size_t)blockIdx.x * 256;
    const int srow = lane >> 3;
    const int scol = ((lane & 7) ^ srow) * 8;         // pre-swizzled global col
    const int swz  = l16 & 7;                         // read-side swizzle

    f32x4 acc[8][4];
    const f32x4 zro = {0.f, 0.f, 0.f, 0.f};
    #pragma unroll
    for (int m = 0; m < 8; ++m)
        #pragma unroll
        for (int n = 0; n < 4; ++n) acc[m][n] = zro;

    const bf16* aSrc[4];
    const bf16* bSrc[4];
    #pragma unroll
    for (int i = 0; i < 4; ++i) {
        int grow = wave * 32 + i * 8 + srow;
        aSrc[i] = A  + (tm + grow) * (size_t)lda + scol;
        bSrc[i] = Bt + (tn + grow) * (size_t)ldb + scol;
    }

#define STAGE(BUF, K0, I)                                                     \
    do {                                                                      \
        gl_lds16(aSrc[I] + (K0), &As[BUF][(wave * 4 + (I)) * 512]);           \
        gl_lds16(bSrc[I] + (K0), &Bs[BUF][(wave * 4 + (I)) * 512]);           \
    } while (0)

#define LDA_F(BUF, M, KK)                                                     \
    (*(const bf16x8*)(const void*)&As[BUF][(wr * 128 + (M) * 16 + l16) * 64 + \
        ((((KK) * 4 + quad) ^ swz) << 3)])
#define LDB_F(BUF, N, KK)                                                     \
    (*(const bf16x8*)(const void*)&Bs[BUF][(wc * 64 + (N) * 16 + l16) * 64 +  \
        ((((KK) * 4 + quad) ^ swz) << 3)])

#define PHASE(M0, M1, PREF_STMT, TAIL_STMT)                                   \
    {                                                                         \
        PREF_STMT;                                                            \
        bf16x8 x0 = LDA_F(cur, M0, 0), x1 = LDA_F(cur, M0, 1);                \
        bf16x8 y0 = LDA_F(cur, M1, 0), y1 = LDA_F(cur, M1, 1);                \
        asm volatile("s_barrier" ::: "memory");                               \
        __builtin_amdgcn_s_setprio(1);                                        \
        _Pragma("unroll")                                                     \
        for (int n = 0; n < 4; ++n) {                                         \
            acc[M0][n] = __builtin_amdgcn_mfma_f32_16x16x32_bf16(x0, bfr[n][0], acc[M0][n], 0, 0, 0); \
            acc[M0][n] = __builtin_amdgcn_mfma_f32_16x16x32_bf16(x1, bfr[n][1], acc[M0][n], 0, 0, 0); \
            acc[M1][n] = __builtin_amdgcn_mfma_f32_16x16x32_bf16(y0, bfr[n][0], acc[M1][n], 0, 0, 0); \
            acc[M1][n] = __builtin_amdgcn_mfma_f32_16x16x32_bf16(y1, bfr[n][1], acc[M1][n], 0, 0, 0); \
        }                                                                     \
        __builtin_amdgcn_s_setprio(0);                                        \
        TAIL_STMT;                                                            \
        asm volatile("s_barrier" ::: "memory");                               \
    }

    #pragma unroll
    for (int i = 0; i < 4; ++i) STAGE(0, 0, i);
    asm volatile("s_waitcnt vmcnt(0)" ::: "memory");
    asm volatile("s_barrier" ::: "memory");

    const int NT = K >> 6;
    bf16x8 bfr[4][2];
    for (int t = 0; t < NT; ++t) {
        const int cur = t & 1, nxt = cur ^ 1;
        const int k1  = (t + 1) << 6;
        const bool pref = (t + 1 < NT);

        #pragma unroll
        for (int n = 0; n < 4; ++n) {
            bfr[n][0] = LDB_F(cur, n, 0);
            bfr[n][1] = LDB_F(cur, n, 1);
        }
        PHASE(0, 1,
              if (pref) { STAGE(nxt, k1, 0); STAGE(nxt, k1, 1); }, )
        PHASE(2, 3,
              if (pref) { STAGE(nxt, k1, 2); STAGE(nxt, k1, 3); }, )
        PHASE(4, 5, , )
        PHASE(6, 7, ,
              asm volatile("s_waitcnt vmcnt(0)" ::: "memory"))
    }
#undef PHASE
#undef LDB_F
#undef LDA_F
#undef STAGE

    // epilogue: bias + fast gelu (v * sigmoid(1.59577 v + 0.0713548 v^3))
    #pragma unroll
    for (int m = 0; m < 8; ++m) {
        #pragma unroll
        for (int n = 0; n < 4; ++n) {
            size_t col = tn + wc * 64 + n * 16 + l16;
            float bb = b2f(bias[col]);
            #pragma unroll
            for (int r = 0; r < 4; ++r) {
                size_t row = tm + wr * 128 + m * 16 + quad * 4 + r;
                float v = acc[m][n][r] + bb;
                float s = v * (1.5957691216057308f + 0.07135481627f * v * v);
                float g = v / (1.f + __expf(-s));
                C[row * (size_t)ldc + col] = f2b(g);
            }
        }
    }
}

// ---------------------------------------------------------------------------
// dtype-branching transpose for raw weight inputs -> bf16 transposed
// ---------------------------------------------------------------------------
__global__ void transpose_any(const void* __restrict__ in, int R, int C,
                              unsigned short* __restrict__ out, int ldo,
                              const int* __restrict__ flag)
{
    __shared__ unsigned short t[32][33];
    int f = *flag;
    int c0 = blockIdx.x * 32, r0 = blockIdx.y * 32;
    int tx = threadIdx.x, ty = threadIdx.y;
    for (int i = ty; i < 32; i += 8) {
        size_t idx = (size_t)(r0 + i) * C + c0 + tx;
        bf16 v = f ? f2b(((const float*)in)[idx]) : ((const bf16*)in)[idx];
        t[i][tx] = *(unsigned short*)&v;
    }
    __syncthreads();
    for (int i = ty; i < 32; i += 8)
        out[(size_t)(c0 + i) * ldo + r0 + tx] = t[tx][i];
}

// videoT [b][2048][1024] -> VTpad [b][1024][512 + 2048] (col offset 512), z=b
__global__ void transpose_vt(const unsigned short* __restrict__ in,
                             unsigned short* __restrict__ out)
{
    __shared__ unsigned short t[32][33];
    int b = blockIdx.z;
    const unsigned short* src = in + (size_t)b * 2048 * 1024;
    unsigned short* dst = out + (size_t)b * 1024 * 2560;
    int c0 = blockIdx.x * 32, r0 = blockIdx.y * 32;
    int tx = threadIdx.x, ty = threadIdx.y;
    for (int i = ty; i < 32; i += 8)
        t[i][tx] = src[(size_t)(r0 + i) * 1024 + c0 + tx];
    __syncthreads();
    for (int i = ty; i < 32; i += 8)
        dst[(size_t)(c0 + i) * 2560 + 512 + r0 + tx] = t[tx][i];
}

// ---------------------------------------------------------------------------
// V transpose into per-head Vt[bh][64][2048] bf16.
// ---------------------------------------------------------------------------
__global__ void transpose_v(const float* __restrict__ qkv, bf16* __restrict__ Vt)
{
    __shared__ float t[32][33];
    int bh = blockIdx.z, b = bh >> 3, h = bh & 7;
    const float* src = qkv + (size_t)b * 2048 * 1536 + 1024 + h * 64;
    int c0 = blockIdx.x * 32, r0 = blockIdx.y * 32;
    int tx = threadIdx.x, ty = threadIdx.y;
    for (int i = ty; i < 32; i += 8)
        t[i][tx] = src[(size_t)(r0 + i) * 1536 + c0 + tx];
    __syncthreads();
    bf16* dst = Vt + (size_t)bh * 64 * 2048;
    for (int i = ty; i < 32; i += 8)
        dst[(size_t)(c0 + i) * 2048 + r0 + tx] = f2b(t[tx][i]);
}

// ---------------------------------------------------------------------------
// Row LayerNorm: one block per row.
// ---------------------------------------------------------------------------
template <typename Tin>
__global__ __launch_bounds__(256) void ln_rows(
    const Tin* __restrict__ in, int C,
    const bf16* __restrict__ g, const bf16* __restrict__ b,
    bf16* __restrict__ out, float eps)
{
    const int row = blockIdx.x, tid = threadIdx.x;
    const Tin* p = in + (size_t)row * C;
    float s = 0.f, ss = 0.f;
    for (int c = tid; c < C; c += 256) {
        float v = ldval(p[c]);
        s += v; ss += v * v;
    }
    #pragma unroll
    for (int d = 32; d > 0; d >>= 1) { s += __shfl_xor(s, d); ss += __shfl_xor(ss, d); }
    __shared__ float red[2][4];
    int wave = tid >> 6, lane = tid & 63;
    if (lane == 0) { red[0][wave] = s; red[1][wave] = ss; }
    __syncthreads();
    s  = red[0][0] + red[0][1] + red[0][2] + red[0][3];
    ss = red[1][0] + red[1][1] + red[1][2] + red[1][3];
    float mu   = s / C;
    float var  = ss / C - mu * mu;
    float rstd = rsqrtf(var + eps);
    bf16* q = out + (size_t)row * C;
    for (int c = tid; c < C; c += 256) {
        float v = ldval(p[c]);
        q[c] = f2b((v - mu) * rstd * b2f(g[c]) + b2f(b[c]));
    }
}

// both adapter LNs in one launch: rows 0..4095 audio, 4096..8191 video. C=1024.
__global__ __launch_bounds__(256) void ln_rows2(
    const bf16* __restrict__ in,
    const bf16* __restrict__ g0, const bf16* __restrict__ b0,
    const bf16* __restrict__ g1, const bf16* __restrict__ b1,
    bf16* __restrict__ out0, bf16* __restrict__ out1)
{
    const int row = blockIdx.x, tid = threadIdx.x;
    const int sel = row >> 12;
    const bf16* p = in + (size_t)row * 1024;
    const bf16* g = sel ? g1 : g0;
    const bf16* b = sel ? b1 : b0;
    bf16* q = (sel ? out1 + (size_t)(row - 4096) * 1024 : out0 + (size_t)row * 1024);
    float s = 0.f, ss = 0.f;
    for (int c = tid; c < 1024; c += 256) {
        float v = b2f(p[c]);
        s += v; ss += v * v;
    }
    #pragma unroll
    for (int d = 32; d > 0; d >>= 1) { s += __shfl_xor(s, d); ss += __shfl_xor(ss, d); }
    __shared__ float red[2][4];
    int wave = tid >> 6, lane = tid & 63;
    if (lane == 0) { red[0][wave] = s; red[1][wave] = ss; }
    __syncthreads();
    s  = red[0][0] + red[0][1] + red[0][2] + red[0][3];
    ss = red[1][0] + red[1][1] + red[1][2] + red[1][3];
    float mu   = s * (1.f / 1024.f);
    float var  = ss * (1.f / 1024.f) - mu * mu;
    float rstd = rsqrtf(var + 1e-5f);
    for (int c = tid; c < 1024; c += 256) {
        float v = b2f(p[c]);
        q[c] = f2b((v - mu) * rstd * b2f(g[c]) + b2f(b[c]));
    }
}

// ---------------------------------------------------------------------------
// Rotary (reads raw text via flag): qrot = rope(text)*DIM^-0.5 ;
// krotPad[b][512+t] = rope(audio_t).
// ---------------------------------------------------------------------------
__global__ __launch_bounds__(256) void rotary_kernel(
    const void* __restrict__ text, const int* __restrict__ flag,
    const bf16* __restrict__ audioT,
    bf16* __restrict__ qrot, bf16* __restrict__ krotPad)
{
    int row = blockIdx.x;
    int t = row & 2047, b = row >> 11;
    int tid = threadIdx.x;
    int f = *flag;
    const float lg = 9.210340371976184f / 512.f;
    size_t base = (size_t)row * 1024;
    size_t kb = ((size_t)(b * 2560 + 512 + t)) * 1024;
    for (int c = tid; c < 512; c += 256) {
        float invf = __expf(-(float)c * lg);
        float th = (float)t * invf;
        float sn, cs;
        sincosf(th, &sn, &cs);
        float q1 = f ? ((const float*)text)[base + c]
                     : b2f(((const bf16*)text)[base + c]);
        float q2 = f ? ((const float*)text)[base + c + 512]
                     : b2f(((const bf16*)text)[base + c + 512]);
        qrot[base + c]       = f2b((q1 * cs - q2 * sn) * 0.03125f);
        qrot[base + c + 512] = f2b((q2 * cs + q1 * sn) * 0.03125f);
        float k1 = b2f(audioT[base + c]), k2 = b2f(audioT[base + c + 512]);
        krotPad[kb + c]       = f2b(k1 * cs - k2 * sn);
        krotPad[kb + c + 512] = f2b(k2 * cs + k1 * sn);
    }
}

// ---------------------------------------------------------------------------
// Local-attention masked softmax. sim [b][w][512][1024] f32 -> attn bf16.
// ---------------------------------------------------------------------------
__global__ __launch_bounds__(256) void softmax_local(
    const float* __restrict__ sim, bf16* __restrict__ attn)
{
    int i  = blockIdx.x;
    int zz = blockIdx.y;
    int w  = zz & 3;
    int tid = threadIdx.x;
    const float* p = sim + ((size_t)zz * 512 + i) * 1024;
    bf16* q = attn + ((size_t)zz * 512 + i) * 1024;
    int jlo = (w == 0) ? 512 : 0;
    int jhi = 512 + i;
    float m = -1e30f;
    #pragma unroll
    for (int k = 0; k < 4; ++k) {
        int c = tid + k * 256;
        if (c >= jlo && c <= jhi) m = fmaxf(m, p[c]);
    }
    #pragma unroll
    for (int d = 32; d > 0; d >>= 1) m = fmaxf(m, __shfl_xor(m, d));
    __shared__ float red[2][4];
    int wave = tid >> 6, lane = tid & 63;
    if (lane == 0) red[0][wave] = m;
    __syncthreads();
    m = fmaxf(fmaxf(red[0][0], red[0][1]), fmaxf(red[0][2], red[0][3]));
    float pv[4];
    float s = 0.f;
    #pragma unroll
    for (int k = 0; k < 4; ++k) {
        int c = tid + k * 256;
        float e = (c >= jlo && c <= jhi) ? __expf(p[c] - m) : 0.f;
        pv[k] = e; s += e;
    }
    #pragma unroll
    for (int d = 32; d > 0; d >>= 1) s += __shfl_xor(s, d);
    if (lane == 0) red[1][wave] = s;
    __syncthreads();
    s = red[1][0] + red[1][1] + red[1][2] + red[1][3];
    float inv = 1.f / s;
    #pragma unroll
    for (int k = 0; k < 4; ++k) q[tid + k * 256] = f2b(pv[k] * inv);
}

// ---------------------------------------------------------------------------
// pack_qk: RMSNorm q/k from qkv f32 [4096][1536] -> per-head bf16 buffers.
// ---------------------------------------------------------------------------
__global__ __launch_bounds__(256) void pack_qk(
    const float* __restrict__ qkv, bf16* __restrict__ Qp, bf16* __restrict__ Kp,
    const bf16* __restrict__ qn_g, const bf16* __restrict__ kn_g)
{
    int gid  = blockIdx.x * 4 + (threadIdx.x >> 6);
    int lane = threadIdx.x & 63;
    int token = gid >> 4, r = gid & 15, part = r >> 3, h = r & 7;
    const float* p = qkv + (size_t)token * 1536 + part * 512 + h * 64 + lane;
    float v = *p;
    float ss = v * v;
    #pragma unroll
    for (int d = 32; d > 0; d >>= 1) ss += __shfl_xor(ss, d);
    float sc = rsqrtf(ss * (1.f / 64.f) + 1e-6f);
    const bf16* gw = part ? kn_g : qn_g;
    float outv = v * sc * b2f(gw[lane]);
    if (!part) outv *= 0.125f;
    int b = token >> 11, t = token & 2047;
    bf16* dst = (part ? Kp : Qp) + ((size_t)(b * 8 + h) * 2048 + t) * 64 + lane;
    *dst = f2b(outv);
}

// ---------------------------------------------------------------------------
// Fused causal flash attention (D=64), swapped-operand softmax (fused5 body,
// verified R7) + 2-way key-split for long blocks (qb >= 32) to halve the
// serial critical path (32 -> 16 tiles). Grid (96,16), 128 thr:
//   bx <  64: qb = 63-bx, chunk 0 (full range if qb<32, first half if >=32)
//   bx >= 64: qb = 63-(bx-64) in [32,63], chunk 1 (second half)
// Split blocks write f32 partials (O, m, l) merged by flash_combine2.
// ---------------------------------------------------------------------------
__global__ __launch_bounds__(128) void flash_fused6(
    const bf16* __restrict__ Qp, const bf16* __restrict__ Kp,
    const bf16* __restrict__ Vt, bf16* __restrict__ o,
    float* __restrict__ Opart, float* __restrict__ MLpart)
{
    __shared__ __align__(16) bf16 Ks[64][72];
    __shared__ __align__(16) bf16 Vs[64][72];
    __shared__ __align__(16) bf16 Ps[2][16][72];
    const int bx = blockIdx.x;
    const int qb = (bx < 64) ? (63 - bx) : (63 - (bx - 64));
    const int chunk = (bx < 64) ? 0 : 1;
    const bool split = (qb >= 32);
    const int bh = blockIdx.y, b = bh >> 3, h = bh & 7;
    const int qm = qb * 32;
    const int tid = threadIdx.x, wave = tid >> 6, lane = tid & 63;
    const int quad = lane >> 4, l16 = lane & 15;
    const bf16* Qg = Qp + (size_t)bh * 2048 * 64;
    const bf16* Kg = Kp + (size_t)bh * 2048 * 64;
    const bf16* Vg = Vt + (size_t)bh * 64 * 2048;

    const int nt_all = (qb >> 1) + 1;
    const int half   = nt_all >> 1;
    const int t0 = (split && chunk == 1) ? half : 0;
    const int t1 = (split && chunk == 0) ? half : nt_all;

    // Q as B-operand: lane l16 -> q-row, quad -> d-chunk
    const int q_row = qm + wave * 16 + l16;
    bf16x8 qa[2];
    qa[0] = *(const bf16x8*)(const void*)(Qg + (size_t)q_row * 64 + quad * 8);
    qa[1] = *(const bf16x8*)(const void*)(Qg + (size_t)q_row * 64 + 32 + quad * 8);

    f32x4 oacc[4];
    const f32x4 zro = {0.f, 0.f, 0.f, 0.f};
    #pragma unroll
    for (int j = 0; j < 4; ++j) oacc[j] = zro;
    float mst = -1e30f, lst = 0.f;

    // staging: 128 threads, each covers half a 64-elem row (4 x 16B)
    const int ldr = tid >> 1, ldc = (tid & 1) * 32;

    for (int t = t0; t < t1; ++t) {
        const int jt = t * 64;
        #pragma unroll
        for (int c = 0; c < 4; ++c) {
            *(uint4*)(void*)&Ks[ldr][ldc + c * 8] =
                *(const uint4*)(const void*)(Kg + (size_t)(jt + ldr) * 64 + ldc + c * 8);
            *(uint4*)(void*)&Vs[ldr][ldc + c * 8] =
                *(const uint4*)(const void*)(Vg + (size_t)ldr * 2048 + jt + ldc + c * 8);
        }
        __syncthreads();

        // ---- QK^T swapped: s[j][r] = score(key = jt + j*16 + quad*4 + r, q_row)
        f32x4 s[4];
        #pragma unroll
        for (int j = 0; j < 4; ++j) s[j] = zro;
        #pragma unroll
        for (int kk = 0; kk < 2; ++kk) {
            #pragma unroll
            for (int j = 0; j < 4; ++j) {
                bf16x8 kf = *(const bf16x8*)(const void*)&Ks[j*16 + l16][kk*32 + quad*8];
                s[j] = __builtin_amdgcn_mfma_f32_16x16x32_bf16(kf, qa[kk], s[j], 0, 0, 0);
            }
        }

        // causal mask
        if (jt + 63 > q_row) {
            #pragma unroll
            for (int j = 0; j < 4; ++j) {
                #pragma unroll
                for (int r = 0; r < 4; ++r) {
                    int key = jt + j * 16 + quad * 4 + r;
                    if (key > q_row) s[j][r] = -1e30f;
                }
            }
        }

        // per-lane (per-quad) local max, then in-place exp + sum
        float mq = s[0][0];
        #pragma unroll
        for (int j = 0; j < 4; ++j)
            #pragma unroll
            for (int r = 0; r < 4; ++r) mq = fmaxf(mq, s[j][r]);
        float sq = 0.f;
        #pragma unroll
        for (int j = 0; j < 4; ++j)
            #pragma unroll
            for (int r = 0; r < 4; ++r) {
                float v = __expf(s[j][r] - mq);
                s[j][r] = v; sq += v;
            }

        // merge (m, s) across the 4 quads of this q-row: two overlapped steps
        float mo = __shfl_xor(mq, 16);
        float so = __shfl_xor(sq, 16);
        float mm = fmaxf(mq, mo);
        sq = sq * __expf(mq - mm) + so * __expf(mo - mm);
        float mo2 = __shfl_xor(mm, 32);
        float so2 = __shfl_xor(sq, 32);
        float mtile = fmaxf(mm, mo2);
        float stile = sq * __expf(mm - mtile) + so2 * __expf(mo2 - mtile);

        // online update (uniform across the 4 quad-lanes of this q-row)
        float mn  = fmaxf(mst, mtile);
        float scl = __expf(mst - mn);
        lst = lst * scl + stile * __expf(mtile - mn);
        mst = mn;
        float pf = __expf(mq - mn);   // per-lane factor for its s[] values

        // rescale O (rows quad*4+r): fetch scl of those q-rows
        float sclq[4];
        #pragma unroll
        for (int r = 0; r < 4; ++r) sclq[r] = __shfl(scl, quad * 4 + r);
        #pragma unroll
        for (int j = 0; j < 4; ++j)
            #pragma unroll
            for (int r = 0; r < 4; ++r) oacc[j][r] *= sclq[r];

        // pack P = s*pf -> bf16 pairs, one uint2 LDS write per j
        #pragma unroll
        for (int j = 0; j < 4; ++j) {
            uint2 u;
            u.x = pk2(s[j][0] * pf, s[j][1] * pf);
            u.y = pk2(s[j][2] * pf, s[j][3] * pf);
            *(uint2*)(void*)&Ps[wave][l16][j * 16 + quad * 4] = u;
        }
        bf16x8 pa0 = *(const bf16x8*)(const void*)&Ps[wave][l16][quad * 8];
        bf16x8 pa1 = *(const bf16x8*)(const void*)&Ps[wave][l16][32 + quad * 8];

        // PV
        #pragma unroll
        for (int j = 0; j < 4; ++j) {
            bf16x8 vb = *(const bf16x8*)(const void*)&Vs[j*16 + l16][quad*8];
            oacc[j] = __builtin_amdgcn_mfma_f32_16x16x32_bf16(pa0, vb, oacc[j], 0, 0, 0);
        }
        #pragma unroll
        for (int j = 0; j < 4; ++j) {
            bf16x8 vb = *(const bf16x8*)(const void*)&Vs[j*16 + l16][32 + quad*8];
            oacc[j] = __builtin_amdgcn_mfma_f32_16x16x32_bf16(pa1, vb, oacc[j], 0, 0, 0);
        }
        __syncthreads();
    }

    if (!split) {
        float invq[4];
        #pragma unroll
        for (int r = 0; r < 4; ++r) invq[r] = 1.f / __shfl(lst, quad * 4 + r);
        #pragma unroll
        for (int j = 0; j < 4; ++j) {
            #pragma unroll
            for (int r = 0; r < 4; ++r) {
                int tr = qm + wave * 16 + quad * 4 + r;
                o[((size_t)(b * 2048 + tr)) * 512 + h * 64 + j * 16 + l16] =
                    f2b(oacc[j][r] * invq[r]);
            }
        }
    } else {
        const int pidx = (bh * 32 + (qb - 32)) * 2 + chunk;
        float* Od = Opart + (size_t)pidx * 2048;
        #pragma unroll
        for (int j = 0; j < 4; ++j)
            #pragma unroll
            for (int r = 0; r < 4; ++r) {
                int lr = wave * 16 + quad * 4 + r;       // local row 0..31
                Od[lr * 64 + j * 16 + l16] = oacc[j][r];
            }
        if (quad == 0) {
            MLpart[(size_t)pidx * 64 + wave * 16 + l16]      = mst;
            MLpart[(size_t)pidx * 64 + 32 + wave * 16 + l16] = lst;
        }
    }
}

// ---------------------------------------------------------------------------
// Merge the 2 key-split chunks for qb in [32,63]. Grid (32,16), 128 thr.
// ---------------------------------------------------------------------------
__global__ __launch_bounds__(128) void flash_combine2(
    const float* __restrict__ Opart, const float* __restrict__ MLpart,
    bf16* __restrict__ o)
{
    int qb = 32 + blockIdx.x;
    int bh = blockIdx.y, b = bh >> 3, h = bh & 7;
    int base = (bh * 32 + (qb - 32)) * 2;
    int row = threadIdx.x >> 2;          // 0..31
    int d0  = (threadIdx.x & 3) * 16;    // 0,16,32,48
    float m0 = MLpart[(size_t)base * 64 + row];
    float l0 = MLpart[(size_t)base * 64 + 32 + row];
    float m1 = MLpart[(size_t)(base + 1) * 64 + row];
    float l1 = MLpart[(size_t)(base + 1) * 64 + 32 + row];
    float mstar = fmaxf(m0, m1);
    float w0 = __expf(m0 - mstar), w1 = __expf(m1 - mstar);
    float inv = 1.f / (l0 * w0 + l1 * w1);
    const float* O0 = Opart + (size_t)base * 2048 + row * 64 + d0;
    const float* O1 = O0 + 2048;
    int t = qb * 32 + row;
    bf16* op = o + ((size_t)(b * 2048 + t)) * 512 + h * 64 + d0;
    #pragma unroll 4
    for (int dd = 0; dd < 16; ++dd)
        op[dd] = f2b((O0[dd] * w0 + O1[dd] * w1) * inv);
}

// ---------------------------------------------------------------------------
// FF2 split-K merge + bias + residual: out f32 = p0+p1+b2+x2. 4M elements.
// ---------------------------------------------------------------------------
__global__ __launch_bounds__(256) void combine_ff2(
    const float* __restrict__ p0, const float* __restrict__ p1,
    const bf16* __restrict__ x2, const bf16* __restrict__ b2,
    float* __restrict__ out)
{
    int i4 = (blockIdx.x * 256 + threadIdx.x) * 4;
    #pragma unroll
    for (int k = 0; k < 4; ++k) {
        int i = i4 + k;
        out[i] = p0[i] + p1[i] + b2f(x2[i]) + b2f(b2[i & 1023]);
    }
}

// ---------------------------------------------------------------------------
static void launch_gemm(int epi, hipStream_t s,
                        const bf16* A, int lda, int zsA, int zsA2,
                        const bf16* Bt, int ldb, int zsB, int zsB2,
                        void* C, int ldc, int zsC, int zsC2,
                        const bf16* bias, int zsBias, float scale,
                        int M, int N, int K, int nz)
{
    bool mt64 = ((M >> 7) * (N >> 7) * nz) <= 512;
    dim3 blk(256);
    if (mt64) {
        dim3 g(N / 128, M / 64, nz);
        switch (epi) {
        case 0: gemm_bt<0,64><<<g, blk, 0, s>>>(A, lda, zsA, zsA2, Bt, ldb, zsB, zsB2, C, ldc, zsC, zsC2, bias, zsBias, scale, K); break;
        case 1: gemm_bt<1,64><<<g, blk, 0, s>>>(A, lda, zsA, zsA2, Bt, ldb, zsB, zsB2, C, ldc, zsC, zsC2, bias, zsBias, scale, K); break;
        default: gemm_bt<2,64><<<g, blk, 0, s>>>(A, lda, zsA, zsA2, Bt, ldb, zsB, zsB2, C, ldc, zsC, zsC2, bias, zsBias, scale, K); break;
        }
    } else {
        dim3 g(N / 128, M / 128, nz);
        switch (epi) {
        case 0: gemm_bt<0,128><<<g, blk, 0, s>>>(A, lda, zsA, zsA2, Bt, ldb, zsB, zsB2, C, ldc, zsC, zsC2, bias, zsBias, scale, K); break;
        case 1: gemm_bt<1,128><<<g, blk, 0, s>>>(A, lda, zsA, zsA2, Bt, ldb, zsB, zsB2, C, ldc, zsC, zsC2, bias, zsBias, scale, K); break;
        default: gemm_bt<2,128><<<g, blk, 0, s>>>(A, lda, zsA, zsA2, Bt, ldb, zsB, zsB2, C, ldc, zsC, zsC2, bias, zsBias, scale, K); break;
        }
    }
}

extern "C" void kernel_launch(void* const* d_in, const int* in_sizes, int n_in,
                              void* d_out, int out_size, void* d_ws, size_t ws_size,
                              hipStream_t stream)
{
    const void* text  = d_in[0];
    const void* audio = d_in[1];
    const void* video = d_in[2];
    const void* Wa    = d_in[3];
    const void* ba    = d_in[4];
    const void* lna_g = d_in[5];
    const void* lna_b = d_in[6];
    const void* Wvid  = d_in[7];
    const void* bvid  = d_in[8];
    const void* lnv_g = d_in[9];
    const void* lnv_b = d_in[10];
    const void* ln1_g = d_in[11];
    const void* ln1_b = d_in[12];
    const void* Wq    = d_in[13];
    const void* Wkv   = d_in[14];
    const void* qn_g  = d_in[15];
    const void* kn_g  = d_in[16];
    const void* Wo    = d_in[17];
    const void* W1    = d_in[18];
    const void* b1    = d_in[19];
    const void* ln2_g = d_in[20];
    const void* ln2_b = d_in[21];
    const void* W2    = d_in[22];
    const void* b2    = d_in[23];

    char* ws = (char*)d_ws;
    size_t off = 0;
    auto alloc = [&](size_t bytes) -> char* {
        char* p = ws + off;
        off += (bytes + 255) & ~(size_t)255;
        return p;
    };
    const size_t MB = 1024 * 1024;
    int*  flag  = (int*)alloc(256);
    bf16* vecs  = (bf16*)alloc(14 * 4096 * 2);
    bf16* WqkvT = (bf16*)alloc((size_t)1536 * 1024 * 2);
    bf16* WoT   = (bf16*)alloc((size_t)1024 * 512 * 2);
    bf16* W1T   = (bf16*)alloc((size_t)4096 * 1024 * 2);
    bf16* W2T   = (bf16*)alloc((size_t)1024 * 4096 * 2);
    char* regionIn = alloc(24 * MB);   // audioC,videoC -> qkvF -> Opart/ML -> p0
    char* region2  = alloc(32 * MB);   // tmp2/tmpF/xF -> g
    char* regionH  = alloc(8 * MB);    // audioT -> h
    char* regionX  = alloc(8 * MB);    // videoT -> x2
    char* regionO  = alloc(4 * MB);    // WaT,WvT -> o
    bf16* qrot    = (bf16*)alloc((size_t)4096 * 1024 * 2);
    bf16* krotPad = (bf16*)alloc((size_t)2 * 2560 * 1024 * 2);
    bf16* VTpad   = (bf16*)alloc((size_t)2 * 1024 * 2560 * 2);
    bf16* attn    = (bf16*)alloc((size_t)8 * 512 * 1024 * 2);

    bf16*  audioC = (bf16*)regionIn;
    bf16*  videoC = audioC + (size_t)4096 * 1024;
    float* qkvF   = (float*)regionIn;
    bf16*  tmp2   = (bf16*)region2;          // adapter GEMM out (2 x 4096x1024 bf16)
    float* tmpF   = (float*)region2;         // sim scores f32
    float* xF     = (float*)(region2 + 16 * MB);
    bf16*  g      = (bf16*)region2;
    bf16*  audioT = (bf16*)regionH;
    bf16*  h      = (bf16*)regionH;
    bf16*  videoT = (bf16*)regionX;
    bf16*  x2     = (bf16*)regionX;
    bf16*  WaT    = (bf16*)regionO;
    bf16*  WvT    = WaT + (size_t)1024 * 1024;
    bf16*  o      = (bf16*)regionO;
    bf16*  Qp     = qrot;
    bf16*  Kp     = krotPad;
    bf16*  Vth    = attn;
    // flash 2-way-split partials (regionIn dead at flash time; 8.7 MB)
    float* Opart  = (float*)regionIn;
    float* MLpart = Opart + (size_t)1024 * 2048;
    // FF2 split-K partials (dead regions at FF2 time)
    float* p0     = (float*)regionIn;        // 16 MB of 24
    float* p1     = (float*)VTpad;           // VTpad+attn contiguous 18 MB

    bf16* baC   = vecs + 0 * 4096;
    bf16* bvidC = vecs + 1 * 4096;
    bf16* lnagC = vecs + 2 * 4096;
    bf16* lnabC = vecs + 3 * 4096;
    bf16* lnvgC = vecs + 4 * 4096;
    bf16* lnvbC = vecs + 5 * 4096;
    bf16* ln1gC = vecs + 6 * 4096;
    bf16* ln1bC = vecs + 7 * 4096;
    bf16* qngC  = vecs + 8 * 4096;
    bf16* kngC  = vecs + 9 * 4096;
    bf16* b1C   = vecs + 10 * 4096;
    bf16* ln2gC = vecs + 11 * 4096;
    bf16* ln2bC = vecs + 12 * 4096;
    bf16* b2C   = vecs + 13 * 4096;

    // 1) dtype flag
    detect_dtype<<<1, 64, 0, stream>>>((const unsigned short*)text, flag);

    // 2) canonicalize audio+video (one launch) + small vectors
    const int NTOK = 4096 * 1024;
    convert2<<<4096, 256, 0, stream>>>(audio, video, audioC, videoC, NTOK, flag);
    VecPack vp;
    const void* vsrc[14] = {ba, bvid, lna_g, lna_b, lnv_g, lnv_b, ln1_g, ln1_b,
                            qn_g, kn_g, b1, ln2_g, ln2_b, b2};
    int vn[14] = {1024, 1024, 1024, 1024, 1024, 1024, 1024, 1024,
                  64, 64, 4096, 4096, 4096, 1024};
    for (int i = 0; i < 14; ++i) { vp.src[i] = vsrc[i]; vp.n[i] = vn[i]; }
    convert_vecs<<<14, 256, 0, stream>>>(vp, vecs, flag);

    // 3) weight transposes
    dim3 tb(32, 8);
    transpose_any<<<dim3(32, 32), tb, 0, stream>>>(Wa, 1024, 1024, (unsigned short*)WaT, 1024, flag);
    transpose_any<<<dim3(32, 32), tb, 0, stream>>>(Wvid, 1024, 1024, (unsigned short*)WvT, 1024, flag);
    transpose_any<<<dim3(16, 32), tb, 0, stream>>>(Wq, 1024, 512, (unsigned short*)WqkvT, 1024, flag);
    transpose_any<<<dim3(32, 32), tb, 0, stream>>>(Wkv, 1024, 1024, (unsigned short*)(WqkvT + (size_t)512 * 1024), 1024, flag);
    transpose_any<<<dim3(32, 16), tb, 0, stream>>>(Wo, 512, 1024, (unsigned short*)WoT, 512, flag);
    transpose_any<<<dim3(128, 32), tb, 0, stream>>>(W1, 1024, 4096, (unsigned short*)W1T, 1024, flag);
    transpose_any<<<dim3(32, 128), tb, 0, stream>>>(W2, 4096, 1024, (unsigned short*)W2T, 4096, flag);

    // 4) adapters: one batched GEMM (nz=2, bf16 out w/ bias) + merged LN
    launch_gemm(1, stream, audioC, 1024, 4096*1024, 0, WaT, 1024, 1024*1024, 0,
                tmp2, 1024, 4096*1024, 0, baC, 4096, 1.f, 4096, 1024, 1024, 2);
    ln_rows2<<<8192, 256, 0, stream>>>(tmp2, lnagC, lnabC, lnvgC, lnvbC, audioT, videoT);

    // 5) pads, rotary (raw text), batched VTpad transpose
    hipMemsetAsync(krotPad, 0, (size_t)2 * 2560 * 1024 * 2, stream);
    hipMemsetAsync(VTpad, 0, (size_t)2 * 1024 * 2560 * 2, stream);
    rotary_kernel<<<4096, 256, 0, stream>>>(text, flag, audioT, qrot, krotPad);
    transpose_vt<<<dim3(32, 64, 2), tb, 0, stream>>>(
        (const unsigned short*)videoT, (unsigned short*)VTpad);

    // 6) local attention: batched sim (nz=8) -> softmax -> batched @V (nz=8)
    launch_gemm(0, stream, qrot, 1024, 512*1024, 0,
                krotPad, 1024, 512*1024, 512*1024,
                tmpF, 1024, 512*1024, 0, nullptr, 0, 1.f, 512, 1024, 1024, 8);
    softmax_local<<<dim3(512, 8), 256, 0, stream>>>(tmpF, attn);
    launch_gemm(0, stream, attn, 1024, 512*1024, 0,
                VTpad, 2560, 512, 1024*2560 - 2048,
                xF, 1024, 512*1024, 0, nullptr, 0, 1.f, 512, 1024, 1024, 8);

    // 7) ln1 -> qkv -> pack -> V transpose -> 2-way-split swapped flash
    ln_rows<float><<<4096, 256, 0, stream>>>(xF, 1024, ln1gC, ln1bC, h, 1e-5f);
    launch_gemm(0, stream, h, 1024, 0, 0, WqkvT, 1024, 0, 0,
                qkvF, 1536, 0, 0, nullptr, 0, 1.f, 4096, 1536, 1024, 1);
    pack_qk<<<16384, 256, 0, stream>>>(qkvF, Qp, Kp, qngC, kngC);
    transpose_v<<<dim3(2, 64, 16), tb, 0, stream>>>(qkvF, Vth);
    flash_fused6<<<dim3(96, 16), 128, 0, stream>>>(Qp, Kp, Vth, o, Opart, MLpart);
    flash_combine2<<<dim3(32, 16), 128, 0, stream>>>(Opart, MLpart, o);

    // 8) x2 = 2*(o@Wo) ; g = gelu(x2@W1+b1) via 8-phase 256^2 ; ln2 ; FF2
    launch_gemm(1, stream, o, 512, 0, 0, WoT, 512, 0, 0,
                x2, 1024, 0, 0, nullptr, 0, 2.f, 4096, 1024, 512, 1);
    gemm_ff1_8ph<<<dim3(16, 16), 512, 0, stream>>>(x2, 1024, W1T, 1024,
                                                   g, 4096, b1C, 1024);
    ln_rows<bf16><<<4096, 256, 0, stream>>>(g, 4096, ln2gC, ln2bC, g, 1e-5f);
    launch_gemm(0, stream, g, 4096, 2048, 0, W2T, 4096, 2048, 0,
                p0, 1024, (int)(p1 - p0), 0, nullptr, 0, 1.f, 4096, 1024, 2048, 2);
    combine_ff2<<<4096, 256, 0, stream>>>(p0, p1, x2, b2C, (float*)d_out);

    (void)in_sizes; (void)n_in; (void)out_size; (void)ws_size;
}

// Round 9
// 549.282 us; speedup vs baseline: 1.1823x; 1.0298x over previous
//
#include <hip/hip_runtime.h>
#include <hip/hip_bf16.h>

typedef __bf16 bf16;
typedef __bf16 bf16x8 __attribute__((ext_vector_type(8)));
typedef __bf16 bf16x4 __attribute__((ext_vector_type(4)));
typedef float  f32x4  __attribute__((ext_vector_type(4)));

static __device__ __forceinline__ float b2f(bf16 x) { return (float)x; }
static __device__ __forceinline__ bf16  f2b(float x) { return (bf16)x; }

// pack two floats -> one uint holding two bf16 (low = a, high = b)
static __device__ __forceinline__ unsigned pk2(float a, float b)
{
    bf16 x = f2b(a), y = f2b(b);
    unsigned short ux = *(unsigned short*)&x;
    unsigned short uy = *(unsigned short*)&y;
    return (unsigned)ux | ((unsigned)uy << 16);
}

// async global->LDS, 16B per lane; lds dest is wave-uniform base (+lane*16)
static __device__ __forceinline__ void gl_lds16(const bf16* g, bf16* l)
{
    __builtin_amdgcn_global_load_lds(
        (const __attribute__((address_space(1))) void*)g,
        (__attribute__((address_space(3))) void*)l,
        16, 0, 0);
}

// ---------------------------------------------------------------------------
// dtype detection: flag=1 -> f32 inputs.
// ---------------------------------------------------------------------------
__global__ void detect_dtype(const unsigned short* __restrict__ p, int* __restrict__ flag)
{
    if (threadIdx.x == 0 && blockIdx.x == 0) {
        int big = 0;
        for (int i = 0; i < 512; ++i) {
            int e = (p[i] >> 7) & 0xFF;
            if (e >= 0xE0) big++;
        }
        *flag = (big > 0) ? 1 : 0;
    }
}

// convert two tensors in one launch (grid split in half)
__global__ __launch_bounds__(256) void convert2(
    const void* __restrict__ sa, const void* __restrict__ sb,
    bf16* __restrict__ da, bf16* __restrict__ db, int n,
    const int* __restrict__ flag)
{
    int f = *flag;
    int half = gridDim.x >> 1;
    const void* s = (blockIdx.x < half) ? sa : sb;
    bf16* d = (blockIdx.x < half) ? da : db;
    int bid = (blockIdx.x < half) ? blockIdx.x : blockIdx.x - half;
    for (int i = bid * 256 + threadIdx.x; i < n; i += half * 256) {
        float v = f ? ((const float*)s)[i] : (float)((const bf16*)s)[i];
        d[i] = f2b(v);
    }
}

struct VecPack { const void* src[14]; int n[14]; };
__global__ __launch_bounds__(256) void convert_vecs(
    VecPack vp, bf16* __restrict__ dst, const int* __restrict__ flag)
{
    int v = blockIdx.x;
    int f = *flag;
    const void* s = vp.src[v];
    int n = vp.n[v];
    bf16* d = dst + (size_t)v * 4096;
    for (int i = threadIdx.x; i < n; i += 256) {
        float x = f ? ((const float*)s)[i] : (float)((const bf16*)s)[i];
        d[i] = f2b(x);
    }
}

// ---------------------------------------------------------------------------
// GEMM: C[M,N] = A[M,K] @ Bt[n][k]. MT x 128 tile, BK=64, 4 waves.
// EPI: 0 = f32 store (+bias)   1 = bf16 (v+bias)*scale   2 = bf16 gelu
//      3 = f32 store v + bias + resid[off] (fused FF2 epilogue)
// ---------------------------------------------------------------------------
template <int EPI, int MT>
__global__ __launch_bounds__(256) void gemm_bt(
    const bf16* __restrict__ A0, int lda, int zsA, int zsA2,
    const bf16* __restrict__ B0, int ldb, int zsB, int zsB2,
    void* __restrict__ C0, int ldc, int zsC, int zsC2,
    const bf16* __restrict__ bias, int zsBias, float scale,
    const bf16* __restrict__ resid, int K)
{
    constexpr int IFR = MT / 32;
    __shared__ __align__(16) bf16 As[MT * 64];
    __shared__ __align__(16) bf16 Bs[128 * 64];
    const int z = blockIdx.z;
    const bf16* A  = A0 + (size_t)z * zsA + (size_t)(z >> 2) * zsA2;
    const bf16* Bt = B0 + (size_t)z * zsB + (size_t)(z >> 2) * zsB2;
    const size_t cbase = (size_t)z * zsC + (size_t)(z >> 2) * zsC2;
    if (bias) bias += (size_t)z * zsBias;
    const int tid  = threadIdx.x;
    const int lane = tid & 63, wave = tid >> 6;
    const int quad = lane >> 4, l16 = lane & 15;
    const size_t tm = (size_t)blockIdx.y * MT, tn = (size_t)blockIdx.x * 128;
    const int wm = (wave >> 1) * (MT / 2), wn = (wave & 1) * 64;
    const int srow = lane >> 3;
    const int scol = ((lane & 7) ^ srow) * 8;

    f32x4 acc[IFR][4];
    const f32x4 zro = {0.f, 0.f, 0.f, 0.f};
    #pragma unroll
    for (int i = 0; i < IFR; ++i)
        #pragma unroll
        for (int j = 0; j < 4; ++j) acc[i][j] = zro;

    const int swzA = l16 & 7;
    for (int k0 = 0; k0 < K; k0 += 64) {
        #pragma unroll
        for (int i = 0; i < IFR; ++i) {
            int chunk = (wave * IFR + i) * 64;
            int row = (chunk >> 3) + srow;
            gl_lds16(A + (tm + row) * (size_t)lda + k0 + scol, As + (size_t)chunk * 8);
        }
        #pragma unroll
        for (int i = 0; i < 4; ++i) {
            int chunk = (wave * 4 + i) * 64;
            int row = (chunk >> 3) + srow;
            gl_lds16(Bt + (tn + row) * (size_t)ldb + k0 + scol, Bs + (size_t)chunk * 8);
        }
        __syncthreads();
        #pragma unroll
        for (int kk = 0; kk < 2; ++kk) {
            bf16x8 af[IFR], bfr[4];
            #pragma unroll
            for (int i = 0; i < IFR; ++i) {
                int row = wm + i * 16 + l16;
                af[i] = *(const bf16x8*)(const void*)&As[(row * 8 + ((kk*4 + quad) ^ swzA)) * 8];
            }
            #pragma unroll
            for (int j = 0; j < 4; ++j) {
                int row = wn + j * 16 + l16;
                bfr[j] = *(const bf16x8*)(const void*)&Bs[(row * 8 + ((kk*4 + quad) ^ swzA)) * 8];
            }
            #pragma unroll
            for (int i = 0; i < IFR; ++i)
                #pragma unroll
                for (int j = 0; j < 4; ++j)
                    acc[i][j] = __builtin_amdgcn_mfma_f32_16x16x32_bf16(
                        af[i], bfr[j], acc[i][j], 0, 0, 0);
        }
        __syncthreads();
    }

    float* Cf = (float*)C0;
    bf16*  Cb = (bf16*)C0;
    #pragma unroll
    for (int i = 0; i < IFR; ++i) {
        #pragma unroll
        for (int j = 0; j < 4; ++j) {
            size_t col = tn + wn + j*16 + l16;
            float bb = bias ? b2f(bias[col]) : 0.f;
            #pragma unroll
            for (int r = 0; r < 4; ++r) {
                size_t row = tm + wm + i*16 + quad*4 + r;
                float v = acc[i][j][r] + bb;
                size_t off = cbase + row * (size_t)ldc + col;
                if (EPI == 0) {
                    Cf[off] = v;
                } else if (EPI == 1) {
                    Cb[off] = f2b(v * scale);
                } else if (EPI == 3) {
                    Cf[off] = v + b2f(resid[off]);
                } else {
                    float g = 0.5f * v * (1.f + tanhf(0.7978845608028654f *
                                  (v + 0.044715f * v * v * v)));
                    Cb[off] = f2b(g);
                }
            }
        }
    }
}

// ---------------------------------------------------------------------------
// FF1 GEMM, 256x256 tile, BK=64, 8 waves, 8-phase-style pipelined schedule.
// C[M,N] = gelu(A[M,K] @ Bt[N,K]^T + bias), bf16 out.
// ---------------------------------------------------------------------------
__global__ __launch_bounds__(512, 2) void gemm_ff1_8ph(
    const bf16* __restrict__ A, int lda,
    const bf16* __restrict__ Bt, int ldb,
    bf16* __restrict__ C, int ldc,
    const bf16* __restrict__ bias, int K)
{
    __shared__ __align__(16) bf16 As[2][256 * 64];
    __shared__ __align__(16) bf16 Bs[2][256 * 64];
    const int tid  = threadIdx.x;
    const int lane = tid & 63, wave = tid >> 6;
    const int quad = lane >> 4, l16 = lane & 15;
    const int wr = wave >> 2, wc = wave & 3;          // 2M x 4N wave grid
    const size_t tm = (size_t)blockIdx.y * 256;
    const size_t tn = (size_t)blockIdx.x * 256;
    const int srow = lane >> 3;
    const int scol = ((lane & 7) ^ srow) * 8;         // pre-swizzled global col
    const int swz  = l16 & 7;                         // read-side swizzle

    f32x4 acc[8][4];
    const f32x4 zro = {0.f, 0.f, 0.f, 0.f};
    #pragma unroll
    for (int m = 0; m < 8; ++m)
        #pragma unroll
        for (int n = 0; n < 4; ++n) acc[m][n] = zro;

    const bf16* aSrc[4];
    const bf16* bSrc[4];
    #pragma unroll
    for (int i = 0; i < 4; ++i) {
        int grow = wave * 32 + i * 8 + srow;
        aSrc[i] = A  + (tm + grow) * (size_t)lda + scol;
        bSrc[i] = Bt + (tn + grow) * (size_t)ldb + scol;
    }

#define STAGE(BUF, K0, I)                                                     \
    do {                                                                      \
        gl_lds16(aSrc[I] + (K0), &As[BUF][(wave * 4 + (I)) * 512]);           \
        gl_lds16(bSrc[I] + (K0), &Bs[BUF][(wave * 4 + (I)) * 512]);           \
    } while (0)

#define LDA_F(BUF, M, KK)                                                     \
    (*(const bf16x8*)(const void*)&As[BUF][(wr * 128 + (M) * 16 + l16) * 64 + \
        ((((KK) * 4 + quad) ^ swz) << 3)])
#define LDB_F(BUF, N, KK)                                                     \
    (*(const bf16x8*)(const void*)&Bs[BUF][(wc * 64 + (N) * 16 + l16) * 64 +  \
        ((((KK) * 4 + quad) ^ swz) << 3)])

#define PHASE(M0, M1, PREF_STMT, TAIL_STMT)                                   \
    {                                                                         \
        PREF_STMT;                                                            \
        bf16x8 x0 = LDA_F(cur, M0, 0), x1 = LDA_F(cur, M0, 1);                \
        bf16x8 y0 = LDA_F(cur, M1, 0), y1 = LDA_F(cur, M1, 1);                \
        asm volatile("s_barrier" ::: "memory");                               \
        __builtin_amdgcn_s_setprio(1);                                        \
        _Pragma("unroll")                                                     \
        for (int n = 0; n < 4; ++n) {                                         \
            acc[M0][n] = __builtin_amdgcn_mfma_f32_16x16x32_bf16(x0, bfr[n][0], acc[M0][n], 0, 0, 0); \
            acc[M0][n] = __builtin_amdgcn_mfma_f32_16x16x32_bf16(x1, bfr[n][1], acc[M0][n], 0, 0, 0); \
            acc[M1][n] = __builtin_amdgcn_mfma_f32_16x16x32_bf16(y0, bfr[n][0], acc[M1][n], 0, 0, 0); \
            acc[M1][n] = __builtin_amdgcn_mfma_f32_16x16x32_bf16(y1, bfr[n][1], acc[M1][n], 0, 0, 0); \
        }                                                                     \
        __builtin_amdgcn_s_setprio(0);                                        \
        TAIL_STMT;                                                            \
        asm volatile("s_barrier" ::: "memory");                               \
    }

    #pragma unroll
    for (int i = 0; i < 4; ++i) STAGE(0, 0, i);
    asm volatile("s_waitcnt vmcnt(0)" ::: "memory");
    asm volatile("s_barrier" ::: "memory");

    const int NT = K >> 6;
    bf16x8 bfr[4][2];
    for (int t = 0; t < NT; ++t) {
        const int cur = t & 1, nxt = cur ^ 1;
        const int k1  = (t + 1) << 6;
        const bool pref = (t + 1 < NT);

        #pragma unroll
        for (int n = 0; n < 4; ++n) {
            bfr[n][0] = LDB_F(cur, n, 0);
            bfr[n][1] = LDB_F(cur, n, 1);
        }
        PHASE(0, 1,
              if (pref) { STAGE(nxt, k1, 0); STAGE(nxt, k1, 1); }, )
        PHASE(2, 3,
              if (pref) { STAGE(nxt, k1, 2); STAGE(nxt, k1, 3); }, )
        PHASE(4, 5, , )
        PHASE(6, 7, ,
              asm volatile("s_waitcnt vmcnt(0)" ::: "memory"))
    }
#undef PHASE
#undef LDB_F
#undef LDA_F
#undef STAGE

    // epilogue: bias + fast gelu (v * sigmoid(1.59577 v + 0.0713548 v^3))
    #pragma unroll
    for (int m = 0; m < 8; ++m) {
        #pragma unroll
        for (int n = 0; n < 4; ++n) {
            size_t col = tn + wc * 64 + n * 16 + l16;
            float bb = b2f(bias[col]);
            #pragma unroll
            for (int r = 0; r < 4; ++r) {
                size_t row = tm + wr * 128 + m * 16 + quad * 4 + r;
                float v = acc[m][n][r] + bb;
                float s = v * (1.5957691216057308f + 0.07135481627f * v * v);
                float g = v / (1.f + __expf(-s));
                C[row * (size_t)ldc + col] = f2b(g);
            }
        }
    }
}

// ---------------------------------------------------------------------------
// dtype-branching transpose for raw weight inputs -> bf16 transposed
// ---------------------------------------------------------------------------
__global__ void transpose_any(const void* __restrict__ in, int R, int C,
                              unsigned short* __restrict__ out, int ldo,
                              const int* __restrict__ flag)
{
    __shared__ unsigned short t[32][33];
    int f = *flag;
    int c0 = blockIdx.x * 32, r0 = blockIdx.y * 32;
    int tx = threadIdx.x, ty = threadIdx.y;
    for (int i = ty; i < 32; i += 8) {
        size_t idx = (size_t)(r0 + i) * C + c0 + tx;
        bf16 v = f ? f2b(((const float*)in)[idx]) : ((const bf16*)in)[idx];
        t[i][tx] = *(unsigned short*)&v;
    }
    __syncthreads();
    for (int i = ty; i < 32; i += 8)
        out[(size_t)(c0 + i) * ldo + r0 + tx] = t[tx][i];
}

// videoT [b][2048][1024] -> VTpad [b][1024][512 + 2048] (col offset 512), z=b
__global__ void transpose_vt(const unsigned short* __restrict__ in,
                             unsigned short* __restrict__ out)
{
    __shared__ unsigned short t[32][33];
    int b = blockIdx.z;
    const unsigned short* src = in + (size_t)b * 2048 * 1024;
    unsigned short* dst = out + (size_t)b * 1024 * 2560;
    int c0 = blockIdx.x * 32, r0 = blockIdx.y * 32;
    int tx = threadIdx.x, ty = threadIdx.y;
    for (int i = ty; i < 32; i += 8)
        t[i][tx] = src[(size_t)(r0 + i) * 1024 + c0 + tx];
    __syncthreads();
    for (int i = ty; i < 32; i += 8)
        dst[(size_t)(c0 + i) * 2560 + 512 + r0 + tx] = t[tx][i];
}

// ---------------------------------------------------------------------------
// V transpose into per-head Vt[bh][64][2048] bf16.
// ---------------------------------------------------------------------------
__global__ void transpose_v(const float* __restrict__ qkv, bf16* __restrict__ Vt)
{
    __shared__ float t[32][33];
    int bh = blockIdx.z, b = bh >> 3, h = bh & 7;
    const float* src = qkv + (size_t)b * 2048 * 1536 + 1024 + h * 64;
    int c0 = blockIdx.x * 32, r0 = blockIdx.y * 32;
    int tx = threadIdx.x, ty = threadIdx.y;
    for (int i = ty; i < 32; i += 8)
        t[i][tx] = src[(size_t)(r0 + i) * 1536 + c0 + tx];
    __syncthreads();
    bf16* dst = Vt + (size_t)bh * 64 * 2048;
    for (int i = ty; i < 32; i += 8)
        dst[(size_t)(c0 + i) * 2048 + r0 + tx] = f2b(t[tx][i]);
}

// ---------------------------------------------------------------------------
// Vectorized row LayerNorms (G13): values held in registers, single read.
// ---------------------------------------------------------------------------
// f32 input, C=1024: one float4 per thread.
__global__ __launch_bounds__(256) void ln_f32_1024(
    const float* __restrict__ in,
    const bf16* __restrict__ g, const bf16* __restrict__ b,
    bf16* __restrict__ out)
{
    const int row = blockIdx.x, tid = threadIdx.x;
    f32x4 v = *(const f32x4*)(in + (size_t)row * 1024 + tid * 4);
    float s  = v[0] + v[1] + v[2] + v[3];
    float ss = v[0]*v[0] + v[1]*v[1] + v[2]*v[2] + v[3]*v[3];
    #pragma unroll
    for (int d = 32; d > 0; d >>= 1) { s += __shfl_xor(s, d); ss += __shfl_xor(ss, d); }
    __shared__ float red[2][4];
    int wave = tid >> 6, lane = tid & 63;
    if (lane == 0) { red[0][wave] = s; red[1][wave] = ss; }
    __syncthreads();
    s  = red[0][0] + red[0][1] + red[0][2] + red[0][3];
    ss = red[1][0] + red[1][1] + red[1][2] + red[1][3];
    float mu   = s * (1.f / 1024.f);
    float var  = ss * (1.f / 1024.f) - mu * mu;
    float rstd = rsqrtf(var + 1e-5f);
    bf16x4 g4 = *(const bf16x4*)(const void*)(g + tid * 4);
    bf16x4 b4 = *(const bf16x4*)(const void*)(b + tid * 4);
    bf16x4 o4;
    #pragma unroll
    for (int j = 0; j < 4; ++j)
        o4[j] = f2b((v[j] - mu) * rstd * b2f(g4[j]) + b2f(b4[j]));
    *(bf16x4*)(void*)(out + (size_t)row * 1024 + tid * 4) = o4;
}

// bf16 input, C=4096: two bf16x8 per thread (in-place safe).
__global__ __launch_bounds__(256) void ln_b16_4096(
    const bf16* __restrict__ in,
    const bf16* __restrict__ g, const bf16* __restrict__ b,
    bf16* __restrict__ out)
{
    const int row = blockIdx.x, tid = threadIdx.x;
    const bf16* p = in + (size_t)row * 4096;
    bf16x8 v0 = *(const bf16x8*)(const void*)(p + tid * 8);
    bf16x8 v1 = *(const bf16x8*)(const void*)(p + 2048 + tid * 8);
    float f0[8], f1[8];
    float s = 0.f, ss = 0.f;
    #pragma unroll
    for (int j = 0; j < 8; ++j) {
        f0[j] = b2f(v0[j]); f1[j] = b2f(v1[j]);
        s += f0[j] + f1[j];
        ss += f0[j]*f0[j] + f1[j]*f1[j];
    }
    #pragma unroll
    for (int d = 32; d > 0; d >>= 1) { s += __shfl_xor(s, d); ss += __shfl_xor(ss, d); }
    __shared__ float red[2][4];
    int wave = tid >> 6, lane = tid & 63;
    if (lane == 0) { red[0][wave] = s; red[1][wave] = ss; }
    __syncthreads();
    s  = red[0][0] + red[0][1] + red[0][2] + red[0][3];
    ss = red[1][0] + red[1][1] + red[1][2] + red[1][3];
    float mu   = s * (1.f / 4096.f);
    float var  = ss * (1.f / 4096.f) - mu * mu;
    float rstd = rsqrtf(var + 1e-5f);
    bf16x8 g0 = *(const bf16x8*)(const void*)(g + tid * 8);
    bf16x8 b0 = *(const bf16x8*)(const void*)(b + tid * 8);
    bf16x8 g1 = *(const bf16x8*)(const void*)(g + 2048 + tid * 8);
    bf16x8 b1 = *(const bf16x8*)(const void*)(b + 2048 + tid * 8);
    bf16x8 o0, o1;
    #pragma unroll
    for (int j = 0; j < 8; ++j) {
        o0[j] = f2b((f0[j] - mu) * rstd * b2f(g0[j]) + b2f(b0[j]));
        o1[j] = f2b((f1[j] - mu) * rstd * b2f(g1[j]) + b2f(b1[j]));
    }
    bf16* q = out + (size_t)row * 4096;
    *(bf16x8*)(void*)(q + tid * 8)        = o0;
    *(bf16x8*)(void*)(q + 2048 + tid * 8) = o1;
}

// both adapter LNs in one launch: rows 0..4095 audio, 4096..8191 video. C=1024.
__global__ __launch_bounds__(256) void ln_rows2(
    const bf16* __restrict__ in,
    const bf16* __restrict__ g0, const bf16* __restrict__ b0,
    const bf16* __restrict__ g1, const bf16* __restrict__ b1,
    bf16* __restrict__ out0, bf16* __restrict__ out1)
{
    const int row = blockIdx.x, tid = threadIdx.x;
    const int sel = row >> 12;
    const bf16* p = in + (size_t)row * 1024;
    const bf16* g = sel ? g1 : g0;
    const bf16* b = sel ? b1 : b0;
    bf16* q = (sel ? out1 + (size_t)(row - 4096) * 1024 : out0 + (size_t)row * 1024);
    bf16x4 v4 = *(const bf16x4*)(const void*)(p + tid * 4);
    float f[4];
    float s = 0.f, ss = 0.f;
    #pragma unroll
    for (int j = 0; j < 4; ++j) {
        f[j] = b2f(v4[j]);
        s += f[j]; ss += f[j]*f[j];
    }
    #pragma unroll
    for (int d = 32; d > 0; d >>= 1) { s += __shfl_xor(s, d); ss += __shfl_xor(ss, d); }
    __shared__ float red[2][4];
    int wave = tid >> 6, lane = tid & 63;
    if (lane == 0) { red[0][wave] = s; red[1][wave] = ss; }
    __syncthreads();
    s  = red[0][0] + red[0][1] + red[0][2] + red[0][3];
    ss = red[1][0] + red[1][1] + red[1][2] + red[1][3];
    float mu   = s * (1.f / 1024.f);
    float var  = ss * (1.f / 1024.f) - mu * mu;
    float rstd = rsqrtf(var + 1e-5f);
    bf16x4 g4 = *(const bf16x4*)(const void*)(g + tid * 4);
    bf16x4 b4 = *(const bf16x4*)(const void*)(b + tid * 4);
    bf16x4 o4;
    #pragma unroll
    for (int j = 0; j < 4; ++j)
        o4[j] = f2b((f[j] - mu) * rstd * b2f(g4[j]) + b2f(b4[j]));
    *(bf16x4*)(void*)(q + tid * 4) = o4;
}

// ---------------------------------------------------------------------------
// Rotary (reads raw text via flag): qrot = rope(text)*DIM^-0.5 ;
// krotPad[b][512+t] = rope(audio_t).
// ---------------------------------------------------------------------------
__global__ __launch_bounds__(256) void rotary_kernel(
    const void* __restrict__ text, const int* __restrict__ flag,
    const bf16* __restrict__ audioT,
    bf16* __restrict__ qrot, bf16* __restrict__ krotPad)
{
    int row = blockIdx.x;
    int t = row & 2047, b = row >> 11;
    int tid = threadIdx.x;
    int f = *flag;
    const float lg = 9.210340371976184f / 512.f;
    size_t base = (size_t)row * 1024;
    size_t kb = ((size_t)(b * 2560 + 512 + t)) * 1024;
    for (int c = tid; c < 512; c += 256) {
        float invf = __expf(-(float)c * lg);
        float th = (float)t * invf;
        float sn, cs;
        sincosf(th, &sn, &cs);
        float q1 = f ? ((const float*)text)[base + c]
                     : b2f(((const bf16*)text)[base + c]);
        float q2 = f ? ((const float*)text)[base + c + 512]
                     : b2f(((const bf16*)text)[base + c + 512]);
        qrot[base + c]       = f2b((q1 * cs - q2 * sn) * 0.03125f);
        qrot[base + c + 512] = f2b((q2 * cs + q1 * sn) * 0.03125f);
        float k1 = b2f(audioT[base + c]), k2 = b2f(audioT[base + c + 512]);
        krotPad[kb + c]       = f2b(k1 * cs - k2 * sn);
        krotPad[kb + c + 512] = f2b(k2 * cs + k1 * sn);
    }
}

// ---------------------------------------------------------------------------
// Local-attention masked softmax. sim [b][w][512][1024] f32 -> attn bf16.
// ---------------------------------------------------------------------------
__global__ __launch_bounds__(256) void softmax_local(
    const float* __restrict__ sim, bf16* __restrict__ attn)
{
    int i  = blockIdx.x;
    int zz = blockIdx.y;
    int w  = zz & 3;
    int tid = threadIdx.x;
    const float* p = sim + ((size_t)zz * 512 + i) * 1024;
    bf16* q = attn + ((size_t)zz * 512 + i) * 1024;
    int jlo = (w == 0) ? 512 : 0;
    int jhi = 512 + i;
    float m = -1e30f;
    #pragma unroll
    for (int k = 0; k < 4; ++k) {
        int c = tid + k * 256;
        if (c >= jlo && c <= jhi) m = fmaxf(m, p[c]);
    }
    #pragma unroll
    for (int d = 32; d > 0; d >>= 1) m = fmaxf(m, __shfl_xor(m, d));
    __shared__ float red[2][4];
    int wave = tid >> 6, lane = tid & 63;
    if (lane == 0) red[0][wave] = m;
    __syncthreads();
    m = fmaxf(fmaxf(red[0][0], red[0][1]), fmaxf(red[0][2], red[0][3]));
    float pv[4];
    float s = 0.f;
    #pragma unroll
    for (int k = 0; k < 4; ++k) {
        int c = tid + k * 256;
        float e = (c >= jlo && c <= jhi) ? __expf(p[c] - m) : 0.f;
        pv[k] = e; s += e;
    }
    #pragma unroll
    for (int d = 32; d > 0; d >>= 1) s += __shfl_xor(s, d);
    if (lane == 0) red[1][wave] = s;
    __syncthreads();
    s = red[1][0] + red[1][1] + red[1][2] + red[1][3];
    float inv = 1.f / s;
    #pragma unroll
    for (int k = 0; k < 4; ++k) q[tid + k * 256] = f2b(pv[k] * inv);
}

// ---------------------------------------------------------------------------
// pack_qk: RMSNorm q/k from qkv f32 [4096][1536] -> per-head bf16 buffers.
// ---------------------------------------------------------------------------
__global__ __launch_bounds__(256) void pack_qk(
    const float* __restrict__ qkv, bf16* __restrict__ Qp, bf16* __restrict__ Kp,
    const bf16* __restrict__ qn_g, const bf16* __restrict__ kn_g)
{
    int gid  = blockIdx.x * 4 + (threadIdx.x >> 6);
    int lane = threadIdx.x & 63;
    int token = gid >> 4, r = gid & 15, part = r >> 3, h = r & 7;
    const float* p = qkv + (size_t)token * 1536 + part * 512 + h * 64 + lane;
    float v = *p;
    float ss = v * v;
    #pragma unroll
    for (int d = 32; d > 0; d >>= 1) ss += __shfl_xor(ss, d);
    float sc = rsqrtf(ss * (1.f / 64.f) + 1e-6f);
    const bf16* gw = part ? kn_g : qn_g;
    float outv = v * sc * b2f(gw[lane]);
    if (!part) outv *= 0.125f;
    int b = token >> 11, t = token & 2047;
    bf16* dst = (part ? Kp : Qp) + ((size_t)(b * 8 + h) * 2048 + t) * 64 + lane;
    *dst = f2b(outv);
}

// ---------------------------------------------------------------------------
// Fused causal flash attention (D=64), swapped-operand softmax + 2-way
// key-split for long blocks (qb >= 32). Grid (96,16), 128 thr. (R8 verified)
// ---------------------------------------------------------------------------
__global__ __launch_bounds__(128) void flash_fused6(
    const bf16* __restrict__ Qp, const bf16* __restrict__ Kp,
    const bf16* __restrict__ Vt, bf16* __restrict__ o,
    float* __restrict__ Opart, float* __restrict__ MLpart)
{
    __shared__ __align__(16) bf16 Ks[64][72];
    __shared__ __align__(16) bf16 Vs[64][72];
    __shared__ __align__(16) bf16 Ps[2][16][72];
    const int bx = blockIdx.x;
    const int qb = (bx < 64) ? (63 - bx) : (63 - (bx - 64));
    const int chunk = (bx < 64) ? 0 : 1;
    const bool split = (qb >= 32);
    const int bh = blockIdx.y, b = bh >> 3, h = bh & 7;
    const int qm = qb * 32;
    const int tid = threadIdx.x, wave = tid >> 6, lane = tid & 63;
    const int quad = lane >> 4, l16 = lane & 15;
    const bf16* Qg = Qp + (size_t)bh * 2048 * 64;
    const bf16* Kg = Kp + (size_t)bh * 2048 * 64;
    const bf16* Vg = Vt + (size_t)bh * 64 * 2048;

    const int nt_all = (qb >> 1) + 1;
    const int half   = nt_all >> 1;
    const int t0 = (split && chunk == 1) ? half : 0;
    const int t1 = (split && chunk == 0) ? half : nt_all;

    const int q_row = qm + wave * 16 + l16;
    bf16x8 qa[2];
    qa[0] = *(const bf16x8*)(const void*)(Qg + (size_t)q_row * 64 + quad * 8);
    qa[1] = *(const bf16x8*)(const void*)(Qg + (size_t)q_row * 64 + 32 + quad * 8);

    f32x4 oacc[4];
    const f32x4 zro = {0.f, 0.f, 0.f, 0.f};
    #pragma unroll
    for (int j = 0; j < 4; ++j) oacc[j] = zro;
    float mst = -1e30f, lst = 0.f;

    const int ldr = tid >> 1, ldc = (tid & 1) * 32;

    for (int t = t0; t < t1; ++t) {
        const int jt = t * 64;
        #pragma unroll
        for (int c = 0; c < 4; ++c) {
            *(uint4*)(void*)&Ks[ldr][ldc + c * 8] =
                *(const uint4*)(const void*)(Kg + (size_t)(jt + ldr) * 64 + ldc + c * 8);
            *(uint4*)(void*)&Vs[ldr][ldc + c * 8] =
                *(const uint4*)(const void*)(Vg + (size_t)ldr * 2048 + jt + ldc + c * 8);
        }
        __syncthreads();

        f32x4 s[4];
        #pragma unroll
        for (int j = 0; j < 4; ++j) s[j] = zro;
        #pragma unroll
        for (int kk = 0; kk < 2; ++kk) {
            #pragma unroll
            for (int j = 0; j < 4; ++j) {
                bf16x8 kf = *(const bf16x8*)(const void*)&Ks[j*16 + l16][kk*32 + quad*8];
                s[j] = __builtin_amdgcn_mfma_f32_16x16x32_bf16(kf, qa[kk], s[j], 0, 0, 0);
            }
        }

        if (jt + 63 > q_row) {
            #pragma unroll
            for (int j = 0; j < 4; ++j) {
                #pragma unroll
                for (int r = 0; r < 4; ++r) {
                    int key = jt + j * 16 + quad * 4 + r;
                    if (key > q_row) s[j][r] = -1e30f;
                }
            }
        }

        float mq = s[0][0];
        #pragma unroll
        for (int j = 0; j < 4; ++j)
            #pragma unroll
            for (int r = 0; r < 4; ++r) mq = fmaxf(mq, s[j][r]);
        float sq = 0.f;
        #pragma unroll
        for (int j = 0; j < 4; ++j)
            #pragma unroll
            for (int r = 0; r < 4; ++r) {
                float v = __expf(s[j][r] - mq);
                s[j][r] = v; sq += v;
            }

        float mo = __shfl_xor(mq, 16);
        float so = __shfl_xor(sq, 16);
        float mm = fmaxf(mq, mo);
        sq = sq * __expf(mq - mm) + so * __expf(mo - mm);
        float mo2 = __shfl_xor(mm, 32);
        float so2 = __shfl_xor(sq, 32);
        float mtile = fmaxf(mm, mo2);
        float stile = sq * __expf(mm - mtile) + so2 * __expf(mo2 - mtile);

        float mn  = fmaxf(mst, mtile);
        float scl = __expf(mst - mn);
        lst = lst * scl + stile * __expf(mtile - mn);
        mst = mn;
        float pf = __expf(mq - mn);

        float sclq[4];
        #pragma unroll
        for (int r = 0; r < 4; ++r) sclq[r] = __shfl(scl, quad * 4 + r);
        #pragma unroll
        for (int j = 0; j < 4; ++j)
            #pragma unroll
            for (int r = 0; r < 4; ++r) oacc[j][r] *= sclq[r];

        #pragma unroll
        for (int j = 0; j < 4; ++j) {
            uint2 u;
            u.x = pk2(s[j][0] * pf, s[j][1] * pf);
            u.y = pk2(s[j][2] * pf, s[j][3] * pf);
            *(uint2*)(void*)&Ps[wave][l16][j * 16 + quad * 4] = u;
        }
        bf16x8 pa0 = *(const bf16x8*)(const void*)&Ps[wave][l16][quad * 8];
        bf16x8 pa1 = *(const bf16x8*)(const void*)&Ps[wave][l16][32 + quad * 8];

        #pragma unroll
        for (int j = 0; j < 4; ++j) {
            bf16x8 vb = *(const bf16x8*)(const void*)&Vs[j*16 + l16][quad*8];
            oacc[j] = __builtin_amdgcn_mfma_f32_16x16x32_bf16(pa0, vb, oacc[j], 0, 0, 0);
        }
        #pragma unroll
        for (int j = 0; j < 4; ++j) {
            bf16x8 vb = *(const bf16x8*)(const void*)&Vs[j*16 + l16][32 + quad*8];
            oacc[j] = __builtin_amdgcn_mfma_f32_16x16x32_bf16(pa1, vb, oacc[j], 0, 0, 0);
        }
        __syncthreads();
    }

    if (!split) {
        float invq[4];
        #pragma unroll
        for (int r = 0; r < 4; ++r) invq[r] = 1.f / __shfl(lst, quad * 4 + r);
        #pragma unroll
        for (int j = 0; j < 4; ++j) {
            #pragma unroll
            for (int r = 0; r < 4; ++r) {
                int tr = qm + wave * 16 + quad * 4 + r;
                o[((size_t)(b * 2048 + tr)) * 512 + h * 64 + j * 16 + l16] =
                    f2b(oacc[j][r] * invq[r]);
            }
        }
    } else {
        const int pidx = (bh * 32 + (qb - 32)) * 2 + chunk;
        float* Od = Opart + (size_t)pidx * 2048;
        #pragma unroll
        for (int j = 0; j < 4; ++j)
            #pragma unroll
            for (int r = 0; r < 4; ++r) {
                int lr = wave * 16 + quad * 4 + r;
                Od[lr * 64 + j * 16 + l16] = oacc[j][r];
            }
        if (quad == 0) {
            MLpart[(size_t)pidx * 64 + wave * 16 + l16]      = mst;
            MLpart[(size_t)pidx * 64 + 32 + wave * 16 + l16] = lst;
        }
    }
}

// ---------------------------------------------------------------------------
// Merge the 2 key-split chunks for qb in [32,63]. Grid (32,16), 128 thr.
// ---------------------------------------------------------------------------
__global__ __launch_bounds__(128) void flash_combine2(
    const float* __restrict__ Opart, const float* __restrict__ MLpart,
    bf16* __restrict__ o)
{
    int qb = 32 + blockIdx.x;
    int bh = blockIdx.y, b = bh >> 3, h = bh & 7;
    int base = (bh * 32 + (qb - 32)) * 2;
    int row = threadIdx.x >> 2;          // 0..31
    int d0  = (threadIdx.x & 3) * 16;    // 0,16,32,48
    float m0 = MLpart[(size_t)base * 64 + row];
    float l0 = MLpart[(size_t)base * 64 + 32 + row];
    float m1 = MLpart[(size_t)(base + 1) * 64 + row];
    float l1 = MLpart[(size_t)(base + 1) * 64 + 32 + row];
    float mstar = fmaxf(m0, m1);
    float w0 = __expf(m0 - mstar), w1 = __expf(m1 - mstar);
    float inv = 1.f / (l0 * w0 + l1 * w1);
    const float* O0 = Opart + (size_t)base * 2048 + row * 64 + d0;
    const float* O1 = O0 + 2048;
    int t = qb * 32 + row;
    bf16* op = o + ((size_t)(b * 2048 + t)) * 512 + h * 64 + d0;
    #pragma unroll 4
    for (int dd = 0; dd < 16; ++dd)
        op[dd] = f2b((O0[dd] * w0 + O1[dd] * w1) * inv);
}

// ---------------------------------------------------------------------------
static void launch_gemm(int epi, hipStream_t s,
                        const bf16* A, int lda, int zsA, int zsA2,
                        const bf16* Bt, int ldb, int zsB, int zsB2,
                        void* C, int ldc, int zsC, int zsC2,
                        const bf16* bias, int zsBias, float scale,
                        const bf16* resid,
                        int M, int N, int K, int nz)
{
    bool mt64 = ((M >> 7) * (N >> 7) * nz) <= 512;
    dim3 blk(256);
    if (mt64) {
        dim3 g(N / 128, M / 64, nz);
        switch (epi) {
        case 0: gemm_bt<0,64><<<g, blk, 0, s>>>(A, lda, zsA, zsA2, Bt, ldb, zsB, zsB2, C, ldc, zsC, zsC2, bias, zsBias, scale, resid, K); break;
        case 1: gemm_bt<1,64><<<g, blk, 0, s>>>(A, lda, zsA, zsA2, Bt, ldb, zsB, zsB2, C, ldc, zsC, zsC2, bias, zsBias, scale, resid, K); break;
        case 3: gemm_bt<3,64><<<g, blk, 0, s>>>(A, lda, zsA, zsA2, Bt, ldb, zsB, zsB2, C, ldc, zsC, zsC2, bias, zsBias, scale, resid, K); break;
        default: gemm_bt<2,64><<<g, blk, 0, s>>>(A, lda, zsA, zsA2, Bt, ldb, zsB, zsB2, C, ldc, zsC, zsC2, bias, zsBias, scale, resid, K); break;
        }
    } else {
        dim3 g(N / 128, M / 128, nz);
        switch (epi) {
        case 0: gemm_bt<0,128><<<g, blk, 0, s>>>(A, lda, zsA, zsA2, Bt, ldb, zsB, zsB2, C, ldc, zsC, zsC2, bias, zsBias, scale, resid, K); break;
        case 1: gemm_bt<1,128><<<g, blk, 0, s>>>(A, lda, zsA, zsA2, Bt, ldb, zsB, zsB2, C, ldc, zsC, zsC2, bias, zsBias, scale, resid, K); break;
        case 3: gemm_bt<3,128><<<g, blk, 0, s>>>(A, lda, zsA, zsA2, Bt, ldb, zsB, zsB2, C, ldc, zsC, zsC2, bias, zsBias, scale, resid, K); break;
        default: gemm_bt<2,128><<<g, blk, 0, s>>>(A, lda, zsA, zsA2, Bt, ldb, zsB, zsB2, C, ldc, zsC, zsC2, bias, zsBias, scale, resid, K); break;
        }
    }
}

extern "C" void kernel_launch(void* const* d_in, const int* in_sizes, int n_in,
                              void* d_out, int out_size, void* d_ws, size_t ws_size,
                              hipStream_t stream)
{
    const void* text  = d_in[0];
    const void* audio = d_in[1];
    const void* video = d_in[2];
    const void* Wa    = d_in[3];
    const void* ba    = d_in[4];
    const void* lna_g = d_in[5];
    const void* lna_b = d_in[6];
    const void* Wvid  = d_in[7];
    const void* bvid  = d_in[8];
    const void* lnv_g = d_in[9];
    const void* lnv_b = d_in[10];
    const void* ln1_g = d_in[11];
    const void* ln1_b = d_in[12];
    const void* Wq    = d_in[13];
    const void* Wkv   = d_in[14];
    const void* qn_g  = d_in[15];
    const void* kn_g  = d_in[16];
    const void* Wo    = d_in[17];
    const void* W1    = d_in[18];
    const void* b1    = d_in[19];
    const void* ln2_g = d_in[20];
    const void* ln2_b = d_in[21];
    const void* W2    = d_in[22];
    const void* b2    = d_in[23];

    char* ws = (char*)d_ws;
    size_t off = 0;
    auto alloc = [&](size_t bytes) -> char* {
        char* p = ws + off;
        off += (bytes + 255) & ~(size_t)255;
        return p;
    };
    const size_t MB = 1024 * 1024;
    int*  flag  = (int*)alloc(256);
    bf16* vecs  = (bf16*)alloc(14 * 4096 * 2);
    bf16* WqkvT = (bf16*)alloc((size_t)1536 * 1024 * 2);
    bf16* WoT   = (bf16*)alloc((size_t)1024 * 512 * 2);
    bf16* W1T   = (bf16*)alloc((size_t)4096 * 1024 * 2);
    bf16* W2T   = (bf16*)alloc((size_t)1024 * 4096 * 2);
    char* regionIn = alloc(24 * MB);   // audioC,videoC -> qkvF -> Opart/ML
    char* region2  = alloc(32 * MB);   // tmp2/tmpF/xF -> g
    char* regionH  = alloc(8 * MB);    // audioT -> h
    char* regionX  = alloc(8 * MB);    // videoT -> x2
    char* regionO  = alloc(4 * MB);    // WaT,WvT -> o
    bf16* qrot    = (bf16*)alloc((size_t)4096 * 1024 * 2);
    bf16* krotPad = (bf16*)alloc((size_t)2 * 2560 * 1024 * 2);
    bf16* VTpad   = (bf16*)alloc((size_t)2 * 1024 * 2560 * 2);
    bf16* attn    = (bf16*)alloc((size_t)8 * 512 * 1024 * 2);

    bf16*  audioC = (bf16*)regionIn;
    bf16*  videoC = audioC + (size_t)4096 * 1024;
    float* qkvF   = (float*)regionIn;
    bf16*  tmp2   = (bf16*)region2;          // adapter GEMM out (2 x 4096x1024 bf16)
    float* tmpF   = (float*)region2;         // sim scores f32
    float* xF     = (float*)(region2 + 16 * MB);
    bf16*  g      = (bf16*)region2;
    bf16*  audioT = (bf16*)regionH;
    bf16*  h      = (bf16*)regionH;
    bf16*  videoT = (bf16*)regionX;
    bf16*  x2     = (bf16*)regionX;
    bf16*  WaT    = (bf16*)regionO;
    bf16*  WvT    = WaT + (size_t)1024 * 1024;
    bf16*  o      = (bf16*)regionO;
    bf16*  Qp     = qrot;
    bf16*  Kp     = krotPad;
    bf16*  Vth    = attn;
    // flash 2-way-split partials (regionIn dead at flash time; 8.7 MB)
    float* Opart  = (float*)regionIn;
    float* MLpart = Opart + (size_t)1024 * 2048;

    bf16* baC   = vecs + 0 * 4096;
    bf16* bvidC = vecs + 1 * 4096;
    bf16* lnagC = vecs + 2 * 4096;
    bf16* lnabC = vecs + 3 * 4096;
    bf16* lnvgC = vecs + 4 * 4096;
    bf16* lnvbC = vecs + 5 * 4096;
    bf16* ln1gC = vecs + 6 * 4096;
    bf16* ln1bC = vecs + 7 * 4096;
    bf16* qngC  = vecs + 8 * 4096;
    bf16* kngC  = vecs + 9 * 4096;
    bf16* b1C   = vecs + 10 * 4096;
    bf16* ln2gC = vecs + 11 * 4096;
    bf16* ln2bC = vecs + 12 * 4096;
    bf16* b2C   = vecs + 13 * 4096;

    // 1) dtype flag
    detect_dtype<<<1, 64, 0, stream>>>((const unsigned short*)text, flag);

    // 2) canonicalize audio+video (one launch) + small vectors
    const int NTOK = 4096 * 1024;
    convert2<<<4096, 256, 0, stream>>>(audio, video, audioC, videoC, NTOK, flag);
    VecPack vp;
    const void* vsrc[14] = {ba, bvid, lna_g, lna_b, lnv_g, lnv_b, ln1_g, ln1_b,
                            qn_g, kn_g, b1, ln2_g, ln2_b, b2};
    int vn[14] = {1024, 1024, 1024, 1024, 1024, 1024, 1024, 1024,
                  64, 64, 4096, 4096, 4096, 1024};
    for (int i = 0; i < 14; ++i) { vp.src[i] = vsrc[i]; vp.n[i] = vn[i]; }
    convert_vecs<<<14, 256, 0, stream>>>(vp, vecs, flag);

    // 3) weight transposes
    dim3 tb(32, 8);
    transpose_any<<<dim3(32, 32), tb, 0, stream>>>(Wa, 1024, 1024, (unsigned short*)WaT, 1024, flag);
    transpose_any<<<dim3(32, 32), tb, 0, stream>>>(Wvid, 1024, 1024, (unsigned short*)WvT, 1024, flag);
    transpose_any<<<dim3(16, 32), tb, 0, stream>>>(Wq, 1024, 512, (unsigned short*)WqkvT, 1024, flag);
    transpose_any<<<dim3(32, 32), tb, 0, stream>>>(Wkv, 1024, 1024, (unsigned short*)(WqkvT + (size_t)512 * 1024), 1024, flag);
    transpose_any<<<dim3(32, 16), tb, 0, stream>>>(Wo, 512, 1024, (unsigned short*)WoT, 512, flag);
    transpose_any<<<dim3(128, 32), tb, 0, stream>>>(W1, 1024, 4096, (unsigned short*)W1T, 1024, flag);
    transpose_any<<<dim3(32, 128), tb, 0, stream>>>(W2, 4096, 1024, (unsigned short*)W2T, 4096, flag);

    // 4) adapters: one batched GEMM (nz=2, bf16 out w/ bias) + merged LN
    launch_gemm(1, stream, audioC, 1024, 4096*1024, 0, WaT, 1024, 1024*1024, 0,
                tmp2, 1024, 4096*1024, 0, baC, 4096, 1.f, nullptr, 4096, 1024, 1024, 2);
    ln_rows2<<<8192, 256, 0, stream>>>(tmp2, lnagC, lnabC, lnvgC, lnvbC, audioT, videoT);

    // 5) pads, rotary (raw text), batched VTpad transpose
    hipMemsetAsync(krotPad, 0, (size_t)2 * 2560 * 1024 * 2, stream);
    hipMemsetAsync(VTpad, 0, (size_t)2 * 1024 * 2560 * 2, stream);
    rotary_kernel<<<4096, 256, 0, stream>>>(text, flag, audioT, qrot, krotPad);
    transpose_vt<<<dim3(32, 64, 2), tb, 0, stream>>>(
        (const unsigned short*)videoT, (unsigned short*)VTpad);

    // 6) local attention: batched sim (nz=8) -> softmax -> batched @V (nz=8)
    launch_gemm(0, stream, qrot, 1024, 512*1024, 0,
                krotPad, 1024, 512*1024, 512*1024,
                tmpF, 1024, 512*1024, 0, nullptr, 0, 1.f, nullptr, 512, 1024, 1024, 8);
    softmax_local<<<dim3(512, 8), 256, 0, stream>>>(tmpF, attn);
    launch_gemm(0, stream, attn, 1024, 512*1024, 0,
                VTpad, 2560, 512, 1024*2560 - 2048,
                xF, 1024, 512*1024, 0, nullptr, 0, 1.f, nullptr, 512, 1024, 1024, 8);

    // 7) ln1 -> qkv -> pack -> V transpose -> 2-way-split swapped flash
    ln_f32_1024<<<4096, 256, 0, stream>>>(xF, ln1gC, ln1bC, h);
    launch_gemm(0, stream, h, 1024, 0, 0, WqkvT, 1024, 0, 0,
                qkvF, 1536, 0, 0, nullptr, 0, 1.f, nullptr, 4096, 1536, 1024, 1);
    pack_qk<<<16384, 256, 0, stream>>>(qkvF, Qp, Kp, qngC, kngC);
    transpose_v<<<dim3(2, 64, 16), tb, 0, stream>>>(qkvF, Vth);
    flash_fused6<<<dim3(96, 16), 128, 0, stream>>>(Qp, Kp, Vth, o, Opart, MLpart);
    flash_combine2<<<dim3(32, 16), 128, 0, stream>>>(Opart, MLpart, o);

    // 8) x2 = 2*(o@Wo) ; g = gelu(x2@W1+b1) via 8-phase 256^2 ; ln2 ;
    //    FF2 single GEMM with fused epilogue: out = g@W2T + b2 + x2.
    launch_gemm(1, stream, o, 512, 0, 0, WoT, 512, 0, 0,
                x2, 1024, 0, 0, nullptr, 0, 2.f, nullptr, 4096, 1024, 512, 1);
    gemm_ff1_8ph<<<dim3(16, 16), 512, 0, stream>>>(x2, 1024, W1T, 1024,
                                                   g, 4096, b1C, 1024);
    ln_b16_4096<<<4096, 256, 0, stream>>>(g, ln2gC, ln2bC, g);
    launch_gemm(3, stream, g, 4096, 0, 0, W2T, 4096, 0, 0,
                d_out, 1024, 0, 0, b2C, 0, 1.f, x2, 4096, 1024, 4096, 1);

    (void)in_sizes; (void)n_in; (void)out_size; (void)ws_size;
}

// Round 10
// 537.431 us; speedup vs baseline: 1.2083x; 1.0221x over previous
//
#include <hip/hip_runtime.h>
#include <hip/hip_bf16.h>

typedef __bf16 bf16;
typedef __bf16 bf16x8 __attribute__((ext_vector_type(8)));
typedef __bf16 bf16x4 __attribute__((ext_vector_type(4)));
typedef float  f32x4  __attribute__((ext_vector_type(4)));

static __device__ __forceinline__ float b2f(bf16 x) { return (float)x; }
static __device__ __forceinline__ bf16  f2b(float x) { return (bf16)x; }

// pack two floats -> one uint holding two bf16 (low = a, high = b)
static __device__ __forceinline__ unsigned pk2(float a, float b)
{
    bf16 x = f2b(a), y = f2b(b);
    unsigned short ux = *(unsigned short*)&x;
    unsigned short uy = *(unsigned short*)&y;
    return (unsigned)ux | ((unsigned)uy << 16);
}

// async global->LDS, 16B per lane; lds dest is wave-uniform base (+lane*16)
static __device__ __forceinline__ void gl_lds16(const bf16* g, bf16* l)
{
    __builtin_amdgcn_global_load_lds(
        (const __attribute__((address_space(1))) void*)g,
        (__attribute__((address_space(3))) void*)l,
        16, 0, 0);
}

// ---------------------------------------------------------------------------
// dtype detection: flag=1 -> f32 inputs.
// ---------------------------------------------------------------------------
__global__ void detect_dtype(const unsigned short* __restrict__ p, int* __restrict__ flag)
{
    if (threadIdx.x == 0 && blockIdx.x == 0) {
        int big = 0;
        for (int i = 0; i < 512; ++i) {
            int e = (p[i] >> 7) & 0xFF;
            if (e >= 0xE0) big++;
        }
        *flag = (big > 0) ? 1 : 0;
    }
}

// convert two tensors in one launch (grid split in half)
__global__ __launch_bounds__(256) void convert2(
    const void* __restrict__ sa, const void* __restrict__ sb,
    bf16* __restrict__ da, bf16* __restrict__ db, int n,
    const int* __restrict__ flag)
{
    int f = *flag;
    int half = gridDim.x >> 1;
    const void* s = (blockIdx.x < half) ? sa : sb;
    bf16* d = (blockIdx.x < half) ? da : db;
    int bid = (blockIdx.x < half) ? blockIdx.x : blockIdx.x - half;
    for (int i = bid * 256 + threadIdx.x; i < n; i += half * 256) {
        float v = f ? ((const float*)s)[i] : (float)((const bf16*)s)[i];
        d[i] = f2b(v);
    }
}

struct VecPack { const void* src[14]; int n[14]; };
__global__ __launch_bounds__(256) void convert_vecs(
    VecPack vp, bf16* __restrict__ dst, const int* __restrict__ flag)
{
    int v = blockIdx.x;
    int f = *flag;
    const void* s = vp.src[v];
    int n = vp.n[v];
    bf16* d = dst + (size_t)v * 4096;
    for (int i = threadIdx.x; i < n; i += 256) {
        float x = f ? ((const float*)s)[i] : (float)((const bf16*)s)[i];
        d[i] = f2b(x);
    }
}

// ---------------------------------------------------------------------------
// GEMM: C[M,N] = A[M,K] @ Bt[n][k]. MT x 128 tile, BK=64, 4 waves.
// EPI: 0 = f32 store (+bias)   1 = bf16 (v+bias)*scale   2 = bf16 gelu
//      3 = f32 store v + bias + resid[off] (fused FF2 epilogue)
// T1 XCD-chunked swizzle when gz==1 and (gx*gy)%8==0: each XCD gets a
// contiguous chunk of the logical grid -> per-XCD L2-resident B panel.
// ---------------------------------------------------------------------------
template <int EPI, int MT>
__global__ __launch_bounds__(256) void gemm_bt(
    const bf16* __restrict__ A0, int lda, int zsA, int zsA2,
    const bf16* __restrict__ B0, int ldb, int zsB, int zsB2,
    void* __restrict__ C0, int ldc, int zsC, int zsC2,
    const bf16* __restrict__ bias, int zsBias, float scale,
    const bf16* __restrict__ resid, int K)
{
    constexpr int IFR = MT / 32;
    __shared__ __align__(16) bf16 As[MT * 64];
    __shared__ __align__(16) bf16 Bs[128 * 64];
    int bx = blockIdx.x, by = blockIdx.y;
    {
        const int gx = gridDim.x, gy = gridDim.y;
        const int T = gx * gy;
        if (gridDim.z == 1 && (T & 7) == 0) {
            int hw = by * gx + bx;
            int lid = (hw & 7) * (T >> 3) + (hw >> 3);
            bx = lid % gx; by = lid / gx;
        }
    }
    const int z = blockIdx.z;
    const bf16* A  = A0 + (size_t)z * zsA + (size_t)(z >> 2) * zsA2;
    const bf16* Bt = B0 + (size_t)z * zsB + (size_t)(z >> 2) * zsB2;
    const size_t cbase = (size_t)z * zsC + (size_t)(z >> 2) * zsC2;
    if (bias) bias += (size_t)z * zsBias;
    const int tid  = threadIdx.x;
    const int lane = tid & 63, wave = tid >> 6;
    const int quad = lane >> 4, l16 = lane & 15;
    const size_t tm = (size_t)by * MT, tn = (size_t)bx * 128;
    const int wm = (wave >> 1) * (MT / 2), wn = (wave & 1) * 64;
    const int srow = lane >> 3;
    const int scol = ((lane & 7) ^ srow) * 8;

    f32x4 acc[IFR][4];
    const f32x4 zro = {0.f, 0.f, 0.f, 0.f};
    #pragma unroll
    for (int i = 0; i < IFR; ++i)
        #pragma unroll
        for (int j = 0; j < 4; ++j) acc[i][j] = zro;

    const int swzA = l16 & 7;
    for (int k0 = 0; k0 < K; k0 += 64) {
        #pragma unroll
        for (int i = 0; i < IFR; ++i) {
            int chunk = (wave * IFR + i) * 64;
            int row = (chunk >> 3) + srow;
            gl_lds16(A + (tm + row) * (size_t)lda + k0 + scol, As + (size_t)chunk * 8);
        }
        #pragma unroll
        for (int i = 0; i < 4; ++i) {
            int chunk = (wave * 4 + i) * 64;
            int row = (chunk >> 3) + srow;
            gl_lds16(Bt + (tn + row) * (size_t)ldb + k0 + scol, Bs + (size_t)chunk * 8);
        }
        __syncthreads();
        #pragma unroll
        for (int kk = 0; kk < 2; ++kk) {
            bf16x8 af[IFR], bfr[4];
            #pragma unroll
            for (int i = 0; i < IFR; ++i) {
                int row = wm + i * 16 + l16;
                af[i] = *(const bf16x8*)(const void*)&As[(row * 8 + ((kk*4 + quad) ^ swzA)) * 8];
            }
            #pragma unroll
            for (int j = 0; j < 4; ++j) {
                int row = wn + j * 16 + l16;
                bfr[j] = *(const bf16x8*)(const void*)&Bs[(row * 8 + ((kk*4 + quad) ^ swzA)) * 8];
            }
            #pragma unroll
            for (int i = 0; i < IFR; ++i)
                #pragma unroll
                for (int j = 0; j < 4; ++j)
                    acc[i][j] = __builtin_amdgcn_mfma_f32_16x16x32_bf16(
                        af[i], bfr[j], acc[i][j], 0, 0, 0);
        }
        __syncthreads();
    }

    float* Cf = (float*)C0;
    bf16*  Cb = (bf16*)C0;
    #pragma unroll
    for (int i = 0; i < IFR; ++i) {
        #pragma unroll
        for (int j = 0; j < 4; ++j) {
            size_t col = tn + wn + j*16 + l16;
            float bb = bias ? b2f(bias[col]) : 0.f;
            #pragma unroll
            for (int r = 0; r < 4; ++r) {
                size_t row = tm + wm + i*16 + quad*4 + r;
                float v = acc[i][j][r] + bb;
                size_t off = cbase + row * (size_t)ldc + col;
                if (EPI == 0) {
                    Cf[off] = v;
                } else if (EPI == 1) {
                    Cb[off] = f2b(v * scale);
                } else if (EPI == 3) {
                    Cf[off] = v + b2f(resid[off]);
                } else {
                    float g = 0.5f * v * (1.f + tanhf(0.7978845608028654f *
                                  (v + 0.044715f * v * v * v)));
                    Cb[off] = f2b(g);
                }
            }
        }
    }
}

// ---------------------------------------------------------------------------
// FF1 GEMM, 256x256 tile, BK=64, 8 waves, 8-phase-style pipelined schedule.
// C[M,N] = gelu(A[M,K] @ Bt[N,K]^T + bias), bf16 out.
// ---------------------------------------------------------------------------
__global__ __launch_bounds__(512, 2) void gemm_ff1_8ph(
    const bf16* __restrict__ A, int lda,
    const bf16* __restrict__ Bt, int ldb,
    bf16* __restrict__ C, int ldc,
    const bf16* __restrict__ bias, int K)
{
    __shared__ __align__(16) bf16 As[2][256 * 64];
    __shared__ __align__(16) bf16 Bs[2][256 * 64];
    const int tid  = threadIdx.x;
    const int lane = tid & 63, wave = tid >> 6;
    const int quad = lane >> 4, l16 = lane & 15;
    const int wr = wave >> 2, wc = wave & 3;          // 2M x 4N wave grid
    const size_t tm = (size_t)blockIdx.y * 256;
    const size_t tn = (size_t)blockIdx.x * 256;
    const int srow = lane >> 3;
    const int scol = ((lane & 7) ^ srow) * 8;         // pre-swizzled global col
    const int swz  = l16 & 7;                         // read-side swizzle

    f32x4 acc[8][4];
    const f32x4 zro = {0.f, 0.f, 0.f, 0.f};
    #pragma unroll
    for (int m = 0; m < 8; ++m)
        #pragma unroll
        for (int n = 0; n < 4; ++n) acc[m][n] = zro;

    const bf16* aSrc[4];
    const bf16* bSrc[4];
    #pragma unroll
    for (int i = 0; i < 4; ++i) {
        int grow = wave * 32 + i * 8 + srow;
        aSrc[i] = A  + (tm + grow) * (size_t)lda + scol;
        bSrc[i] = Bt + (tn + grow) * (size_t)ldb + scol;
    }

#define STAGE(BUF, K0, I)                                                     \
    do {                                                                      \
        gl_lds16(aSrc[I] + (K0), &As[BUF][(wave * 4 + (I)) * 512]);           \
        gl_lds16(bSrc[I] + (K0), &Bs[BUF][(wave * 4 + (I)) * 512]);           \
    } while (0)

#define LDA_F(BUF, M, KK)                                                     \
    (*(const bf16x8*)(const void*)&As[BUF][(wr * 128 + (M) * 16 + l16) * 64 + \
        ((((KK) * 4 + quad) ^ swz) << 3)])
#define LDB_F(BUF, N, KK)                                                     \
    (*(const bf16x8*)(const void*)&Bs[BUF][(wc * 64 + (N) * 16 + l16) * 64 +  \
        ((((KK) * 4 + quad) ^ swz) << 3)])

#define PHASE(M0, M1, PREF_STMT, TAIL_STMT)                                   \
    {                                                                         \
        PREF_STMT;                                                            \
        bf16x8 x0 = LDA_F(cur, M0, 0), x1 = LDA_F(cur, M0, 1);                \
        bf16x8 y0 = LDA_F(cur, M1, 0), y1 = LDA_F(cur, M1, 1);                \
        asm volatile("s_barrier" ::: "memory");                               \
        __builtin_amdgcn_s_setprio(1);                                        \
        _Pragma("unroll")                                                     \
        for (int n = 0; n < 4; ++n) {                                         \
            acc[M0][n] = __builtin_amdgcn_mfma_f32_16x16x32_bf16(x0, bfr[n][0], acc[M0][n], 0, 0, 0); \
            acc[M0][n] = __builtin_amdgcn_mfma_f32_16x16x32_bf16(x1, bfr[n][1], acc[M0][n], 0, 0, 0); \
            acc[M1][n] = __builtin_amdgcn_mfma_f32_16x16x32_bf16(y0, bfr[n][0], acc[M1][n], 0, 0, 0); \
            acc[M1][n] = __builtin_amdgcn_mfma_f32_16x16x32_bf16(y1, bfr[n][1], acc[M1][n], 0, 0, 0); \
        }                                                                     \
        __builtin_amdgcn_s_setprio(0);                                        \
        TAIL_STMT;                                                            \
        asm volatile("s_barrier" ::: "memory");                               \
    }

    #pragma unroll
    for (int i = 0; i < 4; ++i) STAGE(0, 0, i);
    asm volatile("s_waitcnt vmcnt(0)" ::: "memory");
    asm volatile("s_barrier" ::: "memory");

    const int NT = K >> 6;
    bf16x8 bfr[4][2];
    for (int t = 0; t < NT; ++t) {
        const int cur = t & 1, nxt = cur ^ 1;
        const int k1  = (t + 1) << 6;
        const bool pref = (t + 1 < NT);

        #pragma unroll
        for (int n = 0; n < 4; ++n) {
            bfr[n][0] = LDB_F(cur, n, 0);
            bfr[n][1] = LDB_F(cur, n, 1);
        }
        PHASE(0, 1,
              if (pref) { STAGE(nxt, k1, 0); STAGE(nxt, k1, 1); }, )
        PHASE(2, 3,
              if (pref) { STAGE(nxt, k1, 2); STAGE(nxt, k1, 3); }, )
        PHASE(4, 5, , )
        PHASE(6, 7, ,
              asm volatile("s_waitcnt vmcnt(0)" ::: "memory"))
    }
#undef PHASE
#undef LDB_F
#undef LDA_F
#undef STAGE

    // epilogue: bias + fast gelu (v * sigmoid(1.59577 v + 0.0713548 v^3))
    #pragma unroll
    for (int m = 0; m < 8; ++m) {
        #pragma unroll
        for (int n = 0; n < 4; ++n) {
            size_t col = tn + wc * 64 + n * 16 + l16;
            float bb = b2f(bias[col]);
            #pragma unroll
            for (int r = 0; r < 4; ++r) {
                size_t row = tm + wr * 128 + m * 16 + quad * 4 + r;
                float v = acc[m][n][r] + bb;
                float s = v * (1.5957691216057308f + 0.07135481627f * v * v);
                float g = v / (1.f + __expf(-s));
                C[row * (size_t)ldc + col] = f2b(g);
            }
        }
    }
}

// ---------------------------------------------------------------------------
// dtype-branching transpose for raw weight inputs -> bf16 transposed
// ---------------------------------------------------------------------------
__global__ void transpose_any(const void* __restrict__ in, int R, int C,
                              unsigned short* __restrict__ out, int ldo,
                              const int* __restrict__ flag)
{
    __shared__ unsigned short t[32][33];
    int f = *flag;
    int c0 = blockIdx.x * 32, r0 = blockIdx.y * 32;
    int tx = threadIdx.x, ty = threadIdx.y;
    for (int i = ty; i < 32; i += 8) {
        size_t idx = (size_t)(r0 + i) * C + c0 + tx;
        bf16 v = f ? f2b(((const float*)in)[idx]) : ((const bf16*)in)[idx];
        t[i][tx] = *(unsigned short*)&v;
    }
    __syncthreads();
    for (int i = ty; i < 32; i += 8)
        out[(size_t)(c0 + i) * ldo + r0 + tx] = t[tx][i];
}

// videoT [b][2048][1024] -> VTpad [b][1024][512 + 2048] (col offset 512), z=b
__global__ void transpose_vt(const unsigned short* __restrict__ in,
                             unsigned short* __restrict__ out)
{
    __shared__ unsigned short t[32][33];
    int b = blockIdx.z;
    const unsigned short* src = in + (size_t)b * 2048 * 1024;
    unsigned short* dst = out + (size_t)b * 1024 * 2560;
    int c0 = blockIdx.x * 32, r0 = blockIdx.y * 32;
    int tx = threadIdx.x, ty = threadIdx.y;
    for (int i = ty; i < 32; i += 8)
        t[i][tx] = src[(size_t)(r0 + i) * 1024 + c0 + tx];
    __syncthreads();
    for (int i = ty; i < 32; i += 8)
        dst[(size_t)(c0 + i) * 2560 + 512 + r0 + tx] = t[tx][i];
}

// ---------------------------------------------------------------------------
// V transpose into per-head Vt[bh][64][2048] bf16.
// ---------------------------------------------------------------------------
__global__ void transpose_v(const float* __restrict__ qkv, bf16* __restrict__ Vt)
{
    __shared__ float t[32][33];
    int bh = blockIdx.z, b = bh >> 3, h = bh & 7;
    const float* src = qkv + (size_t)b * 2048 * 1536 + 1024 + h * 64;
    int c0 = blockIdx.x * 32, r0 = blockIdx.y * 32;
    int tx = threadIdx.x, ty = threadIdx.y;
    for (int i = ty; i < 32; i += 8)
        t[i][tx] = src[(size_t)(r0 + i) * 1536 + c0 + tx];
    __syncthreads();
    bf16* dst = Vt + (size_t)bh * 64 * 2048;
    for (int i = ty; i < 32; i += 8)
        dst[(size_t)(c0 + i) * 2048 + r0 + tx] = f2b(t[tx][i]);
}

// ---------------------------------------------------------------------------
// Vectorized row LayerNorms (G13): values held in registers, single read.
// ---------------------------------------------------------------------------
// f32 input, C=1024: one float4 per thread.
__global__ __launch_bounds__(256) void ln_f32_1024(
    const float* __restrict__ in,
    const bf16* __restrict__ g, const bf16* __restrict__ b,
    bf16* __restrict__ out)
{
    const int row = blockIdx.x, tid = threadIdx.x;
    f32x4 v = *(const f32x4*)(in + (size_t)row * 1024 + tid * 4);
    float s  = v[0] + v[1] + v[2] + v[3];
    float ss = v[0]*v[0] + v[1]*v[1] + v[2]*v[2] + v[3]*v[3];
    #pragma unroll
    for (int d = 32; d > 0; d >>= 1) { s += __shfl_xor(s, d); ss += __shfl_xor(ss, d); }
    __shared__ float red[2][4];
    int wave = tid >> 6, lane = tid & 63;
    if (lane == 0) { red[0][wave] = s; red[1][wave] = ss; }
    __syncthreads();
    s  = red[0][0] + red[0][1] + red[0][2] + red[0][3];
    ss = red[1][0] + red[1][1] + red[1][2] + red[1][3];
    float mu   = s * (1.f / 1024.f);
    float var  = ss * (1.f / 1024.f) - mu * mu;
    float rstd = rsqrtf(var + 1e-5f);
    bf16x4 g4 = *(const bf16x4*)(const void*)(g + tid * 4);
    bf16x4 b4 = *(const bf16x4*)(const void*)(b + tid * 4);
    bf16x4 o4;
    #pragma unroll
    for (int j = 0; j < 4; ++j)
        o4[j] = f2b((v[j] - mu) * rstd * b2f(g4[j]) + b2f(b4[j]));
    *(bf16x4*)(void*)(out + (size_t)row * 1024 + tid * 4) = o4;
}

// bf16 input, C=4096: two bf16x8 per thread (in-place safe).
__global__ __launch_bounds__(256) void ln_b16_4096(
    const bf16* __restrict__ in,
    const bf16* __restrict__ g, const bf16* __restrict__ b,
    bf16* __restrict__ out)
{
    const int row = blockIdx.x, tid = threadIdx.x;
    const bf16* p = in + (size_t)row * 4096;
    bf16x8 v0 = *(const bf16x8*)(const void*)(p + tid * 8);
    bf16x8 v1 = *(const bf16x8*)(const void*)(p + 2048 + tid * 8);
    float f0[8], f1[8];
    float s = 0.f, ss = 0.f;
    #pragma unroll
    for (int j = 0; j < 8; ++j) {
        f0[j] = b2f(v0[j]); f1[j] = b2f(v1[j]);
        s += f0[j] + f1[j];
        ss += f0[j]*f0[j] + f1[j]*f1[j];
    }
    #pragma unroll
    for (int d = 32; d > 0; d >>= 1) { s += __shfl_xor(s, d); ss += __shfl_xor(ss, d); }
    __shared__ float red[2][4];
    int wave = tid >> 6, lane = tid & 63;
    if (lane == 0) { red[0][wave] = s; red[1][wave] = ss; }
    __syncthreads();
    s  = red[0][0] + red[0][1] + red[0][2] + red[0][3];
    ss = red[1][0] + red[1][1] + red[1][2] + red[1][3];
    float mu   = s * (1.f / 4096.f);
    float var  = ss * (1.f / 4096.f) - mu * mu;
    float rstd = rsqrtf(var + 1e-5f);
    bf16x8 g0 = *(const bf16x8*)(const void*)(g + tid * 8);
    bf16x8 b0 = *(const bf16x8*)(const void*)(b + tid * 8);
    bf16x8 g1 = *(const bf16x8*)(const void*)(g + 2048 + tid * 8);
    bf16x8 b1 = *(const bf16x8*)(const void*)(b + 2048 + tid * 8);
    bf16x8 o0, o1;
    #pragma unroll
    for (int j = 0; j < 8; ++j) {
        o0[j] = f2b((f0[j] - mu) * rstd * b2f(g0[j]) + b2f(b0[j]));
        o1[j] = f2b((f1[j] - mu) * rstd * b2f(g1[j]) + b2f(b1[j]));
    }
    bf16* q = out + (size_t)row * 4096;
    *(bf16x8*)(void*)(q + tid * 8)        = o0;
    *(bf16x8*)(void*)(q + 2048 + tid * 8) = o1;
}

// both adapter LNs in one launch: rows 0..4095 audio, 4096..8191 video. C=1024.
__global__ __launch_bounds__(256) void ln_rows2(
    const bf16* __restrict__ in,
    const bf16* __restrict__ g0, const bf16* __restrict__ b0,
    const bf16* __restrict__ g1, const bf16* __restrict__ b1,
    bf16* __restrict__ out0, bf16* __restrict__ out1)
{
    const int row = blockIdx.x, tid = threadIdx.x;
    const int sel = row >> 12;
    const bf16* p = in + (size_t)row * 1024;
    const bf16* g = sel ? g1 : g0;
    const bf16* b = sel ? b1 : b0;
    bf16* q = (sel ? out1 + (size_t)(row - 4096) * 1024 : out0 + (size_t)row * 1024);
    bf16x4 v4 = *(const bf16x4*)(const void*)(p + tid * 4);
    float f[4];
    float s = 0.f, ss = 0.f;
    #pragma unroll
    for (int j = 0; j < 4; ++j) {
        f[j] = b2f(v4[j]);
        s += f[j]; ss += f[j]*f[j];
    }
    #pragma unroll
    for (int d = 32; d > 0; d >>= 1) { s += __shfl_xor(s, d); ss += __shfl_xor(ss, d); }
    __shared__ float red[2][4];
    int wave = tid >> 6, lane = tid & 63;
    if (lane == 0) { red[0][wave] = s; red[1][wave] = ss; }
    __syncthreads();
    s  = red[0][0] + red[0][1] + red[0][2] + red[0][3];
    ss = red[1][0] + red[1][1] + red[1][2] + red[1][3];
    float mu   = s * (1.f / 1024.f);
    float var  = ss * (1.f / 1024.f) - mu * mu;
    float rstd = rsqrtf(var + 1e-5f);
    bf16x4 g4 = *(const bf16x4*)(const void*)(g + tid * 4);
    bf16x4 b4 = *(const bf16x4*)(const void*)(b + tid * 4);
    bf16x4 o4;
    #pragma unroll
    for (int j = 0; j < 4; ++j)
        o4[j] = f2b((f[j] - mu) * rstd * b2f(g4[j]) + b2f(b4[j]));
    *(bf16x4*)(void*)(q + tid * 4) = o4;
}

// ---------------------------------------------------------------------------
// Rotary (reads raw text via flag): qrot = rope(text)*DIM^-0.5 ;
// krotPad[b][512+t] = rope(audio_t).
// ---------------------------------------------------------------------------
__global__ __launch_bounds__(256) void rotary_kernel(
    const void* __restrict__ text, const int* __restrict__ flag,
    const bf16* __restrict__ audioT,
    bf16* __restrict__ qrot, bf16* __restrict__ krotPad)
{
    int row = blockIdx.x;
    int t = row & 2047, b = row >> 11;
    int tid = threadIdx.x;
    int f = *flag;
    const float lg = 9.210340371976184f / 512.f;
    size_t base = (size_t)row * 1024;
    size_t kb = ((size_t)(b * 2560 + 512 + t)) * 1024;
    for (int c = tid; c < 512; c += 256) {
        float invf = __expf(-(float)c * lg);
        float th = (float)t * invf;
        float sn, cs;
        sincosf(th, &sn, &cs);
        float q1 = f ? ((const float*)text)[base + c]
                     : b2f(((const bf16*)text)[base + c]);
        float q2 = f ? ((const float*)text)[base + c + 512]
                     : b2f(((const bf16*)text)[base + c + 512]);
        qrot[base + c]       = f2b((q1 * cs - q2 * sn) * 0.03125f);
        qrot[base + c + 512] = f2b((q2 * cs + q1 * sn) * 0.03125f);
        float k1 = b2f(audioT[base + c]), k2 = b2f(audioT[base + c + 512]);
        krotPad[kb + c]       = f2b(k1 * cs - k2 * sn);
        krotPad[kb + c + 512] = f2b(k2 * cs + k1 * sn);
    }
}

// ---------------------------------------------------------------------------
// Local-attention masked softmax. sim [b][w][512][1024] f32 -> attn bf16.
// ---------------------------------------------------------------------------
__global__ __launch_bounds__(256) void softmax_local(
    const float* __restrict__ sim, bf16* __restrict__ attn)
{
    int i  = blockIdx.x;
    int zz = blockIdx.y;
    int w  = zz & 3;
    int tid = threadIdx.x;
    const float* p = sim + ((size_t)zz * 512 + i) * 1024;
    bf16* q = attn + ((size_t)zz * 512 + i) * 1024;
    int jlo = (w == 0) ? 512 : 0;
    int jhi = 512 + i;
    float m = -1e30f;
    #pragma unroll
    for (int k = 0; k < 4; ++k) {
        int c = tid + k * 256;
        if (c >= jlo && c <= jhi) m = fmaxf(m, p[c]);
    }
    #pragma unroll
    for (int d = 32; d > 0; d >>= 1) m = fmaxf(m, __shfl_xor(m, d));
    __shared__ float red[2][4];
    int wave = tid >> 6, lane = tid & 63;
    if (lane == 0) red[0][wave] = m;
    __syncthreads();
    m = fmaxf(fmaxf(red[0][0], red[0][1]), fmaxf(red[0][2], red[0][3]));
    float pv[4];
    float s = 0.f;
    #pragma unroll
    for (int k = 0; k < 4; ++k) {
        int c = tid + k * 256;
        float e = (c >= jlo && c <= jhi) ? __expf(p[c] - m) : 0.f;
        pv[k] = e; s += e;
    }
    #pragma unroll
    for (int d = 32; d > 0; d >>= 1) s += __shfl_xor(s, d);
    if (lane == 0) red[1][wave] = s;
    __syncthreads();
    s = red[1][0] + red[1][1] + red[1][2] + red[1][3];
    float inv = 1.f / s;
    #pragma unroll
    for (int k = 0; k < 4; ++k) q[tid + k * 256] = f2b(pv[k] * inv);
}

// ---------------------------------------------------------------------------
// pack_qk: RMSNorm q/k from qkv f32 [4096][1536] -> per-head bf16 buffers.
// ---------------------------------------------------------------------------
__global__ __launch_bounds__(256) void pack_qk(
    const float* __restrict__ qkv, bf16* __restrict__ Qp, bf16* __restrict__ Kp,
    const bf16* __restrict__ qn_g, const bf16* __restrict__ kn_g)
{
    int gid  = blockIdx.x * 4 + (threadIdx.x >> 6);
    int lane = threadIdx.x & 63;
    int token = gid >> 4, r = gid & 15, part = r >> 3, h = r & 7;
    const float* p = qkv + (size_t)token * 1536 + part * 512 + h * 64 + lane;
    float v = *p;
    float ss = v * v;
    #pragma unroll
    for (int d = 32; d > 0; d >>= 1) ss += __shfl_xor(ss, d);
    float sc = rsqrtf(ss * (1.f / 64.f) + 1e-6f);
    const bf16* gw = part ? kn_g : qn_g;
    float outv = v * sc * b2f(gw[lane]);
    if (!part) outv *= 0.125f;
    int b = token >> 11, t = token & 2047;
    bf16* dst = (part ? Kp : Qp) + ((size_t)(b * 8 + h) * 2048 + t) * 64 + lane;
    *dst = f2b(outv);
}

// ---------------------------------------------------------------------------
// Fused causal flash attention (D=64), swapped-operand softmax + 2-way
// key-split for long blocks (qb >= 32). Grid (96,16), 128 thr. (R8 verified)
// ---------------------------------------------------------------------------
__global__ __launch_bounds__(128) void flash_fused6(
    const bf16* __restrict__ Qp, const bf16* __restrict__ Kp,
    const bf16* __restrict__ Vt, bf16* __restrict__ o,
    float* __restrict__ Opart, float* __restrict__ MLpart)
{
    __shared__ __align__(16) bf16 Ks[64][72];
    __shared__ __align__(16) bf16 Vs[64][72];
    __shared__ __align__(16) bf16 Ps[2][16][72];
    const int bx = blockIdx.x;
    const int qb = (bx < 64) ? (63 - bx) : (63 - (bx - 64));
    const int chunk = (bx < 64) ? 0 : 1;
    const bool split = (qb >= 32);
    const int bh = blockIdx.y, b = bh >> 3, h = bh & 7;
    const int qm = qb * 32;
    const int tid = threadIdx.x, wave = tid >> 6, lane = tid & 63;
    const int quad = lane >> 4, l16 = lane & 15;
    const bf16* Qg = Qp + (size_t)bh * 2048 * 64;
    const bf16* Kg = Kp + (size_t)bh * 2048 * 64;
    const bf16* Vg = Vt + (size_t)bh * 64 * 2048;

    const int nt_all = (qb >> 1) + 1;
    const int half   = nt_all >> 1;
    const int t0 = (split && chunk == 1) ? half : 0;
    const int t1 = (split && chunk == 0) ? half : nt_all;

    const int q_row = qm + wave * 16 + l16;
    bf16x8 qa[2];
    qa[0] = *(const bf16x8*)(const void*)(Qg + (size_t)q_row * 64 + quad * 8);
    qa[1] = *(const bf16x8*)(const void*)(Qg + (size_t)q_row * 64 + 32 + quad * 8);

    f32x4 oacc[4];
    const f32x4 zro = {0.f, 0.f, 0.f, 0.f};
    #pragma unroll
    for (int j = 0; j < 4; ++j) oacc[j] = zro;
    float mst = -1e30f, lst = 0.f;

    const int ldr = tid >> 1, ldc = (tid & 1) * 32;

    for (int t = t0; t < t1; ++t) {
        const int jt = t * 64;
        #pragma unroll
        for (int c = 0; c < 4; ++c) {
            *(uint4*)(void*)&Ks[ldr][ldc + c * 8] =
                *(const uint4*)(const void*)(Kg + (size_t)(jt + ldr) * 64 + ldc + c * 8);
            *(uint4*)(void*)&Vs[ldr][ldc + c * 8] =
                *(const uint4*)(const void*)(Vg + (size_t)ldr * 2048 + jt + ldc + c * 8);
        }
        __syncthreads();

        f32x4 s[4];
        #pragma unroll
        for (int j = 0; j < 4; ++j) s[j] = zro;
        #pragma unroll
        for (int kk = 0; kk < 2; ++kk) {
            #pragma unroll
            for (int j = 0; j < 4; ++j) {
                bf16x8 kf = *(const bf16x8*)(const void*)&Ks[j*16 + l16][kk*32 + quad*8];
                s[j] = __builtin_amdgcn_mfma_f32_16x16x32_bf16(kf, qa[kk], s[j], 0, 0, 0);
            }
        }

        if (jt + 63 > q_row) {
            #pragma unroll
            for (int j = 0; j < 4; ++j) {
                #pragma unroll
                for (int r = 0; r < 4; ++r) {
                    int key = jt + j * 16 + quad * 4 + r;
                    if (key > q_row) s[j][r] = -1e30f;
                }
            }
        }

        float mq = s[0][0];
        #pragma unroll
        for (int j = 0; j < 4; ++j)
            #pragma unroll
            for (int r = 0; r < 4; ++r) mq = fmaxf(mq, s[j][r]);
        float sq = 0.f;
        #pragma unroll
        for (int j = 0; j < 4; ++j)
            #pragma unroll
            for (int r = 0; r < 4; ++r) {
                float v = __expf(s[j][r] - mq);
                s[j][r] = v; sq += v;
            }

        float mo = __shfl_xor(mq, 16);
        float so = __shfl_xor(sq, 16);
        float mm = fmaxf(mq, mo);
        sq = sq * __expf(mq - mm) + so * __expf(mo - mm);
        float mo2 = __shfl_xor(mm, 32);
        float so2 = __shfl_xor(sq, 32);
        float mtile = fmaxf(mm, mo2);
        float stile = sq * __expf(mm - mtile) + so2 * __expf(mo2 - mtile);

        float mn  = fmaxf(mst, mtile);
        float scl = __expf(mst - mn);
        lst = lst * scl + stile * __expf(mtile - mn);
        mst = mn;
        float pf = __expf(mq - mn);

        float sclq[4];
        #pragma unroll
        for (int r = 0; r < 4; ++r) sclq[r] = __shfl(scl, quad * 4 + r);
        #pragma unroll
        for (int j = 0; j < 4; ++j)
            #pragma unroll
            for (int r = 0; r < 4; ++r) oacc[j][r] *= sclq[r];

        #pragma unroll
        for (int j = 0; j < 4; ++j) {
            uint2 u;
            u.x = pk2(s[j][0] * pf, s[j][1] * pf);
            u.y = pk2(s[j][2] * pf, s[j][3] * pf);
            *(uint2*)(void*)&Ps[wave][l16][j * 16 + quad * 4] = u;
        }
        bf16x8 pa0 = *(const bf16x8*)(const void*)&Ps[wave][l16][quad * 8];
        bf16x8 pa1 = *(const bf16x8*)(const void*)&Ps[wave][l16][32 + quad * 8];

        #pragma unroll
        for (int j = 0; j < 4; ++j) {
            bf16x8 vb = *(const bf16x8*)(const void*)&Vs[j*16 + l16][quad*8];
            oacc[j] = __builtin_amdgcn_mfma_f32_16x16x32_bf16(pa0, vb, oacc[j], 0, 0, 0);
        }
        #pragma unroll
        for (int j = 0; j < 4; ++j) {
            bf16x8 vb = *(const bf16x8*)(const void*)&Vs[j*16 + l16][32 + quad*8];
            oacc[j] = __builtin_amdgcn_mfma_f32_16x16x32_bf16(pa1, vb, oacc[j], 0, 0, 0);
        }
        __syncthreads();
    }

    if (!split) {
        float invq[4];
        #pragma unroll
        for (int r = 0; r < 4; ++r) invq[r] = 1.f / __shfl(lst, quad * 4 + r);
        #pragma unroll
        for (int j = 0; j < 4; ++j) {
            #pragma unroll
            for (int r = 0; r < 4; ++r) {
                int tr = qm + wave * 16 + quad * 4 + r;
                o[((size_t)(b * 2048 + tr)) * 512 + h * 64 + j * 16 + l16] =
                    f2b(oacc[j][r] * invq[r]);
            }
        }
    } else {
        const int pidx = (bh * 32 + (qb - 32)) * 2 + chunk;
        float* Od = Opart + (size_t)pidx * 2048;
        #pragma unroll
        for (int j = 0; j < 4; ++j)
            #pragma unroll
            for (int r = 0; r < 4; ++r) {
                int lr = wave * 16 + quad * 4 + r;
                Od[lr * 64 + j * 16 + l16] = oacc[j][r];
            }
        if (quad == 0) {
            MLpart[(size_t)pidx * 64 + wave * 16 + l16]      = mst;
            MLpart[(size_t)pidx * 64 + 32 + wave * 16 + l16] = lst;
        }
    }
}

// ---------------------------------------------------------------------------
// Merge the 2 key-split chunks for qb in [32,63]. Grid (32,16), 128 thr.
// ---------------------------------------------------------------------------
__global__ __launch_bounds__(128) void flash_combine2(
    const float* __restrict__ Opart, const float* __restrict__ MLpart,
    bf16* __restrict__ o)
{
    int qb = 32 + blockIdx.x;
    int bh = blockIdx.y, b = bh >> 3, h = bh & 7;
    int base = (bh * 32 + (qb - 32)) * 2;
    int row = threadIdx.x >> 2;          // 0..31
    int d0  = (threadIdx.x & 3) * 16;    // 0,16,32,48
    float m0 = MLpart[(size_t)base * 64 + row];
    float l0 = MLpart[(size_t)base * 64 + 32 + row];
    float m1 = MLpart[(size_t)(base + 1) * 64 + row];
    float l1 = MLpart[(size_t)(base + 1) * 64 + 32 + row];
    float mstar = fmaxf(m0, m1);
    float w0 = __expf(m0 - mstar), w1 = __expf(m1 - mstar);
    float inv = 1.f / (l0 * w0 + l1 * w1);
    const float* O0 = Opart + (size_t)base * 2048 + row * 64 + d0;
    const float* O1 = O0 + 2048;
    int t = qb * 32 + row;
    bf16* op = o + ((size_t)(b * 2048 + t)) * 512 + h * 64 + d0;
    #pragma unroll 4
    for (int dd = 0; dd < 16; ++dd)
        op[dd] = f2b((O0[dd] * w0 + O1[dd] * w1) * inv);
}

// ---------------------------------------------------------------------------
static void launch_gemm(int epi, hipStream_t s,
                        const bf16* A, int lda, int zsA, int zsA2,
                        const bf16* Bt, int ldb, int zsB, int zsB2,
                        void* C, int ldc, int zsC, int zsC2,
                        const bf16* bias, int zsBias, float scale,
                        const bf16* resid,
                        int M, int N, int K, int nz)
{
    bool mt64 = ((M >> 7) * (N >> 7) * nz) <= 512;
    dim3 blk(256);
    if (mt64) {
        dim3 g(N / 128, M / 64, nz);
        switch (epi) {
        case 0: gemm_bt<0,64><<<g, blk, 0, s>>>(A, lda, zsA, zsA2, Bt, ldb, zsB, zsB2, C, ldc, zsC, zsC2, bias, zsBias, scale, resid, K); break;
        case 1: gemm_bt<1,64><<<g, blk, 0, s>>>(A, lda, zsA, zsA2, Bt, ldb, zsB, zsB2, C, ldc, zsC, zsC2, bias, zsBias, scale, resid, K); break;
        case 3: gemm_bt<3,64><<<g, blk, 0, s>>>(A, lda, zsA, zsA2, Bt, ldb, zsB, zsB2, C, ldc, zsC, zsC2, bias, zsBias, scale, resid, K); break;
        default: gemm_bt<2,64><<<g, blk, 0, s>>>(A, lda, zsA, zsA2, Bt, ldb, zsB, zsB2, C, ldc, zsC, zsC2, bias, zsBias, scale, resid, K); break;
        }
    } else {
        dim3 g(N / 128, M / 128, nz);
        switch (epi) {
        case 0: gemm_bt<0,128><<<g, blk, 0, s>>>(A, lda, zsA, zsA2, Bt, ldb, zsB, zsB2, C, ldc, zsC, zsC2, bias, zsBias, scale, resid, K); break;
        case 1: gemm_bt<1,128><<<g, blk, 0, s>>>(A, lda, zsA, zsA2, Bt, ldb, zsB, zsB2, C, ldc, zsC, zsC2, bias, zsBias, scale, resid, K); break;
        case 3: gemm_bt<3,128><<<g, blk, 0, s>>>(A, lda, zsA, zsA2, Bt, ldb, zsB, zsB2, C, ldc, zsC, zsC2, bias, zsBias, scale, resid, K); break;
        default: gemm_bt<2,128><<<g, blk, 0, s>>>(A, lda, zsA, zsA2, Bt, ldb, zsB, zsB2, C, ldc, zsC, zsC2, bias, zsBias, scale, resid, K); break;
        }
    }
}

extern "C" void kernel_launch(void* const* d_in, const int* in_sizes, int n_in,
                              void* d_out, int out_size, void* d_ws, size_t ws_size,
                              hipStream_t stream)
{
    const void* text  = d_in[0];
    const void* audio = d_in[1];
    const void* video = d_in[2];
    const void* Wa    = d_in[3];
    const void* ba    = d_in[4];
    const void* lna_g = d_in[5];
    const void* lna_b = d_in[6];
    const void* Wvid  = d_in[7];
    const void* bvid  = d_in[8];
    const void* lnv_g = d_in[9];
    const void* lnv_b = d_in[10];
    const void* ln1_g = d_in[11];
    const void* ln1_b = d_in[12];
    const void* Wq    = d_in[13];
    const void* Wkv   = d_in[14];
    const void* qn_g  = d_in[15];
    const void* kn_g  = d_in[16];
    const void* Wo    = d_in[17];
    const void* W1    = d_in[18];
    const void* b1    = d_in[19];
    const void* ln2_g = d_in[20];
    const void* ln2_b = d_in[21];
    const void* W2    = d_in[22];
    const void* b2    = d_in[23];

    char* ws = (char*)d_ws;
    size_t off = 0;
    auto alloc = [&](size_t bytes) -> char* {
        char* p = ws + off;
        off += (bytes + 255) & ~(size_t)255;
        return p;
    };
    const size_t MB = 1024 * 1024;
    int*  flag  = (int*)alloc(256);
    bf16* vecs  = (bf16*)alloc(14 * 4096 * 2);
    bf16* WqkvT = (bf16*)alloc((size_t)1536 * 1024 * 2);
    bf16* WoT   = (bf16*)alloc((size_t)1024 * 512 * 2);
    bf16* W1T   = (bf16*)alloc((size_t)4096 * 1024 * 2);
    bf16* W2T   = (bf16*)alloc((size_t)1024 * 4096 * 2);
    char* regionIn = alloc(24 * MB);   // audioC,videoC -> qkvF -> Opart/ML
    char* region2  = alloc(32 * MB);   // tmp2/tmpF/xF -> g
    char* regionH  = alloc(8 * MB);    // audioT -> h
    char* regionX  = alloc(8 * MB);    // videoT -> x2
    char* regionO  = alloc(4 * MB);    // WaT,WvT -> o
    bf16* qrot    = (bf16*)alloc((size_t)4096 * 1024 * 2);
    bf16* krotPad = (bf16*)alloc((size_t)2 * 2560 * 1024 * 2);
    bf16* VTpad   = (bf16*)alloc((size_t)2 * 1024 * 2560 * 2);
    bf16* attn    = (bf16*)alloc((size_t)8 * 512 * 1024 * 2);

    bf16*  audioC = (bf16*)regionIn;
    bf16*  videoC = audioC + (size_t)4096 * 1024;
    float* qkvF   = (float*)regionIn;
    bf16*  tmp2   = (bf16*)region2;          // adapter GEMM out (2 x 4096x1024 bf16)
    float* tmpF   = (float*)region2;         // sim scores f32
    float* xF     = (float*)(region2 + 16 * MB);
    bf16*  g      = (bf16*)region2;
    bf16*  audioT = (bf16*)regionH;
    bf16*  h      = (bf16*)regionH;
    bf16*  videoT = (bf16*)regionX;
    bf16*  x2     = (bf16*)regionX;
    bf16*  WaT    = (bf16*)regionO;
    bf16*  WvT    = WaT + (size_t)1024 * 1024;
    bf16*  o      = (bf16*)regionO;
    bf16*  Qp     = qrot;
    bf16*  Kp     = krotPad;
    bf16*  Vth    = attn;
    // flash 2-way-split partials (regionIn dead at flash time; 8.7 MB)
    float* Opart  = (float*)regionIn;
    float* MLpart = Opart + (size_t)1024 * 2048;

    bf16* baC   = vecs + 0 * 4096;
    bf16* bvidC = vecs + 1 * 4096;
    bf16* lnagC = vecs + 2 * 4096;
    bf16* lnabC = vecs + 3 * 4096;
    bf16* lnvgC = vecs + 4 * 4096;
    bf16* lnvbC = vecs + 5 * 4096;
    bf16* ln1gC = vecs + 6 * 4096;
    bf16* ln1bC = vecs + 7 * 4096;
    bf16* qngC  = vecs + 8 * 4096;
    bf16* kngC  = vecs + 9 * 4096;
    bf16* b1C   = vecs + 10 * 4096;
    bf16* ln2gC = vecs + 11 * 4096;
    bf16* ln2bC = vecs + 12 * 4096;
    bf16* b2C   = vecs + 13 * 4096;

    // 1) dtype flag
    detect_dtype<<<1, 64, 0, stream>>>((const unsigned short*)text, flag);

    // 2) canonicalize audio+video (one launch) + small vectors
    const int NTOK = 4096 * 1024;
    convert2<<<4096, 256, 0, stream>>>(audio, video, audioC, videoC, NTOK, flag);
    VecPack vp;
    const void* vsrc[14] = {ba, bvid, lna_g, lna_b, lnv_g, lnv_b, ln1_g, ln1_b,
                            qn_g, kn_g, b1, ln2_g, ln2_b, b2};
    int vn[14] = {1024, 1024, 1024, 1024, 1024, 1024, 1024, 1024,
                  64, 64, 4096, 4096, 4096, 1024};
    for (int i = 0; i < 14; ++i) { vp.src[i] = vsrc[i]; vp.n[i] = vn[i]; }
    convert_vecs<<<14, 256, 0, stream>>>(vp, vecs, flag);

    // 3) weight transposes
    dim3 tb(32, 8);
    transpose_any<<<dim3(32, 32), tb, 0, stream>>>(Wa, 1024, 1024, (unsigned short*)WaT, 1024, flag);
    transpose_any<<<dim3(32, 32), tb, 0, stream>>>(Wvid, 1024, 1024, (unsigned short*)WvT, 1024, flag);
    transpose_any<<<dim3(16, 32), tb, 0, stream>>>(Wq, 1024, 512, (unsigned short*)WqkvT, 1024, flag);
    transpose_any<<<dim3(32, 32), tb, 0, stream>>>(Wkv, 1024, 1024, (unsigned short*)(WqkvT + (size_t)512 * 1024), 1024, flag);
    transpose_any<<<dim3(32, 16), tb, 0, stream>>>(Wo, 512, 1024, (unsigned short*)WoT, 512, flag);
    transpose_any<<<dim3(128, 32), tb, 0, stream>>>(W1, 1024, 4096, (unsigned short*)W1T, 1024, flag);
    transpose_any<<<dim3(32, 128), tb, 0, stream>>>(W2, 4096, 1024, (unsigned short*)W2T, 4096, flag);

    // 4) adapters: one batched GEMM (nz=2, bf16 out w/ bias) + merged LN
    launch_gemm(1, stream, audioC, 1024, 4096*1024, 0, WaT, 1024, 1024*1024, 0,
                tmp2, 1024, 4096*1024, 0, baC, 4096, 1.f, nullptr, 4096, 1024, 1024, 2);
    ln_rows2<<<8192, 256, 0, stream>>>(tmp2, lnagC, lnabC, lnvgC, lnvbC, audioT, videoT);

    // 5) pads, rotary (raw text), batched VTpad transpose
    hipMemsetAsync(krotPad, 0, (size_t)2 * 2560 * 1024 * 2, stream);
    hipMemsetAsync(VTpad, 0, (size_t)2 * 1024 * 2560 * 2, stream);
    rotary_kernel<<<4096, 256, 0, stream>>>(text, flag, audioT, qrot, krotPad);
    transpose_vt<<<dim3(32, 64, 2), tb, 0, stream>>>(
        (const unsigned short*)videoT, (unsigned short*)VTpad);

    // 6) local attention: batched sim (nz=8) -> softmax -> batched @V (nz=8)
    launch_gemm(0, stream, qrot, 1024, 512*1024, 0,
                krotPad, 1024, 512*1024, 512*1024,
                tmpF, 1024, 512*1024, 0, nullptr, 0, 1.f, nullptr, 512, 1024, 1024, 8);
    softmax_local<<<dim3(512, 8), 256, 0, stream>>>(tmpF, attn);
    launch_gemm(0, stream, attn, 1024, 512*1024, 0,
                VTpad, 2560, 512, 1024*2560 - 2048,
                xF, 1024, 512*1024, 0, nullptr, 0, 1.f, nullptr, 512, 1024, 1024, 8);

    // 7) ln1 -> qkv -> pack -> V transpose -> 2-way-split swapped flash
    ln_f32_1024<<<4096, 256, 0, stream>>>(xF, ln1gC, ln1bC, h);
    launch_gemm(0, stream, h, 1024, 0, 0, WqkvT, 1024, 0, 0,
                qkvF, 1536, 0, 0, nullptr, 0, 1.f, nullptr, 4096, 1536, 1024, 1);
    pack_qk<<<16384, 256, 0, stream>>>(qkvF, Qp, Kp, qngC, kngC);
    transpose_v<<<dim3(2, 64, 16), tb, 0, stream>>>(qkvF, Vth);
    flash_fused6<<<dim3(96, 16), 128, 0, stream>>>(Qp, Kp, Vth, o, Opart, MLpart);
    flash_combine2<<<dim3(32, 16), 128, 0, stream>>>(Opart, MLpart, o);

    // 8) x2 = 2*(o@Wo) ; g = gelu(x2@W1+b1) via 8-phase 256^2 ; ln2 ;
    //    FF2 single GEMM with fused epilogue: out = g@W2T + b2 + x2.
    launch_gemm(1, stream, o, 512, 0, 0, WoT, 512, 0, 0,
                x2, 1024, 0, 0, nullptr, 0, 2.f, nullptr, 4096, 1024, 512, 1);
    gemm_ff1_8ph<<<dim3(16, 16), 512, 0, stream>>>(x2, 1024, W1T, 1024,
                                                   g, 4096, b1C, 1024);
    ln_b16_4096<<<4096, 256, 0, stream>>>(g, ln2gC, ln2bC, g);
    launch_gemm(3, stream, g, 4096, 0, 0, W2T, 4096, 0, 0,
                d_out, 1024, 0, 0, b2C, 0, 1.f, x2, 4096, 1024, 4096, 1);

    (void)in_sizes; (void)n_in; (void)out_size; (void)ws_size;
}

// Round 11
// 521.136 us; speedup vs baseline: 1.2461x; 1.0313x over previous
//
#include <hip/hip_runtime.h>
#include <hip/hip_bf16.h>

typedef __bf16 bf16;
typedef __bf16 bf16x8 __attribute__((ext_vector_type(8)));
typedef __bf16 bf16x4 __attribute__((ext_vector_type(4)));
typedef float  f32x4  __attribute__((ext_vector_type(4)));

static __device__ __forceinline__ float b2f(bf16 x) { return (float)x; }
static __device__ __forceinline__ bf16  f2b(float x) { return (bf16)x; }

// pack two floats -> one uint holding two bf16 (low = a, high = b)
static __device__ __forceinline__ unsigned pk2(float a, float b)
{
    bf16 x = f2b(a), y = f2b(b);
    unsigned short ux = *(unsigned short*)&x;
    unsigned short uy = *(unsigned short*)&y;
    return (unsigned)ux | ((unsigned)uy << 16);
}

// async global->LDS, 16B per lane; lds dest is wave-uniform base (+lane*16)
static __device__ __forceinline__ void gl_lds16(const bf16* g, bf16* l)
{
    __builtin_amdgcn_global_load_lds(
        (const __attribute__((address_space(1))) void*)g,
        (__attribute__((address_space(3))) void*)l,
        16, 0, 0);
}

// ---------------------------------------------------------------------------
// dtype detection: flag=1 -> f32 inputs.
// ---------------------------------------------------------------------------
__global__ void detect_dtype(const unsigned short* __restrict__ p, int* __restrict__ flag)
{
    if (threadIdx.x == 0 && blockIdx.x == 0) {
        int big = 0;
        for (int i = 0; i < 512; ++i) {
            int e = (p[i] >> 7) & 0xFF;
            if (e >= 0xE0) big++;
        }
        *flag = (big > 0) ? 1 : 0;
    }
}

// convert two tensors in one launch (grid split in half)
__global__ __launch_bounds__(256) void convert2(
    const void* __restrict__ sa, const void* __restrict__ sb,
    bf16* __restrict__ da, bf16* __restrict__ db, int n,
    const int* __restrict__ flag)
{
    int f = *flag;
    int half = gridDim.x >> 1;
    const void* s = (blockIdx.x < half) ? sa : sb;
    bf16* d = (blockIdx.x < half) ? da : db;
    int bid = (blockIdx.x < half) ? blockIdx.x : blockIdx.x - half;
    for (int i = bid * 256 + threadIdx.x; i < n; i += half * 256) {
        float v = f ? ((const float*)s)[i] : (float)((const bf16*)s)[i];
        d[i] = f2b(v);
    }
}

struct VecPack { const void* src[14]; int n[14]; };
__global__ __launch_bounds__(256) void convert_vecs(
    VecPack vp, bf16* __restrict__ dst, const int* __restrict__ flag)
{
    int v = blockIdx.x;
    int f = *flag;
    const void* s = vp.src[v];
    int n = vp.n[v];
    bf16* d = dst + (size_t)v * 4096;
    for (int i = threadIdx.x; i < n; i += 256) {
        float x = f ? ((const float*)s)[i] : (float)((const bf16*)s)[i];
        d[i] = f2b(x);
    }
}

// ---------------------------------------------------------------------------
// GEMM: C[M,N] = A[M,K] @ Bt[n][k]. MT x 128 tile, BK=64, 4 waves.
// EPI: 0 = f32 store (+bias)   1 = bf16 (v+bias)*scale   2 = bf16 gelu
//      3 = f32 store v + bias + resid[off]
// T1 XCD-chunked swizzle when (gx*gy)%8==0 (applies per z-slice; XCD of a
// block = (by*gx+bx)%8 independent of z since gx*gy*z is a multiple of 8).
// ---------------------------------------------------------------------------
template <int EPI, int MT>
__global__ __launch_bounds__(256) void gemm_bt(
    const bf16* __restrict__ A0, int lda, int zsA, int zsA2,
    const bf16* __restrict__ B0, int ldb, int zsB, int zsB2,
    void* __restrict__ C0, int ldc, int zsC, int zsC2,
    const bf16* __restrict__ bias, int zsBias, float scale,
    const bf16* __restrict__ resid, int K)
{
    constexpr int IFR = MT / 32;
    __shared__ __align__(16) bf16 As[MT * 64];
    __shared__ __align__(16) bf16 Bs[128 * 64];
    int bx = blockIdx.x, by = blockIdx.y;
    {
        const int gx = gridDim.x, gy = gridDim.y;
        const int T = gx * gy;
        if ((T & 7) == 0) {
            int hw = by * gx + bx;
            int lid = (hw & 7) * (T >> 3) + (hw >> 3);
            bx = lid % gx; by = lid / gx;
        }
    }
    const int z = blockIdx.z;
    const bf16* A  = A0 + (size_t)z * zsA + (size_t)(z >> 2) * zsA2;
    const bf16* Bt = B0 + (size_t)z * zsB + (size_t)(z >> 2) * zsB2;
    const size_t cbase = (size_t)z * zsC + (size_t)(z >> 2) * zsC2;
    if (bias) bias += (size_t)z * zsBias;
    const int tid  = threadIdx.x;
    const int lane = tid & 63, wave = tid >> 6;
    const int quad = lane >> 4, l16 = lane & 15;
    const size_t tm = (size_t)by * MT, tn = (size_t)bx * 128;
    const int wm = (wave >> 1) * (MT / 2), wn = (wave & 1) * 64;
    const int srow = lane >> 3;
    const int scol = ((lane & 7) ^ srow) * 8;

    f32x4 acc[IFR][4];
    const f32x4 zro = {0.f, 0.f, 0.f, 0.f};
    #pragma unroll
    for (int i = 0; i < IFR; ++i)
        #pragma unroll
        for (int j = 0; j < 4; ++j) acc[i][j] = zro;

    const int swzA = l16 & 7;
    for (int k0 = 0; k0 < K; k0 += 64) {
        #pragma unroll
        for (int i = 0; i < IFR; ++i) {
            int chunk = (wave * IFR + i) * 64;
            int row = (chunk >> 3) + srow;
            gl_lds16(A + (tm + row) * (size_t)lda + k0 + scol, As + (size_t)chunk * 8);
        }
        #pragma unroll
        for (int i = 0; i < 4; ++i) {
            int chunk = (wave * 4 + i) * 64;
            int row = (chunk >> 3) + srow;
            gl_lds16(Bt + (tn + row) * (size_t)ldb + k0 + scol, Bs + (size_t)chunk * 8);
        }
        __syncthreads();
        #pragma unroll
        for (int kk = 0; kk < 2; ++kk) {
            bf16x8 af[IFR], bfr[4];
            #pragma unroll
            for (int i = 0; i < IFR; ++i) {
                int row = wm + i * 16 + l16;
                af[i] = *(const bf16x8*)(const void*)&As[(row * 8 + ((kk*4 + quad) ^ swzA)) * 8];
            }
            #pragma unroll
            for (int j = 0; j < 4; ++j) {
                int row = wn + j * 16 + l16;
                bfr[j] = *(const bf16x8*)(const void*)&Bs[(row * 8 + ((kk*4 + quad) ^ swzA)) * 8];
            }
            #pragma unroll
            for (int i = 0; i < IFR; ++i)
                #pragma unroll
                for (int j = 0; j < 4; ++j)
                    acc[i][j] = __builtin_amdgcn_mfma_f32_16x16x32_bf16(
                        af[i], bfr[j], acc[i][j], 0, 0, 0);
        }
        __syncthreads();
    }

    float* Cf = (float*)C0;
    bf16*  Cb = (bf16*)C0;
    #pragma unroll
    for (int i = 0; i < IFR; ++i) {
        #pragma unroll
        for (int j = 0; j < 4; ++j) {
            size_t col = tn + wn + j*16 + l16;
            float bb = bias ? b2f(bias[col]) : 0.f;
            #pragma unroll
            for (int r = 0; r < 4; ++r) {
                size_t row = tm + wm + i*16 + quad*4 + r;
                float v = acc[i][j][r] + bb;
                size_t off = cbase + row * (size_t)ldc + col;
                if (EPI == 0) {
                    Cf[off] = v;
                } else if (EPI == 1) {
                    Cb[off] = f2b(v * scale);
                } else if (EPI == 3) {
                    Cf[off] = v + b2f(resid[off]);
                } else {
                    float g = 0.5f * v * (1.f + tanhf(0.7978845608028654f *
                                  (v + 0.044715f * v * v * v)));
                    Cb[off] = f2b(g);
                }
            }
        }
    }
}

// ---------------------------------------------------------------------------
// FF1 GEMM, 256x256 tile, BK=64, 8 waves, 8-phase-style pipelined schedule.
// C[M,N] = gelu(A[M,K] @ Bt[N,K]^T + bias), bf16 out.
// ---------------------------------------------------------------------------
__global__ __launch_bounds__(512, 2) void gemm_ff1_8ph(
    const bf16* __restrict__ A, int lda,
    const bf16* __restrict__ Bt, int ldb,
    bf16* __restrict__ C, int ldc,
    const bf16* __restrict__ bias, int K)
{
    __shared__ __align__(16) bf16 As[2][256 * 64];
    __shared__ __align__(16) bf16 Bs[2][256 * 64];
    const int tid  = threadIdx.x;
    const int lane = tid & 63, wave = tid >> 6;
    const int quad = lane >> 4, l16 = lane & 15;
    const int wr = wave >> 2, wc = wave & 3;          // 2M x 4N wave grid
    const size_t tm = (size_t)blockIdx.y * 256;
    const size_t tn = (size_t)blockIdx.x * 256;
    const int srow = lane >> 3;
    const int scol = ((lane & 7) ^ srow) * 8;         // pre-swizzled global col
    const int swz  = l16 & 7;                         // read-side swizzle

    f32x4 acc[8][4];
    const f32x4 zro = {0.f, 0.f, 0.f, 0.f};
    #pragma unroll
    for (int m = 0; m < 8; ++m)
        #pragma unroll
        for (int n = 0; n < 4; ++n) acc[m][n] = zro;

    const bf16* aSrc[4];
    const bf16* bSrc[4];
    #pragma unroll
    for (int i = 0; i < 4; ++i) {
        int grow = wave * 32 + i * 8 + srow;
        aSrc[i] = A  + (tm + grow) * (size_t)lda + scol;
        bSrc[i] = Bt + (tn + grow) * (size_t)ldb + scol;
    }

#define STAGE(BUF, K0, I)                                                     \
    do {                                                                      \
        gl_lds16(aSrc[I] + (K0), &As[BUF][(wave * 4 + (I)) * 512]);           \
        gl_lds16(bSrc[I] + (K0), &Bs[BUF][(wave * 4 + (I)) * 512]);           \
    } while (0)

#define LDA_F(BUF, M, KK)                                                     \
    (*(const bf16x8*)(const void*)&As[BUF][(wr * 128 + (M) * 16 + l16) * 64 + \
        ((((KK) * 4 + quad) ^ swz) << 3)])
#define LDB_F(BUF, N, KK)                                                     \
    (*(const bf16x8*)(const void*)&Bs[BUF][(wc * 64 + (N) * 16 + l16) * 64 +  \
        ((((KK) * 4 + quad) ^ swz) << 3)])

#define PHASE(M0, M1, PREF_STMT, TAIL_STMT)                                   \
    {                                                                         \
        PREF_STMT;                                                            \
        bf16x8 x0 = LDA_F(cur, M0, 0), x1 = LDA_F(cur, M0, 1);                \
        bf16x8 y0 = LDA_F(cur, M1, 0), y1 = LDA_F(cur, M1, 1);                \
        asm volatile("s_barrier" ::: "memory");                               \
        __builtin_amdgcn_s_setprio(1);                                        \
        _Pragma("unroll")                                                     \
        for (int n = 0; n < 4; ++n) {                                         \
            acc[M0][n] = __builtin_amdgcn_mfma_f32_16x16x32_bf16(x0, bfr[n][0], acc[M0][n], 0, 0, 0); \
            acc[M0][n] = __builtin_amdgcn_mfma_f32_16x16x32_bf16(x1, bfr[n][1], acc[M0][n], 0, 0, 0); \
            acc[M1][n] = __builtin_amdgcn_mfma_f32_16x16x32_bf16(y0, bfr[n][0], acc[M1][n], 0, 0, 0); \
            acc[M1][n] = __builtin_amdgcn_mfma_f32_16x16x32_bf16(y1, bfr[n][1], acc[M1][n], 0, 0, 0); \
        }                                                                     \
        __builtin_amdgcn_s_setprio(0);                                        \
        TAIL_STMT;                                                            \
        asm volatile("s_barrier" ::: "memory");                               \
    }

    #pragma unroll
    for (int i = 0; i < 4; ++i) STAGE(0, 0, i);
    asm volatile("s_waitcnt vmcnt(0)" ::: "memory");
    asm volatile("s_barrier" ::: "memory");

    const int NT = K >> 6;
    bf16x8 bfr[4][2];
    for (int t = 0; t < NT; ++t) {
        const int cur = t & 1, nxt = cur ^ 1;
        const int k1  = (t + 1) << 6;
        const bool pref = (t + 1 < NT);

        #pragma unroll
        for (int n = 0; n < 4; ++n) {
            bfr[n][0] = LDB_F(cur, n, 0);
            bfr[n][1] = LDB_F(cur, n, 1);
        }
        PHASE(0, 1,
              if (pref) { STAGE(nxt, k1, 0); STAGE(nxt, k1, 1); }, )
        PHASE(2, 3,
              if (pref) { STAGE(nxt, k1, 2); STAGE(nxt, k1, 3); }, )
        PHASE(4, 5, , )
        PHASE(6, 7, ,
              asm volatile("s_waitcnt vmcnt(0)" ::: "memory"))
    }
#undef PHASE
#undef LDB_F
#undef LDA_F
#undef STAGE

    // epilogue: bias + fast gelu (v * sigmoid(1.59577 v + 0.0713548 v^3))
    #pragma unroll
    for (int m = 0; m < 8; ++m) {
        #pragma unroll
        for (int n = 0; n < 4; ++n) {
            size_t col = tn + wc * 64 + n * 16 + l16;
            float bb = b2f(bias[col]);
            #pragma unroll
            for (int r = 0; r < 4; ++r) {
                size_t row = tm + wr * 128 + m * 16 + quad * 4 + r;
                float v = acc[m][n][r] + bb;
                float s = v * (1.5957691216057308f + 0.07135481627f * v * v);
                float g = v / (1.f + __expf(-s));
                C[row * (size_t)ldc + col] = f2b(g);
            }
        }
    }
}

// ---------------------------------------------------------------------------
// Batched dtype-branching transposes: all 7 weight transposes in ONE launch.
// Per-transpose tile grids concatenated along blockIdx.x; each tile is the
// original 32x32 LDS transpose body.
// ---------------------------------------------------------------------------
struct TPack {
    const void* src[7];
    unsigned short* dst[7];
    int R[7], C[7], ldo[7], cnt[7];   // cnt = (C/32)*(R/32)
};
__global__ void transpose_pack(TPack tp, const int* __restrict__ flag)
{
    __shared__ unsigned short t[32][33];
    int f = *flag;
    int tile = blockIdx.x;
    int k = 0;
    while (tile >= tp.cnt[k]) { tile -= tp.cnt[k]; ++k; }
    const void* in = tp.src[k];
    unsigned short* out = tp.dst[k];
    const int C = tp.C[k], ldo = tp.ldo[k];
    const int gx = C >> 5;
    int c0 = (tile % gx) * 32, r0 = (tile / gx) * 32;
    int tx = threadIdx.x, ty = threadIdx.y;
    for (int i = ty; i < 32; i += 8) {
        size_t idx = (size_t)(r0 + i) * C + c0 + tx;
        bf16 v = f ? f2b(((const float*)in)[idx]) : ((const bf16*)in)[idx];
        t[i][tx] = *(unsigned short*)&v;
    }
    __syncthreads();
    for (int i = ty; i < 32; i += 8)
        out[(size_t)(c0 + i) * ldo + r0 + tx] = t[tx][i];
}

// videoT [b][2048][1024] -> VTpad [b][1024][512 + 2048] (col offset 512), z=b
__global__ void transpose_vt(const unsigned short* __restrict__ in,
                             unsigned short* __restrict__ out)
{
    __shared__ unsigned short t[32][33];
    int b = blockIdx.z;
    const unsigned short* src = in + (size_t)b * 2048 * 1024;
    unsigned short* dst = out + (size_t)b * 1024 * 2560;
    int c0 = blockIdx.x * 32, r0 = blockIdx.y * 32;
    int tx = threadIdx.x, ty = threadIdx.y;
    for (int i = ty; i < 32; i += 8)
        t[i][tx] = src[(size_t)(r0 + i) * 1024 + c0 + tx];
    __syncthreads();
    for (int i = ty; i < 32; i += 8)
        dst[(size_t)(c0 + i) * 2560 + 512 + r0 + tx] = t[tx][i];
}

// ---------------------------------------------------------------------------
// V transpose into per-head Vt[bh][64][2048] bf16.
// ---------------------------------------------------------------------------
__global__ void transpose_v(const float* __restrict__ qkv, bf16* __restrict__ Vt)
{
    __shared__ float t[32][33];
    int bh = blockIdx.z, b = bh >> 3, h = bh & 7;
    const float* src = qkv + (size_t)b * 2048 * 1536 + 1024 + h * 64;
    int c0 = blockIdx.x * 32, r0 = blockIdx.y * 32;
    int tx = threadIdx.x, ty = threadIdx.y;
    for (int i = ty; i < 32; i += 8)
        t[i][tx] = src[(size_t)(r0 + i) * 1536 + c0 + tx];
    __syncthreads();
    bf16* dst = Vt + (size_t)bh * 64 * 2048;
    for (int i = ty; i < 32; i += 8)
        dst[(size_t)(c0 + i) * 2048 + r0 + tx] = f2b(t[tx][i]);
}

// ---------------------------------------------------------------------------
// Vectorized row LayerNorms (G13): values held in registers, single read.
// ---------------------------------------------------------------------------
// f32 input, C=1024: one float4 per thread.
__global__ __launch_bounds__(256) void ln_f32_1024(
    const float* __restrict__ in,
    const bf16* __restrict__ g, const bf16* __restrict__ b,
    bf16* __restrict__ out)
{
    const int row = blockIdx.x, tid = threadIdx.x;
    f32x4 v = *(const f32x4*)(in + (size_t)row * 1024 + tid * 4);
    float s  = v[0] + v[1] + v[2] + v[3];
    float ss = v[0]*v[0] + v[1]*v[1] + v[2]*v[2] + v[3]*v[3];
    #pragma unroll
    for (int d = 32; d > 0; d >>= 1) { s += __shfl_xor(s, d); ss += __shfl_xor(ss, d); }
    __shared__ float red[2][4];
    int wave = tid >> 6, lane = tid & 63;
    if (lane == 0) { red[0][wave] = s; red[1][wave] = ss; }
    __syncthreads();
    s  = red[0][0] + red[0][1] + red[0][2] + red[0][3];
    ss = red[1][0] + red[1][1] + red[1][2] + red[1][3];
    float mu   = s * (1.f / 1024.f);
    float var  = ss * (1.f / 1024.f) - mu * mu;
    float rstd = rsqrtf(var + 1e-5f);
    bf16x4 g4 = *(const bf16x4*)(const void*)(g + tid * 4);
    bf16x4 b4 = *(const bf16x4*)(const void*)(b + tid * 4);
    bf16x4 o4;
    #pragma unroll
    for (int j = 0; j < 4; ++j)
        o4[j] = f2b((v[j] - mu) * rstd * b2f(g4[j]) + b2f(b4[j]));
    *(bf16x4*)(void*)(out + (size_t)row * 1024 + tid * 4) = o4;
}

// bf16 input, C=4096: two bf16x8 per thread (in-place safe).
__global__ __launch_bounds__(256) void ln_b16_4096(
    const bf16* __restrict__ in,
    const bf16* __restrict__ g, const bf16* __restrict__ b,
    bf16* __restrict__ out)
{
    const int row = blockIdx.x, tid = threadIdx.x;
    const bf16* p = in + (size_t)row * 4096;
    bf16x8 v0 = *(const bf16x8*)(const void*)(p + tid * 8);
    bf16x8 v1 = *(const bf16x8*)(const void*)(p + 2048 + tid * 8);
    float f0[8], f1[8];
    float s = 0.f, ss = 0.f;
    #pragma unroll
    for (int j = 0; j < 8; ++j) {
        f0[j] = b2f(v0[j]); f1[j] = b2f(v1[j]);
        s += f0[j] + f1[j];
        ss += f0[j]*f0[j] + f1[j]*f1[j];
    }
    #pragma unroll
    for (int d = 32; d > 0; d >>= 1) { s += __shfl_xor(s, d); ss += __shfl_xor(ss, d); }
    __shared__ float red[2][4];
    int wave = tid >> 6, lane = tid & 63;
    if (lane == 0) { red[0][wave] = s; red[1][wave] = ss; }
    __syncthreads();
    s  = red[0][0] + red[0][1] + red[0][2] + red[0][3];
    ss = red[1][0] + red[1][1] + red[1][2] + red[1][3];
    float mu   = s * (1.f / 4096.f);
    float var  = ss * (1.f / 4096.f) - mu * mu;
    float rstd = rsqrtf(var + 1e-5f);
    bf16x8 g0 = *(const bf16x8*)(const void*)(g + tid * 8);
    bf16x8 b0 = *(const bf16x8*)(const void*)(b + tid * 8);
    bf16x8 g1 = *(const bf16x8*)(const void*)(g + 2048 + tid * 8);
    bf16x8 b1 = *(const bf16x8*)(const void*)(b + 2048 + tid * 8);
    bf16x8 o0, o1;
    #pragma unroll
    for (int j = 0; j < 8; ++j) {
        o0[j] = f2b((f0[j] - mu) * rstd * b2f(g0[j]) + b2f(b0[j]));
        o1[j] = f2b((f1[j] - mu) * rstd * b2f(g1[j]) + b2f(b1[j]));
    }
    bf16* q = out + (size_t)row * 4096;
    *(bf16x8*)(void*)(q + tid * 8)        = o0;
    *(bf16x8*)(void*)(q + 2048 + tid * 8) = o1;
}

// both adapter LNs in one launch: rows 0..4095 audio, 4096..8191 video. C=1024.
__global__ __launch_bounds__(256) void ln_rows2(
    const bf16* __restrict__ in,
    const bf16* __restrict__ g0, const bf16* __restrict__ b0,
    const bf16* __restrict__ g1, const bf16* __restrict__ b1,
    bf16* __restrict__ out0, bf16* __restrict__ out1)
{
    const int row = blockIdx.x, tid = threadIdx.x;
    const int sel = row >> 12;
    const bf16* p = in + (size_t)row * 1024;
    const bf16* g = sel ? g1 : g0;
    const bf16* b = sel ? b1 : b0;
    bf16* q = (sel ? out1 + (size_t)(row - 4096) * 1024 : out0 + (size_t)row * 1024);
    bf16x4 v4 = *(const bf16x4*)(const void*)(p + tid * 4);
    float f[4];
    float s = 0.f, ss = 0.f;
    #pragma unroll
    for (int j = 0; j < 4; ++j) {
        f[j] = b2f(v4[j]);
        s += f[j]; ss += f[j]*f[j];
    }
    #pragma unroll
    for (int d = 32; d > 0; d >>= 1) { s += __shfl_xor(s, d); ss += __shfl_xor(ss, d); }
    __shared__ float red[2][4];
    int wave = tid >> 6, lane = tid & 63;
    if (lane == 0) { red[0][wave] = s; red[1][wave] = ss; }
    __syncthreads();
    s  = red[0][0] + red[0][1] + red[0][2] + red[0][3];
    ss = red[1][0] + red[1][1] + red[1][2] + red[1][3];
    float mu   = s * (1.f / 1024.f);
    float var  = ss * (1.f / 1024.f) - mu * mu;
    float rstd = rsqrtf(var + 1e-5f);
    bf16x4 g4 = *(const bf16x4*)(const void*)(g + tid * 4);
    bf16x4 b4 = *(const bf16x4*)(const void*)(b + tid * 4);
    bf16x4 o4;
    #pragma unroll
    for (int j = 0; j < 4; ++j)
        o4[j] = f2b((f[j] - mu) * rstd * b2f(g4[j]) + b2f(b4[j]));
    *(bf16x4*)(void*)(q + tid * 4) = o4;
}

// ---------------------------------------------------------------------------
// Rotary, b-deduplicated: grid 2048 (t); one sincos per (t,c) reused for
// both batches. qrot = rope(text)*DIM^-0.5 ; krotPad[b][512+t] = rope(audio_t).
// ---------------------------------------------------------------------------
__global__ __launch_bounds__(256) void rotary_kernel(
    const void* __restrict__ text, const int* __restrict__ flag,
    const bf16* __restrict__ audioT,
    bf16* __restrict__ qrot, bf16* __restrict__ krotPad)
{
    int t = blockIdx.x;
    int tid = threadIdx.x;
    int f = *flag;
    const float lg = 9.210340371976184f / 512.f;
    for (int c = tid; c < 512; c += 256) {
        float invf = __expf(-(float)c * lg);
        float th = (float)t * invf;
        float sn, cs;
        sincosf(th, &sn, &cs);
        #pragma unroll
        for (int b = 0; b < 2; ++b) {
            size_t base = ((size_t)(b * 2048 + t)) * 1024;
            size_t kb = ((size_t)(b * 2560 + 512 + t)) * 1024;
            float q1 = f ? ((const float*)text)[base + c]
                         : b2f(((const bf16*)text)[base + c]);
            float q2 = f ? ((const float*)text)[base + c + 512]
                         : b2f(((const bf16*)text)[base + c + 512]);
            qrot[base + c]       = f2b((q1 * cs - q2 * sn) * 0.03125f);
            qrot[base + c + 512] = f2b((q2 * cs + q1 * sn) * 0.03125f);
            float k1 = b2f(audioT[base + c]), k2 = b2f(audioT[base + c + 512]);
            krotPad[kb + c]       = f2b(k1 * cs - k2 * sn);
            krotPad[kb + c + 512] = f2b(k2 * cs + k1 * sn);
        }
    }
}

// ---------------------------------------------------------------------------
// Local-attention masked softmax. sim [b][w][512][1024] f32 -> attn bf16.
// ---------------------------------------------------------------------------
__global__ __launch_bounds__(256) void softmax_local(
    const float* __restrict__ sim, bf16* __restrict__ attn)
{
    int i  = blockIdx.x;
    int zz = blockIdx.y;
    int w  = zz & 3;
    int tid = threadIdx.x;
    const float* p = sim + ((size_t)zz * 512 + i) * 1024;
    bf16* q = attn + ((size_t)zz * 512 + i) * 1024;
    int jlo = (w == 0) ? 512 : 0;
    int jhi = 512 + i;
    float m = -1e30f;
    #pragma unroll
    for (int k = 0; k < 4; ++k) {
        int c = tid + k * 256;
        if (c >= jlo && c <= jhi) m = fmaxf(m, p[c]);
    }
    #pragma unroll
    for (int d = 32; d > 0; d >>= 1) m = fmaxf(m, __shfl_xor(m, d));
    __shared__ float red[2][4];
    int wave = tid >> 6, lane = tid & 63;
    if (lane == 0) red[0][wave] = m;
    __syncthreads();
    m = fmaxf(fmaxf(red[0][0], red[0][1]), fmaxf(red[0][2], red[0][3]));
    float pv[4];
    float s = 0.f;
    #pragma unroll
    for (int k = 0; k < 4; ++k) {
        int c = tid + k * 256;
        float e = (c >= jlo && c <= jhi) ? __expf(p[c] - m) : 0.f;
        pv[k] = e; s += e;
    }
    #pragma unroll
    for (int d = 32; d > 0; d >>= 1) s += __shfl_xor(s, d);
    if (lane == 0) red[1][wave] = s;
    __syncthreads();
    s = red[1][0] + red[1][1] + red[1][2] + red[1][3];
    float inv = 1.f / s;
    #pragma unroll
    for (int k = 0; k < 4; ++k) q[tid + k * 256] = f2b(pv[k] * inv);
}

// ---------------------------------------------------------------------------
// pack_qk: RMSNorm q/k from qkv f32 [4096][1536] -> per-head bf16 buffers.
// ---------------------------------------------------------------------------
__global__ __launch_bounds__(256) void pack_qk(
    const float* __restrict__ qkv, bf16* __restrict__ Qp, bf16* __restrict__ Kp,
    const bf16* __restrict__ qn_g, const bf16* __restrict__ kn_g)
{
    int gid  = blockIdx.x * 4 + (threadIdx.x >> 6);
    int lane = threadIdx.x & 63;
    int token = gid >> 4, r = gid & 15, part = r >> 3, h = r & 7;
    const float* p = qkv + (size_t)token * 1536 + part * 512 + h * 64 + lane;
    float v = *p;
    float ss = v * v;
    #pragma unroll
    for (int d = 32; d > 0; d >>= 1) ss += __shfl_xor(ss, d);
    float sc = rsqrtf(ss * (1.f / 64.f) + 1e-6f);
    const bf16* gw = part ? kn_g : qn_g;
    float outv = v * sc * b2f(gw[lane]);
    if (!part) outv *= 0.125f;
    int b = token >> 11, t = token & 2047;
    bf16* dst = (part ? Kp : Qp) + ((size_t)(b * 8 + h) * 2048 + t) * 64 + lane;
    *dst = f2b(outv);
}

// ---------------------------------------------------------------------------
// Fused causal flash attention (D=64), swapped-operand softmax + 2-way
// key-split for long blocks (qb >= 32). Grid (96,16), 128 thr. (R8 verified)
// ---------------------------------------------------------------------------
__global__ __launch_bounds__(128) void flash_fused6(
    const bf16* __restrict__ Qp, const bf16* __restrict__ Kp,
    const bf16* __restrict__ Vt, bf16* __restrict__ o,
    float* __restrict__ Opart, float* __restrict__ MLpart)
{
    __shared__ __align__(16) bf16 Ks[64][72];
    __shared__ __align__(16) bf16 Vs[64][72];
    __shared__ __align__(16) bf16 Ps[2][16][72];
    const int bx = blockIdx.x;
    const int qb = (bx < 64) ? (63 - bx) : (63 - (bx - 64));
    const int chunk = (bx < 64) ? 0 : 1;
    const bool split = (qb >= 32);
    const int bh = blockIdx.y, b = bh >> 3, h = bh & 7;
    const int qm = qb * 32;
    const int tid = threadIdx.x, wave = tid >> 6, lane = tid & 63;
    const int quad = lane >> 4, l16 = lane & 15;
    const bf16* Qg = Qp + (size_t)bh * 2048 * 64;
    const bf16* Kg = Kp + (size_t)bh * 2048 * 64;
    const bf16* Vg = Vt + (size_t)bh * 64 * 2048;

    const int nt_all = (qb >> 1) + 1;
    const int half   = nt_all >> 1;
    const int t0 = (split && chunk == 1) ? half : 0;
    const int t1 = (split && chunk == 0) ? half : nt_all;

    const int q_row = qm + wave * 16 + l16;
    bf16x8 qa[2];
    qa[0] = *(const bf16x8*)(const void*)(Qg + (size_t)q_row * 64 + quad * 8);
    qa[1] = *(const bf16x8*)(const void*)(Qg + (size_t)q_row * 64 + 32 + quad * 8);

    f32x4 oacc[4];
    const f32x4 zro = {0.f, 0.f, 0.f, 0.f};
    #pragma unroll
    for (int j = 0; j < 4; ++j) oacc[j] = zro;
    float mst = -1e30f, lst = 0.f;

    const int ldr = tid >> 1, ldc = (tid & 1) * 32;

    for (int t = t0; t < t1; ++t) {
        const int jt = t * 64;
        #pragma unroll
        for (int c = 0; c < 4; ++c) {
            *(uint4*)(void*)&Ks[ldr][ldc + c * 8] =
                *(const uint4*)(const void*)(Kg + (size_t)(jt + ldr) * 64 + ldc + c * 8);
            *(uint4*)(void*)&Vs[ldr][ldc + c * 8] =
                *(const uint4*)(const void*)(Vg + (size_t)ldr * 2048 + jt + ldc + c * 8);
        }
        __syncthreads();

        f32x4 s[4];
        #pragma unroll
        for (int j = 0; j < 4; ++j) s[j] = zro;
        #pragma unroll
        for (int kk = 0; kk < 2; ++kk) {
            #pragma unroll
            for (int j = 0; j < 4; ++j) {
                bf16x8 kf = *(const bf16x8*)(const void*)&Ks[j*16 + l16][kk*32 + quad*8];
                s[j] = __builtin_amdgcn_mfma_f32_16x16x32_bf16(kf, qa[kk], s[j], 0, 0, 0);
            }
        }

        if (jt + 63 > q_row) {
            #pragma unroll
            for (int j = 0; j < 4; ++j) {
                #pragma unroll
                for (int r = 0; r < 4; ++r) {
                    int key = jt + j * 16 + quad * 4 + r;
                    if (key > q_row) s[j][r] = -1e30f;
                }
            }
        }

        float mq = s[0][0];
        #pragma unroll
        for (int j = 0; j < 4; ++j)
            #pragma unroll
            for (int r = 0; r < 4; ++r) mq = fmaxf(mq, s[j][r]);
        float sq = 0.f;
        #pragma unroll
        for (int j = 0; j < 4; ++j)
            #pragma unroll
            for (int r = 0; r < 4; ++r) {
                float v = __expf(s[j][r] - mq);
                s[j][r] = v; sq += v;
            }

        float mo = __shfl_xor(mq, 16);
        float so = __shfl_xor(sq, 16);
        float mm = fmaxf(mq, mo);
        sq = sq * __expf(mq - mm) + so * __expf(mo - mm);
        float mo2 = __shfl_xor(mm, 32);
        float so2 = __shfl_xor(sq, 32);
        float mtile = fmaxf(mm, mo2);
        float stile = sq * __expf(mm - mtile) + so2 * __expf(mo2 - mtile);

        float mn  = fmaxf(mst, mtile);
        float scl = __expf(mst - mn);
        lst = lst * scl + stile * __expf(mtile - mn);
        mst = mn;
        float pf = __expf(mq - mn);

        float sclq[4];
        #pragma unroll
        for (int r = 0; r < 4; ++r) sclq[r] = __shfl(scl, quad * 4 + r);
        #pragma unroll
        for (int j = 0; j < 4; ++j)
            #pragma unroll
            for (int r = 0; r < 4; ++r) oacc[j][r] *= sclq[r];

        #pragma unroll
        for (int j = 0; j < 4; ++j) {
            uint2 u;
            u.x = pk2(s[j][0] * pf, s[j][1] * pf);
            u.y = pk2(s[j][2] * pf, s[j][3] * pf);
            *(uint2*)(void*)&Ps[wave][l16][j * 16 + quad * 4] = u;
        }
        bf16x8 pa0 = *(const bf16x8*)(const void*)&Ps[wave][l16][quad * 8];
        bf16x8 pa1 = *(const bf16x8*)(const void*)&Ps[wave][l16][32 + quad * 8];

        #pragma unroll
        for (int j = 0; j < 4; ++j) {
            bf16x8 vb = *(const bf16x8*)(const void*)&Vs[j*16 + l16][quad*8];
            oacc[j] = __builtin_amdgcn_mfma_f32_16x16x32_bf16(pa0, vb, oacc[j], 0, 0, 0);
        }
        #pragma unroll
        for (int j = 0; j < 4; ++j) {
            bf16x8 vb = *(const bf16x8*)(const void*)&Vs[j*16 + l16][32 + quad*8];
            oacc[j] = __builtin_amdgcn_mfma_f32_16x16x32_bf16(pa1, vb, oacc[j], 0, 0, 0);
        }
        __syncthreads();
    }

    if (!split) {
        float invq[4];
        #pragma unroll
        for (int r = 0; r < 4; ++r) invq[r] = 1.f / __shfl(lst, quad * 4 + r);
        #pragma unroll
        for (int j = 0; j < 4; ++j) {
            #pragma unroll
            for (int r = 0; r < 4; ++r) {
                int tr = qm + wave * 16 + quad * 4 + r;
                o[((size_t)(b * 2048 + tr)) * 512 + h * 64 + j * 16 + l16] =
                    f2b(oacc[j][r] * invq[r]);
            }
        }
    } else {
        const int pidx = (bh * 32 + (qb - 32)) * 2 + chunk;
        float* Od = Opart + (size_t)pidx * 2048;
        #pragma unroll
        for (int j = 0; j < 4; ++j)
            #pragma unroll
            for (int r = 0; r < 4; ++r) {
                int lr = wave * 16 + quad * 4 + r;
                Od[lr * 64 + j * 16 + l16] = oacc[j][r];
            }
        if (quad == 0) {
            MLpart[(size_t)pidx * 64 + wave * 16 + l16]      = mst;
            MLpart[(size_t)pidx * 64 + 32 + wave * 16 + l16] = lst;
        }
    }
}

// ---------------------------------------------------------------------------
// Merge the 2 key-split chunks for qb in [32,63]. Grid (32,16), 128 thr.
// ---------------------------------------------------------------------------
__global__ __launch_bounds__(128) void flash_combine2(
    const float* __restrict__ Opart, const float* __restrict__ MLpart,
    bf16* __restrict__ o)
{
    int qb = 32 + blockIdx.x;
    int bh = blockIdx.y, b = bh >> 3, h = bh & 7;
    int base = (bh * 32 + (qb - 32)) * 2;
    int row = threadIdx.x >> 2;          // 0..31
    int d0  = (threadIdx.x & 3) * 16;    // 0,16,32,48
    float m0 = MLpart[(size_t)base * 64 + row];
    float l0 = MLpart[(size_t)base * 64 + 32 + row];
    float m1 = MLpart[(size_t)(base + 1) * 64 + row];
    float l1 = MLpart[(size_t)(base + 1) * 64 + 32 + row];
    float mstar = fmaxf(m0, m1);
    float w0 = __expf(m0 - mstar), w1 = __expf(m1 - mstar);
    float inv = 1.f / (l0 * w0 + l1 * w1);
    const float* O0 = Opart + (size_t)base * 2048 + row * 64 + d0;
    const float* O1 = O0 + 2048;
    int t = qb * 32 + row;
    bf16* op = o + ((size_t)(b * 2048 + t)) * 512 + h * 64 + d0;
    #pragma unroll 4
    for (int dd = 0; dd < 16; ++dd)
        op[dd] = f2b((O0[dd] * w0 + O1[dd] * w1) * inv);
}

// ---------------------------------------------------------------------------
// FF2 split-K merge + bias + residual: out f32 = p0+p1+b2+x2. 4M elements.
// ---------------------------------------------------------------------------
__global__ __launch_bounds__(256) void combine_ff2(
    const float* __restrict__ p0, const float* __restrict__ p1,
    const bf16* __restrict__ x2, const bf16* __restrict__ b2,
    float* __restrict__ out)
{
    int i4 = (blockIdx.x * 256 + threadIdx.x) * 4;
    #pragma unroll
    for (int k = 0; k < 4; ++k) {
        int i = i4 + k;
        out[i] = p0[i] + p1[i] + b2f(x2[i]) + b2f(b2[i & 1023]);
    }
}

// ---------------------------------------------------------------------------
static void launch_gemm(int epi, hipStream_t s,
                        const bf16* A, int lda, int zsA, int zsA2,
                        const bf16* Bt, int ldb, int zsB, int zsB2,
                        void* C, int ldc, int zsC, int zsC2,
                        const bf16* bias, int zsBias, float scale,
                        const bf16* resid,
                        int M, int N, int K, int nz)
{
    bool mt64 = ((M >> 7) * (N >> 7) * nz) <= 512;
    dim3 blk(256);
    if (mt64) {
        dim3 g(N / 128, M / 64, nz);
        switch (epi) {
        case 0: gemm_bt<0,64><<<g, blk, 0, s>>>(A, lda, zsA, zsA2, Bt, ldb, zsB, zsB2, C, ldc, zsC, zsC2, bias, zsBias, scale, resid, K); break;
        case 1: gemm_bt<1,64><<<g, blk, 0, s>>>(A, lda, zsA, zsA2, Bt, ldb, zsB, zsB2, C, ldc, zsC, zsC2, bias, zsBias, scale, resid, K); break;
        case 3: gemm_bt<3,64><<<g, blk, 0, s>>>(A, lda, zsA, zsA2, Bt, ldb, zsB, zsB2, C, ldc, zsC, zsC2, bias, zsBias, scale, resid, K); break;
        default: gemm_bt<2,64><<<g, blk, 0, s>>>(A, lda, zsA, zsA2, Bt, ldb, zsB, zsB2, C, ldc, zsC, zsC2, bias, zsBias, scale, resid, K); break;
        }
    } else {
        dim3 g(N / 128, M / 128, nz);
        switch (epi) {
        case 0: gemm_bt<0,128><<<g, blk, 0, s>>>(A, lda, zsA, zsA2, Bt, ldb, zsB, zsB2, C, ldc, zsC, zsC2, bias, zsBias, scale, resid, K); break;
        case 1: gemm_bt<1,128><<<g, blk, 0, s>>>(A, lda, zsA, zsA2, Bt, ldb, zsB, zsB2, C, ldc, zsC, zsC2, bias, zsBias, scale, resid, K); break;
        case 3: gemm_bt<3,128><<<g, blk, 0, s>>>(A, lda, zsA, zsA2, Bt, ldb, zsB, zsB2, C, ldc, zsC, zsC2, bias, zsBias, scale, resid, K); break;
        default: gemm_bt<2,128><<<g, blk, 0, s>>>(A, lda, zsA, zsA2, Bt, ldb, zsB, zsB2, C, ldc, zsC, zsC2, bias, zsBias, scale, resid, K); break;
        }
    }
}

extern "C" void kernel_launch(void* const* d_in, const int* in_sizes, int n_in,
                              void* d_out, int out_size, void* d_ws, size_t ws_size,
                              hipStream_t stream)
{
    const void* text  = d_in[0];
    const void* audio = d_in[1];
    const void* video = d_in[2];
    const void* Wa    = d_in[3];
    const void* ba    = d_in[4];
    const void* lna_g = d_in[5];
    const void* lna_b = d_in[6];
    const void* Wvid  = d_in[7];
    const void* bvid  = d_in[8];
    const void* lnv_g = d_in[9];
    const void* lnv_b = d_in[10];
    const void* ln1_g = d_in[11];
    const void* ln1_b = d_in[12];
    const void* Wq    = d_in[13];
    const void* Wkv   = d_in[14];
    const void* qn_g  = d_in[15];
    const void* kn_g  = d_in[16];
    const void* Wo    = d_in[17];
    const void* W1    = d_in[18];
    const void* b1    = d_in[19];
    const void* ln2_g = d_in[20];
    const void* ln2_b = d_in[21];
    const void* W2    = d_in[22];
    const void* b2    = d_in[23];

    char* ws = (char*)d_ws;
    size_t off = 0;
    auto alloc = [&](size_t bytes) -> char* {
        char* p = ws + off;
        off += (bytes + 255) & ~(size_t)255;
        return p;
    };
    const size_t MB = 1024 * 1024;
    int*  flag  = (int*)alloc(256);
    bf16* vecs  = (bf16*)alloc(14 * 4096 * 2);
    bf16* WqkvT = (bf16*)alloc((size_t)1536 * 1024 * 2);
    bf16* WoT   = (bf16*)alloc((size_t)1024 * 512 * 2);
    bf16* W1T   = (bf16*)alloc((size_t)4096 * 1024 * 2);
    bf16* W2T   = (bf16*)alloc((size_t)1024 * 4096 * 2);
    char* regionIn = alloc(24 * MB);   // audioC,videoC -> qkvF -> Opart/ML -> p0
    char* region2  = alloc(32 * MB);   // tmp2/tmpF/xF -> g
    char* regionH  = alloc(8 * MB);    // audioT -> h
    char* regionX  = alloc(8 * MB);    // videoT -> x2
    char* regionO  = alloc(4 * MB);    // WaT,WvT -> o
    bf16* qrot    = (bf16*)alloc((size_t)4096 * 1024 * 2);
    bf16* krotPad = (bf16*)alloc((size_t)2 * 2560 * 1024 * 2);
    bf16* VTpad   = (bf16*)alloc((size_t)2 * 1024 * 2560 * 2);
    bf16* attn    = (bf16*)alloc((size_t)8 * 512 * 1024 * 2);

    bf16*  audioC = (bf16*)regionIn;
    bf16*  videoC = audioC + (size_t)4096 * 1024;
    float* qkvF   = (float*)regionIn;
    bf16*  tmp2   = (bf16*)region2;          // adapter GEMM out (2 x 4096x1024 bf16)
    float* tmpF   = (float*)region2;         // sim scores f32
    float* xF     = (float*)(region2 + 16 * MB);
    bf16*  g      = (bf16*)region2;
    bf16*  audioT = (bf16*)regionH;
    bf16*  h      = (bf16*)regionH;
    bf16*  videoT = (bf16*)regionX;
    bf16*  x2     = (bf16*)regionX;
    bf16*  WaT    = (bf16*)regionO;
    bf16*  WvT    = WaT + (size_t)1024 * 1024;
    bf16*  o      = (bf16*)regionO;
    bf16*  Qp     = qrot;
    bf16*  Kp     = krotPad;
    bf16*  Vth    = attn;
    // flash 2-way-split partials (regionIn dead at flash time; 8.7 MB)
    float* Opart  = (float*)regionIn;
    float* MLpart = Opart + (size_t)1024 * 2048;
    // FF2 split-K partials (dead regions at FF2 time)
    float* p0     = (float*)regionIn;        // 16 MB of 24
    float* p1     = (float*)VTpad;           // VTpad+attn contiguous ~19 MB

    bf16* baC   = vecs + 0 * 4096;
    bf16* bvidC = vecs + 1 * 4096;
    bf16* lnagC = vecs + 2 * 4096;
    bf16* lnabC = vecs + 3 * 4096;
    bf16* lnvgC = vecs + 4 * 4096;
    bf16* lnvbC = vecs + 5 * 4096;
    bf16* ln1gC = vecs + 6 * 4096;
    bf16* ln1bC = vecs + 7 * 4096;
    bf16* qngC  = vecs + 8 * 4096;
    bf16* kngC  = vecs + 9 * 4096;
    bf16* b1C   = vecs + 10 * 4096;
    bf16* ln2gC = vecs + 11 * 4096;
    bf16* ln2bC = vecs + 12 * 4096;
    bf16* b2C   = vecs + 13 * 4096;

    // 1) dtype flag
    detect_dtype<<<1, 64, 0, stream>>>((const unsigned short*)text, flag);

    // 2) canonicalize audio+video (one launch) + small vectors
    const int NTOK = 4096 * 1024;
    convert2<<<4096, 256, 0, stream>>>(audio, video, audioC, videoC, NTOK, flag);
    VecPack vp;
    const void* vsrc[14] = {ba, bvid, lna_g, lna_b, lnv_g, lnv_b, ln1_g, ln1_b,
                            qn_g, kn_g, b1, ln2_g, ln2_b, b2};
    int vn[14] = {1024, 1024, 1024, 1024, 1024, 1024, 1024, 1024,
                  64, 64, 4096, 4096, 4096, 1024};
    for (int i = 0; i < 14; ++i) { vp.src[i] = vsrc[i]; vp.n[i] = vn[i]; }
    convert_vecs<<<14, 256, 0, stream>>>(vp, vecs, flag);

    // 3) all 7 weight transposes in ONE launch
    dim3 tb(32, 8);
    {
        TPack tp;
        const void* tsrc[7] = {Wa, Wvid, Wq, Wkv, Wo, W1, W2};
        unsigned short* tdst[7] = {
            (unsigned short*)WaT, (unsigned short*)WvT,
            (unsigned short*)WqkvT, (unsigned short*)(WqkvT + (size_t)512 * 1024),
            (unsigned short*)WoT, (unsigned short*)W1T, (unsigned short*)W2T};
        int tR[7] = {1024, 1024, 1024, 1024, 512, 1024, 4096};
        int tC[7] = {1024, 1024, 512, 1024, 1024, 4096, 1024};
        int tldo[7] = {1024, 1024, 1024, 1024, 512, 1024, 4096};
        int total = 0;
        for (int i = 0; i < 7; ++i) {
            tp.src[i] = tsrc[i]; tp.dst[i] = tdst[i];
            tp.R[i] = tR[i]; tp.C[i] = tC[i]; tp.ldo[i] = tldo[i];
            tp.cnt[i] = (tC[i] >> 5) * (tR[i] >> 5);
            total += tp.cnt[i];
        }
        transpose_pack<<<total, tb, 0, stream>>>(tp, flag);
    }

    // 4) adapters: one batched GEMM (nz=2, bf16 out w/ bias) + merged LN
    launch_gemm(1, stream, audioC, 1024, 4096*1024, 0, WaT, 1024, 1024*1024, 0,
                tmp2, 1024, 4096*1024, 0, baC, 4096, 1.f, nullptr, 4096, 1024, 1024, 2);
    ln_rows2<<<8192, 256, 0, stream>>>(tmp2, lnagC, lnabC, lnvgC, lnvbC, audioT, videoT);

    // 5) pads, rotary (raw text), batched VTpad transpose
    hipMemsetAsync(krotPad, 0, (size_t)2 * 2560 * 1024 * 2, stream);
    hipMemsetAsync(VTpad, 0, (size_t)2 * 1024 * 2560 * 2, stream);
    rotary_kernel<<<2048, 256, 0, stream>>>(text, flag, audioT, qrot, krotPad);
    transpose_vt<<<dim3(32, 64, 2), tb, 0, stream>>>(
        (const unsigned short*)videoT, (unsigned short*)VTpad);

    // 6) local attention: batched sim (nz=8) -> softmax -> batched @V (nz=8)
    launch_gemm(0, stream, qrot, 1024, 512*1024, 0,
                krotPad, 1024, 512*1024, 512*1024,
                tmpF, 1024, 512*1024, 0, nullptr, 0, 1.f, nullptr, 512, 1024, 1024, 8);
    softmax_local<<<dim3(512, 8), 256, 0, stream>>>(tmpF, attn);
    launch_gemm(0, stream, attn, 1024, 512*1024, 0,
                VTpad, 2560, 512, 1024*2560 - 2048,
                xF, 1024, 512*1024, 0, nullptr, 0, 1.f, nullptr, 512, 1024, 1024, 8);

    // 7) ln1 -> qkv -> pack -> V transpose -> 2-way-split swapped flash
    ln_f32_1024<<<4096, 256, 0, stream>>>(xF, ln1gC, ln1bC, h);
    launch_gemm(0, stream, h, 1024, 0, 0, WqkvT, 1024, 0, 0,
                qkvF, 1536, 0, 0, nullptr, 0, 1.f, nullptr, 4096, 1536, 1024, 1);
    pack_qk<<<16384, 256, 0, stream>>>(qkvF, Qp, Kp, qngC, kngC);
    transpose_v<<<dim3(2, 64, 16), tb, 0, stream>>>(qkvF, Vth);
    flash_fused6<<<dim3(96, 16), 128, 0, stream>>>(Qp, Kp, Vth, o, Opart, MLpart);
    flash_combine2<<<dim3(32, 16), 128, 0, stream>>>(Opart, MLpart, o);

    // 8) x2 = 2*(o@Wo) ; g = gelu(x2@W1+b1) via 8-phase 256^2 ; ln2 ;
    //    FF2 split-K=2 (4 blocks/CU) + combine (bias + residual).
    launch_gemm(1, stream, o, 512, 0, 0, WoT, 512, 0, 0,
                x2, 1024, 0, 0, nullptr, 0, 2.f, nullptr, 4096, 1024, 512, 1);
    gemm_ff1_8ph<<<dim3(16, 16), 512, 0, stream>>>(x2, 1024, W1T, 1024,
                                                   g, 4096, b1C, 1024);
    ln_b16_4096<<<4096, 256, 0, stream>>>(g, ln2gC, ln2bC, g);
    launch_gemm(0, stream, g, 4096, 2048, 0, W2T, 4096, 2048, 0,
                p0, 1024, (int)(p1 - p0), 0, nullptr, 0, 1.f, nullptr, 4096, 1024, 2048, 2);
    combine_ff2<<<4096, 256, 0, stream>>>(p0, p1, x2, b2C, (float*)d_out);

    (void)in_sizes; (void)n_in; (void)out_size; (void)ws_size;
}